// Round 1
// baseline (1026.105 us; speedup 1.0000x reference)
//
#include <hip/hip_runtime.h>
#include <math.h>

// AAGCN block, fp32, N=32 C=64 T=512 V=21 E=16 S=3.
// Round 1: correctness-first multi-kernel implementation.
// y0 is staged in d_out (88MB); d_ws needs ~7.4MB of f32 scratch.

#define Nn 32
#define Cc 64
#define Tt 512
#define Vv 21
#define Ee 16
#define Ss 3
#define EPSf 1e-5f
#define NCHUNK 16
#define SVV (Ss*Vv*Vv)   // 1323

__device__ __forceinline__ float sigm(float x){ return 1.f/(1.f+expf(-x)); }

// BN1-shuffled load: xb[n][a][b][v]  (a = out channel, b = out time)
// raw-reshape algebra: src channel = b&63, src time = a*8 + (b>>6), BN idx j = v*64 + a
__device__ __forceinline__ float load_xb(const float* __restrict__ x,
    const float* __restrict__ g1, const float* __restrict__ b1,
    const float* __restrict__ mu1, const float* __restrict__ var1,
    int n, int a, int b, int v)
{
    int csrc = b & 63;
    int tsrc = a*8 + (b >> 6);
    float val = x[ ((size_t)(n*Cc + csrc)*Tt + tsrc)*Vv + v ];
    int j = v*64 + a;
    float sc = g1[j] * rsqrtf(var1[j] + EPSf);
    return (val - mu1[j]) * sc + b1[j];
}

// ---------------- attention pre-activation partials ----------------
// grid (NCHUNK, N); each block: 32 t's, accumulates pre[s][u][v] partials.
__global__ __launch_bounds__(256) void k_attn(
    const float* __restrict__ x,
    const float* __restrict__ g1, const float* __restrict__ b1,
    const float* __restrict__ mu1, const float* __restrict__ var1,
    const float* __restrict__ wa, const float* __restrict__ ba,
    const float* __restrict__ wb, const float* __restrict__ bb,
    float* __restrict__ part)
{
    const int chunk = blockIdx.x;
    const int n = blockIdx.y;
    const int tid = threadIdx.x;

    __shared__ float was[48][64];
    __shared__ float wbs[48][64];
    __shared__ float xbt[2][64][22];
    __shared__ float m1s[2][48][22];
    __shared__ float m2s[2][48][22];

    for (int i = tid; i < 48*64; i += 256){
        was[i>>6][i&63] = wa[i];
        wbs[i>>6][i&63] = wb[i];
    }

    // m-phase mapping: thread (v = tid%21, se base = tid/21), 4 se per thread
    const int mv  = tid % 21;
    const int ms0 = tid / 21;   // 0..11 valid (tid<252)
    float bas[4] = {0,0,0,0}, bbs2[4] = {0,0,0,0};
    if (tid < 252){
        #pragma unroll
        for (int j = 0; j < 4; ++j){ bas[j] = ba[ms0 + 12*j]; bbs2[j] = bb[ms0 + 12*j]; }
    }

    float acc[6] = {0.f,0.f,0.f,0.f,0.f,0.f};

    for (int t2 = 0; t2 < 16; ++t2){
        const int tb = chunk*32 + t2*2;
        __syncthreads();
        for (int i = tid; i < 2*64*21; i += 256){
            int tt = i / 1344; int r = i % 1344;
            int a = r / 21, v = r % 21;
            xbt[tt][a][v] = load_xb(x, g1,b1,mu1,var1, n, a, tb+tt, v);
        }
        __syncthreads();
        if (tid < 252){
            float m1a[4], m1b[4], m2a[4], m2b[4];
            #pragma unroll
            for (int j = 0; j < 4; ++j){
                m1a[j]=bas[j]; m1b[j]=bas[j]; m2a[j]=bbs2[j]; m2b[j]=bbs2[j];
            }
            for (int c = 0; c < 64; ++c){
                float x0 = xbt[0][c][mv];
                float x1 = xbt[1][c][mv];
                #pragma unroll
                for (int j = 0; j < 4; ++j){
                    float wav = was[ms0+12*j][c];
                    float wbv = wbs[ms0+12*j][c];
                    m1a[j] += x0*wav;  m1b[j] += x1*wav;
                    m2a[j] += x0*wbv;  m2b[j] += x1*wbv;
                }
            }
            #pragma unroll
            for (int j = 0; j < 4; ++j){
                m1s[0][ms0+12*j][mv] = m1a[j];
                m1s[1][ms0+12*j][mv] = m1b[j];
                m2s[0][ms0+12*j][mv] = m2a[j];
                m2s[1][ms0+12*j][mv] = m2b[j];
            }
        }
        __syncthreads();
        #pragma unroll
        for (int k = 0; k < 6; ++k){
            int idx = tid + k*256;
            if (idx < SVV){
                int s = idx / 441; int r = idx % 441;
                int u = r / 21, vv = r % 21;
                float t0 = 0.f;
                #pragma unroll
                for (int e = 0; e < 16; ++e){
                    t0 += m1s[0][s*16+e][u]*m2s[0][s*16+e][vv];
                    t0 += m1s[1][s*16+e][u]*m2s[1][s*16+e][vv];
                }
                acc[k] += t0;
            }
        }
    }
    #pragma unroll
    for (int k = 0; k < 6; ++k){
        int idx = tid + k*256;
        if (idx < SVV) part[ (size_t)(n*NCHUNK + chunk)*SVV + idx ] = acc[k];
    }
}

// ---------------- adj = PA + tanh(pre/8192)*alpha ----------------
__global__ void k_adj(const float* __restrict__ part, const float* __restrict__ PA,
                      const float* __restrict__ alpha, float* __restrict__ adj)
{
    int i = blockIdx.x*256 + threadIdx.x;
    if (i >= Nn*SVV) return;
    int n = i / SVV;
    int idx = i % SVV;
    float pre = 0.f;
    for (int ch = 0; ch < NCHUNK; ++ch)
        pre += part[(size_t)(n*NCHUNK+ch)*SVV + idx];
    adj[i] = PA[idx] + tanhf(pre * (1.f/8192.f)) * alpha[0];
}

// ---------------- graph conv + wd + BN2 + residual + relu ----------------
// grid (T/4, N); 4 t per block; 4x6 register tile on (o,v).
__global__ __launch_bounds__(256) void k_y0(
    const float* __restrict__ x,
    const float* __restrict__ g1, const float* __restrict__ b1,
    const float* __restrict__ mu1, const float* __restrict__ var1,
    const float* __restrict__ adj,
    const float* __restrict__ wd, const float* __restrict__ bd,
    const float* __restrict__ g2, const float* __restrict__ b2,
    const float* __restrict__ mu2, const float* __restrict__ var2,
    float* __restrict__ y0)
{
    const int n = blockIdx.y;
    const int t0 = blockIdx.x * 4;
    const int tid = threadIdx.x;

    __shared__ float xbt[4][64][22];
    __shared__ float zs[4][64][22];
    __shared__ float adjc[21][22];
    __shared__ float wds[64][65];

    for (int i = tid; i < 4*64*21; i += 256){
        int tt = i / 1344; int r = i % 1344;
        int a = r / 21, v = r % 21;
        xbt[tt][a][v] = load_xb(x, g1,b1,mu1,var1, n, a, t0+tt, v);
    }

    const int tt = tid >> 6;
    const int og = (tid >> 2) & 15;
    const int q  = tid & 3;
    const int o0 = og*4;
    const int v0 = q*6;
    const int nv = (q==3) ? 3 : 6;

    float acc[4][6];
    #pragma unroll
    for (int i2 = 0; i2 < 4; ++i2)
        #pragma unroll
        for (int j = 0; j < 6; ++j) acc[i2][j] = 0.f;

    for (int s = 0; s < 3; ++s){
        __syncthreads();
        for (int i = tid; i < 441; i += 256)
            adjc[i/21][i%21] = adj[ (size_t)n*SVV + s*441 + i ];
        for (int i = tid; i < 4096; i += 256)
            wds[i>>6][i&63] = wd[s*4096 + i];
        __syncthreads();
        // z-phase: thread (zt = tid>>6, zc = tid&63) computes one z row
        {
            const int zc = tid & 63;
            const int zt = tid >> 6;
            float xr[21];
            #pragma unroll
            for (int u = 0; u < 21; ++u) xr[u] = xbt[zt][zc][u];
            #pragma unroll
            for (int v = 0; v < 21; ++v){
                float z = 0.f;
                #pragma unroll
                for (int u = 0; u < 21; ++u) z += xr[u]*adjc[u][v];
                zs[zt][zc][v] = z;
            }
        }
        __syncthreads();
        // y-phase: acc[o-i][v-j] += wd[s][o][c] * z[c][v]
        for (int c = 0; c < 64; ++c){
            float w0 = wds[o0+0][c];
            float w1 = wds[o0+1][c];
            float w2 = wds[o0+2][c];
            float w3 = wds[o0+3][c];
            #pragma unroll
            for (int j = 0; j < 6; ++j){
                if (j < nv){
                    float zv = zs[tt][c][v0+j];
                    acc[0][j] += w0*zv;
                    acc[1][j] += w1*zv;
                    acc[2][j] += w2*zv;
                    acc[3][j] += w3*zv;
                }
            }
        }
    }
    // epilogue: +bd.sum, BN2, +residual, relu
    #pragma unroll
    for (int i2 = 0; i2 < 4; ++i2){
        int o = o0 + i2;
        float bsum = bd[o] + bd[64+o] + bd[128+o];
        float sc = g2[o]*rsqrtf(var2[o]+EPSf);
        for (int j = 0; j < nv; ++j){
            int v = v0 + j;
            float val = acc[i2][j] + bsum;
            val = (val - mu2[o])*sc + b2[o];
            val += xbt[tt][o][v];
            y0[ ((size_t)(n*Cc + o)*Tt + (t0+tt))*Vv + v ] = fmaxf(val, 0.f);
        }
    }
}

// ---------------- M1[n,c,v] = sum_t y0 ----------------
__global__ __launch_bounds__(256) void k_M1(const float* __restrict__ y0, float* __restrict__ M1)
{
    const int c = blockIdx.x, n = blockIdx.y, tid = threadIdx.x;
    float a[21];
    #pragma unroll
    for (int v = 0; v < 21; ++v) a[v] = 0.f;
    for (int t = tid; t < Tt; t += 256){
        const float* p = &y0[ ((size_t)(n*Cc+c)*Tt + t)*Vv ];
        #pragma unroll
        for (int v = 0; v < 21; ++v) a[v] += p[v];
    }
    __shared__ float red[256][21];
    #pragma unroll
    for (int v = 0; v < 21; ++v) red[tid][v] = a[v];
    __syncthreads();
    for (int off = 128; off > 0; off >>= 1){
        if (tid < off){
            #pragma unroll
            for (int v = 0; v < 21; ++v) red[tid][v] += red[tid+off][v];
        }
        __syncthreads();
    }
    if (tid < 21) M1[(size_t)(n*Cc+c)*Vv + tid] = red[0][tid];
}

// ---------------- s1[n,v] = 1 + sigmoid(conv21(M1/T)) ----------------
__global__ void k_s1(const float* __restrict__ M1, const float* __restrict__ w_sa,
                     const float* __restrict__ b_sa, float* __restrict__ s1)
{
    int i = blockIdx.x*256 + threadIdx.x;
    if (i >= Nn*Vv) return;
    int n = i / Vv, v = i % Vv;
    float sum = b_sa[0];
    for (int c = 0; c < Cc; ++c){
        const float* row = &M1[(size_t)(n*Cc+c)*Vv];
        #pragma unroll
        for (int k = 0; k < 21; ++k){
            int src = v + k - 10;
            if (src >= 0 && src < Vv)
                sum += row[src] * (1.f/512.f) * w_sa[c*21 + k];
        }
    }
    s1[i] = 1.f + sigm(sum);
}

// ---------------- M2[n,c,t] = sum_v y0*s1 ----------------
__global__ __launch_bounds__(256) void k_M2(const float* __restrict__ y0, const float* __restrict__ s1,
                      float* __restrict__ M2)
{
    int t = blockIdx.x*256 + threadIdx.x;
    int nc = blockIdx.y;
    int n = nc >> 6;
    __shared__ float s1s[21];
    if (threadIdx.x < 21) s1s[threadIdx.x] = s1[n*Vv + threadIdx.x];
    __syncthreads();
    const float* p = &y0[ ((size_t)nc*Tt + t)*Vv ];
    float sum = 0.f;
    #pragma unroll
    for (int v = 0; v < 21; ++v) sum += p[v]*s1s[v];
    M2[(size_t)nc*Tt + t] = sum;
}

// ---------------- s2[n,t] = 1 + sigmoid(conv9(M2/V)) ----------------
__global__ __launch_bounds__(512) void k_s2(const float* __restrict__ M2, const float* __restrict__ w_ta,
                      const float* __restrict__ b_ta, float* __restrict__ s2)
{
    int n = blockIdx.x, t = threadIdx.x;
    float sum = b_ta[0];
    for (int c = 0; c < Cc; ++c){
        const float* row = &M2[(size_t)(n*Cc+c)*Tt];
        #pragma unroll
        for (int k = 0; k < 9; ++k){
            int src = t + k - 4;
            if (src >= 0 && src < Tt)
                sum += row[src] * (1.f/21.f) * w_ta[c*9 + k];
        }
    }
    s2[n*Tt + t] = 1.f + sigm(sum);
}

// ---------------- s3[n,c]: channel SE from M2 and s2 ----------------
__global__ __launch_bounds__(64) void k_s3(const float* __restrict__ M2, const float* __restrict__ s2,
                     const float* __restrict__ w1, const float* __restrict__ bf1,
                     const float* __restrict__ w2, const float* __restrict__ bf2,
                     float* __restrict__ s3)
{
    int n = blockIdx.x, c = threadIdx.x;
    __shared__ float sec[64];
    __shared__ float hh[32];
    const float* row = &M2[(size_t)(n*Cc+c)*Tt];
    const float* s2r = &s2[n*Tt];
    float dot = 0.f;
    for (int t = 0; t < Tt; ++t) dot += row[t]*s2r[t];
    sec[c] = dot * (1.f/(512.f*21.f));
    __syncthreads();
    if (c < 32){
        float h = bf1[c];
        for (int k = 0; k < 64; ++k) h += w1[c*64+k]*sec[k];
        hh[c] = fmaxf(h, 0.f);
    }
    __syncthreads();
    float o = bf2[c];
    for (int k = 0; k < 32; ++k) o += w2[c*32+k]*hh[k];
    s3[n*Cc + c] = 1.f + sigm(o);
}

// ---------------- final in-place: relu(y0*s1*s2*s3) ----------------
__global__ __launch_bounds__(256) void k_final(float* __restrict__ y,
    const float* __restrict__ s1, const float* __restrict__ s2, const float* __restrict__ s3)
{
    const size_t total = (size_t)Nn*Cc*Tt*Vv;
    for (size_t i = (size_t)blockIdx.x*256 + threadIdx.x; i < total; i += (size_t)gridDim.x*256){
        int v = (int)(i % Vv);
        size_t r = i / Vv;
        int t = (int)(r % Tt); r /= Tt;
        int c = (int)(r % Cc);
        int n = (int)(r / Cc);
        float val = y[i] * s1[n*Vv+v] * s2[n*Tt+t] * s3[n*Cc+c];
        y[i] = fmaxf(val, 0.f);
    }
}

extern "C" void kernel_launch(void* const* d_in, const int* in_sizes, int n_in,
                              void* d_out, int out_size, void* d_ws, size_t ws_size,
                              hipStream_t stream)
{
    const float* x    = (const float*)d_in[0];
    // d_in[1] = A (unused; PA is used per reference)
    const float* g1   = (const float*)d_in[2];
    const float* b1   = (const float*)d_in[3];
    const float* mu1  = (const float*)d_in[4];
    const float* var1 = (const float*)d_in[5];
    const float* PA   = (const float*)d_in[6];
    const float* alpha= (const float*)d_in[7];
    const float* wa   = (const float*)d_in[8];
    const float* ba   = (const float*)d_in[9];
    const float* wb   = (const float*)d_in[10];
    const float* bb   = (const float*)d_in[11];
    const float* wd   = (const float*)d_in[12];
    const float* bd   = (const float*)d_in[13];
    const float* g2   = (const float*)d_in[14];
    const float* b2   = (const float*)d_in[15];
    const float* mu2  = (const float*)d_in[16];
    const float* var2 = (const float*)d_in[17];
    const float* w_sa = (const float*)d_in[18];
    const float* b_sa = (const float*)d_in[19];
    const float* w_ta = (const float*)d_in[20];
    const float* b_ta = (const float*)d_in[21];
    const float* w_fc1= (const float*)d_in[22];
    const float* b_fc1= (const float*)d_in[23];
    const float* w_fc2= (const float*)d_in[24];
    const float* b_fc2= (const float*)d_in[25];

    float* ws   = (float*)d_ws;
    float* part = ws;                 // 32*16*1323 = 677376
    float* adj  = part + 677376;      // 42336
    float* M1   = adj  + 42336;       // 43008
    float* s1   = M1   + 43008;       // 672
    float* M2   = s1   + 672;         // 1048576
    float* s2   = M2   + 1048576;     // 16384
    float* s3   = s2   + 16384;       // 2048
    // total ws: 1,830,400 floats = 7.32 MB
    float* y0   = (float*)d_out;

    k_attn<<<dim3(NCHUNK, Nn), 256, 0, stream>>>(x, g1,b1,mu1,var1, wa,ba,wb,bb, part);
    k_adj<<<(Nn*SVV + 255)/256, 256, 0, stream>>>(part, PA, alpha, adj);
    k_y0<<<dim3(Tt/4, Nn), 256, 0, stream>>>(x, g1,b1,mu1,var1, adj, wd,bd, g2,b2,mu2,var2, y0);
    k_M1<<<dim3(Cc, Nn), 256, 0, stream>>>(y0, M1);
    k_s1<<<(Nn*Vv + 255)/256, 256, 0, stream>>>(M1, w_sa, b_sa, s1);
    k_M2<<<dim3(Tt/256, Nn*Cc), 256, 0, stream>>>(y0, s1, M2);
    k_s2<<<Nn, 512, 0, stream>>>(M2, w_ta, b_ta, s2);
    k_s3<<<Nn, 64, 0, stream>>>(M2, s2, w_fc1, b_fc1, w_fc2, b_fc2, s3);
    k_final<<<2048, 256, 0, stream>>>(y0, s1, s2, s3);
}

// Round 3
// 841.774 us; speedup vs baseline: 1.2190x; 1.2190x over previous
//
#include <hip/hip_runtime.h>
#include <hip/hip_bf16.h>
#include <math.h>

// AAGCN block, N=32 C=64 T=512 V=21 E=16 S=3.
// Round 3: fix k_y0 xbuf staging (was only filling 24/48 cols -> garbage t1).

#define Nn 32
#define Cc 64
#define Tt 512
#define Vv 21
#define VP 24
#define Ee 16
#define Ss 3
#define EPSf 1e-5f
#define NCHUNK 16
#define SVV (Ss*Vv*Vv)   // 1323

__device__ __forceinline__ float sigm(float x){ return 1.f/(1.f+expf(-x)); }
__device__ __forceinline__ float bf2f(unsigned short u){ return __uint_as_float((unsigned)u << 16); }

// ---------------- materialize xb (BN1 + raw-reshape shuffle), bf16, V->24 pad ----------------
// xbP[n][a][b][vp] = BN1(x[n][b&63][a*8+(b>>6)][v]), param j = v*64+a; vp>=21 -> 0
__global__ __launch_bounds__(256) void k_xb(
    const float* __restrict__ x,
    const float* __restrict__ g1, const float* __restrict__ b1,
    const float* __restrict__ mu1, const float* __restrict__ var1,
    __hip_bfloat16* __restrict__ xbP)
{
    const int a = blockIdx.x;   // out channel 0..63
    const int n = blockIdx.y;
    const int tid = threadIdx.x;
    __shared__ float brick[64][172];  // [csrc][t8*21+v]
    __shared__ float psc[21], pmu[21], pbe[21];
    if (tid < 21){
        int j = tid*64 + a;
        psc[tid] = g1[j]*rsqrtf(var1[j]+EPSf);
        pmu[tid] = mu1[j];
        pbe[tid] = b1[j];
    }
    // x[n][c][a*8 .. a*8+7][0..20]: per c, 168 contiguous floats
    const float* xs = x + (size_t)(n*64)*10752 + a*168;
    for (int i = tid; i < 64*168; i += 256){
        int c = i / 168, r = i % 168;
        brick[c][r] = xs[(size_t)c*10752 + r];
    }
    __syncthreads();
    __hip_bfloat16* op = xbP + (size_t)(n*64 + a)*512*VP;
    for (int i = tid; i < 512*VP; i += 256){
        int b = i / VP, vp = i % VP;
        float val = 0.f;
        if (vp < 21){
            float xv = brick[b & 63][(b >> 6)*21 + vp];
            val = (xv - pmu[vp]) * psc[vp] + pbe[vp];
        }
        op[i] = __float2bfloat16(val);
    }
}

// ---------------- attention pre-activation partials ----------------
__global__ __launch_bounds__(256) void k_attn(
    const __hip_bfloat16* __restrict__ xbP,
    const float* __restrict__ wa, const float* __restrict__ ba,
    const float* __restrict__ wb, const float* __restrict__ bb,
    float* __restrict__ part)
{
    const int chunk = blockIdx.x;
    const int n = blockIdx.y;
    const int tid = threadIdx.x;

    __shared__ float was[48][64];
    __shared__ float wbs[48][64];
    __shared__ float xbt[2][64][22];
    __shared__ float m1s[2][48][22];
    __shared__ float m2s[2][48][22];

    for (int i = tid; i < 48*64; i += 256){
        was[i>>6][i&63] = wa[i];
        wbs[i>>6][i&63] = wb[i];
    }

    const int mv  = tid % 21;
    const int ms0 = tid / 21;   // 0..11 valid (tid<252)
    float bas[4] = {0,0,0,0}, bbs2[4] = {0,0,0,0};
    if (tid < 252){
        #pragma unroll
        for (int j = 0; j < 4; ++j){ bas[j] = ba[ms0 + 12*j]; bbs2[j] = bb[ms0 + 12*j]; }
    }

    float acc[6] = {0.f,0.f,0.f,0.f,0.f,0.f};

    for (int t2 = 0; t2 < 16; ++t2){
        const int tb = chunk*32 + t2*2;
        __syncthreads();
        for (int i = tid; i < 2*64*21; i += 256){
            int tt = i / 1344; int r = i % 1344;
            int a = r / 21, v = r % 21;
            xbt[tt][a][v] = bf2f(*(const unsigned short*)(xbP + ((size_t)((n*64+a)*512) + tb+tt)*VP + v));
        }
        __syncthreads();
        if (tid < 252){
            float m1a[4], m1b[4], m2a[4], m2b[4];
            #pragma unroll
            for (int j = 0; j < 4; ++j){
                m1a[j]=bas[j]; m1b[j]=bas[j]; m2a[j]=bbs2[j]; m2b[j]=bbs2[j];
            }
            for (int c = 0; c < 64; ++c){
                float x0 = xbt[0][c][mv];
                float x1 = xbt[1][c][mv];
                #pragma unroll
                for (int j = 0; j < 4; ++j){
                    float wav = was[ms0+12*j][c];
                    float wbv = wbs[ms0+12*j][c];
                    m1a[j] += x0*wav;  m1b[j] += x1*wav;
                    m2a[j] += x0*wbv;  m2b[j] += x1*wbv;
                }
            }
            #pragma unroll
            for (int j = 0; j < 4; ++j){
                m1s[0][ms0+12*j][mv] = m1a[j];
                m1s[1][ms0+12*j][mv] = m1b[j];
                m2s[0][ms0+12*j][mv] = m2a[j];
                m2s[1][ms0+12*j][mv] = m2b[j];
            }
        }
        __syncthreads();
        #pragma unroll
        for (int k = 0; k < 6; ++k){
            int idx = tid + k*256;
            if (idx < SVV){
                int s = idx / 441; int r = idx % 441;
                int u = r / 21, vv = r % 21;
                float t0 = 0.f;
                #pragma unroll
                for (int e = 0; e < 16; ++e){
                    t0 += m1s[0][s*16+e][u]*m2s[0][s*16+e][vv];
                    t0 += m1s[1][s*16+e][u]*m2s[1][s*16+e][vv];
                }
                acc[k] += t0;
            }
        }
    }
    #pragma unroll
    for (int k = 0; k < 6; ++k){
        int idx = tid + k*256;
        if (idx < SVV) part[ (size_t)(n*NCHUNK + chunk)*SVV + idx ] = acc[k];
    }
}

// ---------------- adj = PA + tanh(pre/8192)*alpha ----------------
__global__ void k_adj(const float* __restrict__ part, const float* __restrict__ PA,
                      const float* __restrict__ alpha, float* __restrict__ adj)
{
    int i = blockIdx.x*256 + threadIdx.x;
    if (i >= Nn*SVV) return;
    int n = i / SVV;
    int idx = i % SVV;
    float pre = 0.f;
    for (int ch = 0; ch < NCHUNK; ++ch)
        pre += part[(size_t)(n*NCHUNK+ch)*SVV + idx];
    adj[i] = PA[idx] + tanhf(pre * (1.f/8192.f)) * alpha[0];
}

// ---------------- graph conv + wd + BN2 + residual + relu ----------------
// block = (t-pair, n); 256 threads.
// cols: 48 = 2t x 24vp. y GEMM: thread (i_o 0..15, j_c 0..15) -> 4o x 3col tile.
__global__ __launch_bounds__(256) void k_y0(
    const __hip_bfloat16* __restrict__ xbP,
    const float* __restrict__ adj,
    const float* __restrict__ wd, const float* __restrict__ bd,
    const float* __restrict__ g2, const float* __restrict__ b2,
    const float* __restrict__ mu2, const float* __restrict__ var2,
    float* __restrict__ y0)
{
    const int n = blockIdx.y;
    const int t0 = blockIdx.x * 2;
    const int tid = threadIdx.x;

    __shared__ float xbuf[64][49];   // [c][t*24+v], stride 49 (odd -> conflict-free rows)
    __shared__ float zbuf[64][52];
    __shared__ float wdT[64][68];    // [c][quad-swizzled o]
    __shared__ float adjs[21][24];   // padded, pads = 0

    // stage xbuf: per c, 48 contiguous bf16 (two t-rows of 24) = 12 ushort4
    {
        const unsigned short* src = (const unsigned short*)(xbP + ((size_t)(n*64)*512 + t0)*VP);
        for (int i = tid; i < 64*12; i += 256){
            int c = i / 12, q = i % 12;
            ushort4 u4 = *reinterpret_cast<const ushort4*>(src + (size_t)c*512*VP + q*4);
            xbuf[c][q*4+0] = bf2f(u4.x);
            xbuf[c][q*4+1] = bf2f(u4.y);
            xbuf[c][q*4+2] = bf2f(u4.z);
            xbuf[c][q*4+3] = bf2f(u4.w);
        }
    }

    const int i_o = tid >> 4;    // 0..15: o-quad
    const int j_c = tid & 15;    // 0..15: col-triple
    const int zcol = tid % 48;
    const int zcg  = tid / 48;   // 0..4 active (tid<240)
    const int zt24 = (zcol / 24) * 24;
    const int zv   = zcol % 24;

    float acc[4][3];
    #pragma unroll
    for (int r = 0; r < 4; ++r){ acc[r][0]=0.f; acc[r][1]=0.f; acc[r][2]=0.f; }

    for (int s = 0; s < 3; ++s){
        __syncthreads();   // prev y-phase done before restaging wdT / rewriting zbuf
        for (int i = tid; i < 4096; i += 256){
            int o = i >> 6, c = i & 63;
            int pcol = 4*((o>>2) ^ (c & 15)) + (o & 3);
            wdT[c][pcol] = wd[s*4096 + i];
        }
        for (int i = tid; i < 21*VP; i += 256){
            int u = i / VP, vp = i % VP;
            adjs[u][vp] = (vp < 21) ? adj[(size_t)n*SVV + s*441 + u*21 + vp] : 0.f;
        }
        __syncthreads();
        // z-phase: column-parallel, adj column hoisted to registers
        if (tid < 240){
            float areg[21];
            #pragma unroll
            for (int u = 0; u < 21; ++u) areg[u] = adjs[u][zv];
            for (int c = zcg; c < 64; c += 5){
                float zacc = 0.f;
                #pragma unroll
                for (int u = 0; u < 21; ++u) zacc += xbuf[c][zt24 + u] * areg[u];
                zbuf[c][zcol] = zacc;
            }
        }
        __syncthreads();
        // y-phase: acc[o][col] += wd[o][c] * z[c][col]
        for (int c = 0; c < 64; ++c){
            const float4 w4 = *reinterpret_cast<const float4*>(&wdT[c][4*(i_o ^ (c & 15))]);
            float z0 = zbuf[c][3*j_c + 0];
            float z1 = zbuf[c][3*j_c + 1];
            float z2 = zbuf[c][3*j_c + 2];
            acc[0][0] += w4.x*z0; acc[0][1] += w4.x*z1; acc[0][2] += w4.x*z2;
            acc[1][0] += w4.y*z0; acc[1][1] += w4.y*z1; acc[1][2] += w4.y*z2;
            acc[2][0] += w4.z*z0; acc[2][1] += w4.z*z1; acc[2][2] += w4.z*z2;
            acc[3][0] += w4.w*z0; acc[3][1] += w4.w*z1; acc[3][2] += w4.w*z2;
        }
    }

    // epilogue: +bd.sum, BN2, +residual(xbuf), relu, store
    #pragma unroll
    for (int r = 0; r < 4; ++r){
        const int o = 4*i_o + r;
        const float bsum = bd[o] + bd[64+o] + bd[128+o];
        const float sc = g2[o]*rsqrtf(var2[o]+EPSf);
        const float mu = mu2[o], be = b2[o];
        #pragma unroll
        for (int cc = 0; cc < 3; ++cc){
            const int col = 3*j_c + cc;
            const int tt = col / 24, v = col % 24;
            if (v < 21){
                float val = acc[r][cc] + bsum;
                val = (val - mu)*sc + be;
                val += xbuf[o][col];
                y0[((size_t)(n*64+o)*512 + (t0+tt))*21 + v] = fmaxf(val, 0.f);
            }
        }
    }
}

// ---------------- M1[n,c,v] = sum_t y0 ----------------
__global__ __launch_bounds__(256) void k_M1(const float* __restrict__ y0, float* __restrict__ M1)
{
    const int c = blockIdx.x, n = blockIdx.y, tid = threadIdx.x;
    float a[21];
    #pragma unroll
    for (int v = 0; v < 21; ++v) a[v] = 0.f;
    for (int t = tid; t < Tt; t += 256){
        const float* p = &y0[ ((size_t)(n*Cc+c)*Tt + t)*Vv ];
        #pragma unroll
        for (int v = 0; v < 21; ++v) a[v] += p[v];
    }
    __shared__ float red[256][21];
    #pragma unroll
    for (int v = 0; v < 21; ++v) red[tid][v] = a[v];
    __syncthreads();
    for (int off = 128; off > 0; off >>= 1){
        if (tid < off){
            #pragma unroll
            for (int v = 0; v < 21; ++v) red[tid][v] += red[tid+off][v];
        }
        __syncthreads();
    }
    if (tid < 21) M1[(size_t)(n*Cc+c)*Vv + tid] = red[0][tid];
}

// ---------------- s1[n,v] = 1 + sigmoid(conv21(M1/T)) ----------------
__global__ void k_s1(const float* __restrict__ M1, const float* __restrict__ w_sa,
                     const float* __restrict__ b_sa, float* __restrict__ s1)
{
    int i = blockIdx.x*256 + threadIdx.x;
    if (i >= Nn*Vv) return;
    int n = i / Vv, v = i % Vv;
    float sum = b_sa[0];
    for (int c = 0; c < Cc; ++c){
        const float* row = &M1[(size_t)(n*Cc+c)*Vv];
        #pragma unroll
        for (int k = 0; k < 21; ++k){
            int src = v + k - 10;
            if (src >= 0 && src < Vv)
                sum += row[src] * (1.f/512.f) * w_sa[c*21 + k];
        }
    }
    s1[i] = 1.f + sigm(sum);
}

// ---------------- M2[n,c,t] = sum_v y0*s1 ----------------
__global__ __launch_bounds__(256) void k_M2(const float* __restrict__ y0, const float* __restrict__ s1,
                      float* __restrict__ M2)
{
    int t = blockIdx.x*256 + threadIdx.x;
    int nc = blockIdx.y;
    int n = nc >> 6;
    __shared__ float s1s[21];
    if (threadIdx.x < 21) s1s[threadIdx.x] = s1[n*Vv + threadIdx.x];
    __syncthreads();
    const float* p = &y0[ ((size_t)nc*Tt + t)*Vv ];
    float sum = 0.f;
    #pragma unroll
    for (int v = 0; v < 21; ++v) sum += p[v]*s1s[v];
    M2[(size_t)nc*Tt + t] = sum;
}

// ---------------- s2[n,t] = 1 + sigmoid(conv9(M2/V)) ----------------
__global__ __launch_bounds__(512) void k_s2(const float* __restrict__ M2, const float* __restrict__ w_ta,
                      const float* __restrict__ b_ta, float* __restrict__ s2)
{
    int n = blockIdx.x, t = threadIdx.x;
    float sum = b_ta[0];
    for (int c = 0; c < Cc; ++c){
        const float* row = &M2[(size_t)(n*Cc+c)*Tt];
        #pragma unroll
        for (int k = 0; k < 9; ++k){
            int src = t + k - 4;
            if (src >= 0 && src < Tt)
                sum += row[src] * (1.f/21.f) * w_ta[c*9 + k];
        }
    }
    s2[n*Tt + t] = 1.f + sigm(sum);
}

// ---------------- s3[n,c]: channel SE from M2 and s2 ----------------
__global__ __launch_bounds__(64) void k_s3(const float* __restrict__ M2, const float* __restrict__ s2,
                     const float* __restrict__ w1, const float* __restrict__ bf1,
                     const float* __restrict__ w2, const float* __restrict__ bf2,
                     float* __restrict__ s3)
{
    int n = blockIdx.x, c = threadIdx.x;
    __shared__ float sec[64];
    __shared__ float hh[32];
    const float* row = &M2[(size_t)(n*Cc+c)*Tt];
    const float* s2r = &s2[n*Tt];
    float dot = 0.f;
    for (int t = 0; t < Tt; ++t) dot += row[t]*s2r[t];
    sec[c] = dot * (1.f/(512.f*21.f));
    __syncthreads();
    if (c < 32){
        float h = bf1[c];
        for (int k = 0; k < 64; ++k) h += w1[c*64+k]*sec[k];
        hh[c] = fmaxf(h, 0.f);
    }
    __syncthreads();
    float o = bf2[c];
    for (int k = 0; k < 32; ++k) o += w2[c*32+k]*hh[k];
    s3[n*Cc + c] = 1.f + sigm(o);
}

// ---------------- final in-place: relu(y0*s1*s2*s3) ----------------
__global__ __launch_bounds__(256) void k_final(float* __restrict__ y,
    const float* __restrict__ s1, const float* __restrict__ s2, const float* __restrict__ s3)
{
    const size_t total = (size_t)Nn*Cc*Tt*Vv;
    for (size_t i = (size_t)blockIdx.x*256 + threadIdx.x; i < total; i += (size_t)gridDim.x*256){
        int v = (int)(i % Vv);
        size_t r = i / Vv;
        int t = (int)(r % Tt); r /= Tt;
        int c = (int)(r % Cc);
        int n = (int)(r / Cc);
        float val = y[i] * s1[n*Vv+v] * s2[n*Tt+t] * s3[n*Cc+c];
        y[i] = fmaxf(val, 0.f);
    }
}

extern "C" void kernel_launch(void* const* d_in, const int* in_sizes, int n_in,
                              void* d_out, int out_size, void* d_ws, size_t ws_size,
                              hipStream_t stream)
{
    const float* x    = (const float*)d_in[0];
    const float* g1   = (const float*)d_in[2];
    const float* b1   = (const float*)d_in[3];
    const float* mu1  = (const float*)d_in[4];
    const float* var1 = (const float*)d_in[5];
    const float* PA   = (const float*)d_in[6];
    const float* alpha= (const float*)d_in[7];
    const float* wa   = (const float*)d_in[8];
    const float* ba   = (const float*)d_in[9];
    const float* wb   = (const float*)d_in[10];
    const float* bb   = (const float*)d_in[11];
    const float* wd   = (const float*)d_in[12];
    const float* bd   = (const float*)d_in[13];
    const float* g2   = (const float*)d_in[14];
    const float* b2   = (const float*)d_in[15];
    const float* mu2  = (const float*)d_in[16];
    const float* var2 = (const float*)d_in[17];
    const float* w_sa = (const float*)d_in[18];
    const float* b_sa = (const float*)d_in[19];
    const float* w_ta = (const float*)d_in[20];
    const float* b_ta = (const float*)d_in[21];
    const float* w_fc1= (const float*)d_in[22];
    const float* b_fc1= (const float*)d_in[23];
    const float* w_fc2= (const float*)d_in[24];
    const float* b_fc2= (const float*)d_in[25];

    // ws layout: xbP bf16 [32][64][512][24] = 25,165,824 elems = 50.33 MB, then f32 scratch
    __hip_bfloat16* xbP = (__hip_bfloat16*)d_ws;
    float* fws  = (float*)d_ws + 12582912;   // 50.33MB / 4
    float* part = fws;                 // 677376
    float* adjw = part + 677376;       // 42336
    float* M1   = adjw + 42336;        // 43008
    float* s1   = M1   + 43008;        // 672
    float* M2   = s1   + 672;          // 1048576
    float* s2   = M2   + 1048576;      // 16384
    float* s3   = s2   + 16384;        // 2048
    float* y0   = (float*)d_out;

    k_xb  <<<dim3(64, Nn), 256, 0, stream>>>(x, g1,b1,mu1,var1, xbP);
    k_attn<<<dim3(NCHUNK, Nn), 256, 0, stream>>>(xbP, wa,ba,wb,bb, part);
    k_adj <<<(Nn*SVV + 255)/256, 256, 0, stream>>>(part, PA, alpha, adjw);
    k_y0  <<<dim3(Tt/2, Nn), 256, 0, stream>>>(xbP, adjw, wd,bd, g2,b2,mu2,var2, y0);
    k_M1  <<<dim3(Cc, Nn), 256, 0, stream>>>(y0, M1);
    k_s1  <<<(Nn*Vv + 255)/256, 256, 0, stream>>>(M1, w_sa, b_sa, s1);
    k_M2  <<<dim3(Tt/256, Nn*Cc), 256, 0, stream>>>(y0, s1, M2);
    k_s2  <<<Nn, 512, 0, stream>>>(M2, w_ta, b_ta, s2);
    k_s3  <<<Nn, 64, 0, stream>>>(M2, s2, w_fc1, b_fc1, w_fc2, b_fc2, s3);
    k_final<<<2048, 256, 0, stream>>>(y0, s1, s2, s3);
}

// Round 4
// 797.332 us; speedup vs baseline: 1.2869x; 1.0557x over previous
//
#include <hip/hip_runtime.h>
#include <hip/hip_bf16.h>
#include <math.h>

// AAGCN block, N=32 C=64 T=512 V=21 E=16 S=3.
// Round 4: kill LDS bank conflicts.
//  - k_wdT pre-transposes wd into swizzled global layout; k_y0 stages it
//    with a coalesced conflict-free float4 copy (was 8-16-way conflicted).
//  - xbuf stride 49->52, float4 staging stores.
//  - k_attn: pad was/wbs to [48][65], m1s/m2s to [2][48][23].

#define Nn 32
#define Cc 64
#define Tt 512
#define Vv 21
#define VP 24
#define Ee 16
#define Ss 3
#define EPSf 1e-5f
#define NCHUNK 16
#define SVV (Ss*Vv*Vv)   // 1323

__device__ __forceinline__ float sigm(float x){ return 1.f/(1.f+expf(-x)); }
__device__ __forceinline__ float bf2f(unsigned short u){ return __uint_as_float((unsigned)u << 16); }

// ---------------- materialize xb (BN1 + raw-reshape shuffle), bf16, V->24 pad ----------------
// xbP[n][a][b][vp] = BN1(x[n][b&63][a*8+(b>>6)][v]), param j = v*64+a; vp>=21 -> 0
__global__ __launch_bounds__(256) void k_xb(
    const float* __restrict__ x,
    const float* __restrict__ g1, const float* __restrict__ b1,
    const float* __restrict__ mu1, const float* __restrict__ var1,
    __hip_bfloat16* __restrict__ xbP)
{
    const int a = blockIdx.x;   // out channel 0..63
    const int n = blockIdx.y;
    const int tid = threadIdx.x;
    __shared__ float brick[64][172];  // [csrc][t8*21+v]
    __shared__ float psc[21], pmu[21], pbe[21];
    if (tid < 21){
        int j = tid*64 + a;
        psc[tid] = g1[j]*rsqrtf(var1[j]+EPSf);
        pmu[tid] = mu1[j];
        pbe[tid] = b1[j];
    }
    const float* xs = x + (size_t)(n*64)*10752 + a*168;
    for (int i = tid; i < 64*168; i += 256){
        int c = i / 168, r = i % 168;
        brick[c][r] = xs[(size_t)c*10752 + r];
    }
    __syncthreads();
    __hip_bfloat16* op = xbP + (size_t)(n*64 + a)*512*VP;
    for (int i = tid; i < 512*VP; i += 256){
        int b = i / VP, vp = i % VP;
        float val = 0.f;
        if (vp < 21){
            float xv = brick[b & 63][(b >> 6)*21 + vp];
            val = (xv - pmu[vp]) * psc[vp] + pbe[vp];
        }
        op[i] = __float2bfloat16(val);
    }
}

// ---------------- pre-transpose wd into swizzled layout ----------------
// wdT_g[s][c][4*((o>>2)^(c&15)) + (o&3)] = wd[s][o][c]
__global__ __launch_bounds__(256) void k_wdT(const float* __restrict__ wd, float* __restrict__ wdTg)
{
    int i = blockIdx.x*256 + threadIdx.x;
    if (i >= Ss*4096) return;
    int s = i >> 12, rem = i & 4095;
    int o = rem >> 6, c = rem & 63;
    int pcol = 4*((o>>2) ^ (c & 15)) + (o & 3);
    wdTg[(size_t)s*4096 + c*64 + pcol] = wd[i];
}

// ---------------- attention pre-activation partials ----------------
__global__ __launch_bounds__(256) void k_attn(
    const __hip_bfloat16* __restrict__ xbP,
    const float* __restrict__ wa, const float* __restrict__ ba,
    const float* __restrict__ wb, const float* __restrict__ bb,
    float* __restrict__ part)
{
    const int chunk = blockIdx.x;
    const int n = blockIdx.y;
    const int tid = threadIdx.x;

    __shared__ float was[48][65];
    __shared__ float wbs[48][65];
    __shared__ float xbt[2][64][22];
    __shared__ float m1s[2][48][23];
    __shared__ float m2s[2][48][23];

    for (int i = tid; i < 48*64; i += 256){
        was[i>>6][i&63] = wa[i];
        wbs[i>>6][i&63] = wb[i];
    }

    const int mv  = tid % 21;
    const int ms0 = tid / 21;   // 0..11 valid (tid<252)
    float bas[4] = {0,0,0,0}, bbs2[4] = {0,0,0,0};
    if (tid < 252){
        #pragma unroll
        for (int j = 0; j < 4; ++j){ bas[j] = ba[ms0 + 12*j]; bbs2[j] = bb[ms0 + 12*j]; }
    }

    float acc[6] = {0.f,0.f,0.f,0.f,0.f,0.f};

    for (int t2 = 0; t2 < 16; ++t2){
        const int tb = chunk*32 + t2*2;
        __syncthreads();
        for (int i = tid; i < 2*64*21; i += 256){
            int tt = i / 1344; int r = i % 1344;
            int a = r / 21, v = r % 21;
            xbt[tt][a][v] = bf2f(*(const unsigned short*)(xbP + ((size_t)((n*64+a)*512) + tb+tt)*VP + v));
        }
        __syncthreads();
        if (tid < 252){
            float m1a[4], m1b[4], m2a[4], m2b[4];
            #pragma unroll
            for (int j = 0; j < 4; ++j){
                m1a[j]=bas[j]; m1b[j]=bas[j]; m2a[j]=bbs2[j]; m2b[j]=bbs2[j];
            }
            for (int c = 0; c < 64; ++c){
                float x0 = xbt[0][c][mv];
                float x1 = xbt[1][c][mv];
                #pragma unroll
                for (int j = 0; j < 4; ++j){
                    float wav = was[ms0+12*j][c];
                    float wbv = wbs[ms0+12*j][c];
                    m1a[j] += x0*wav;  m1b[j] += x1*wav;
                    m2a[j] += x0*wbv;  m2b[j] += x1*wbv;
                }
            }
            #pragma unroll
            for (int j = 0; j < 4; ++j){
                m1s[0][ms0+12*j][mv] = m1a[j];
                m1s[1][ms0+12*j][mv] = m1b[j];
                m2s[0][ms0+12*j][mv] = m2a[j];
                m2s[1][ms0+12*j][mv] = m2b[j];
            }
        }
        __syncthreads();
        #pragma unroll
        for (int k = 0; k < 6; ++k){
            int idx = tid + k*256;
            if (idx < SVV){
                int s = idx / 441; int r = idx % 441;
                int u = r / 21, vv = r % 21;
                float t0 = 0.f;
                #pragma unroll
                for (int e = 0; e < 16; ++e){
                    t0 += m1s[0][s*16+e][u]*m2s[0][s*16+e][vv];
                    t0 += m1s[1][s*16+e][u]*m2s[1][s*16+e][vv];
                }
                acc[k] += t0;
            }
        }
    }
    #pragma unroll
    for (int k = 0; k < 6; ++k){
        int idx = tid + k*256;
        if (idx < SVV) part[ (size_t)(n*NCHUNK + chunk)*SVV + idx ] = acc[k];
    }
}

// ---------------- adj = PA + tanh(pre/8192)*alpha ----------------
__global__ void k_adj(const float* __restrict__ part, const float* __restrict__ PA,
                      const float* __restrict__ alpha, float* __restrict__ adj)
{
    int i = blockIdx.x*256 + threadIdx.x;
    if (i >= Nn*SVV) return;
    int n = i / SVV;
    int idx = i % SVV;
    float pre = 0.f;
    for (int ch = 0; ch < NCHUNK; ++ch)
        pre += part[(size_t)(n*NCHUNK+ch)*SVV + idx];
    adj[i] = PA[idx] + tanhf(pre * (1.f/8192.f)) * alpha[0];
}

// ---------------- graph conv + wd + BN2 + residual + relu ----------------
// block = (t-pair, n); 256 threads.
// cols: 48 = 2t x 24vp. y GEMM: thread (i_o 0..15, j_c 0..15) -> 4o x 3col tile.
__global__ __launch_bounds__(256) void k_y0(
    const __hip_bfloat16* __restrict__ xbP,
    const float* __restrict__ adj,
    const float* __restrict__ wdTg, const float* __restrict__ bd,
    const float* __restrict__ g2, const float* __restrict__ b2,
    const float* __restrict__ mu2, const float* __restrict__ var2,
    float* __restrict__ y0)
{
    const int n = blockIdx.y;
    const int t0 = blockIdx.x * 2;
    const int tid = threadIdx.x;

    __shared__ float xbuf[64][52];   // [c][t*24+v], stride 52
    __shared__ float zbuf[64][52];
    __shared__ float wdT[64][68];    // [c][quad-swizzled o]
    __shared__ float adjs[21][24];   // padded, pads = 0

    // stage xbuf: per c, 48 contiguous bf16 (two t-rows of 24) = 12 ushort4 -> float4 stores
    {
        const unsigned short* src = (const unsigned short*)(xbP + ((size_t)(n*64)*512 + t0)*VP);
        for (int i = tid; i < 64*12; i += 256){
            int c = i / 12, q = i % 12;
            ushort4 u4 = *reinterpret_cast<const ushort4*>(src + (size_t)c*512*VP + q*4);
            float4 f4 = make_float4(bf2f(u4.x), bf2f(u4.y), bf2f(u4.z), bf2f(u4.w));
            *reinterpret_cast<float4*>(&xbuf[c][q*4]) = f4;
        }
    }

    const int i_o = tid >> 4;    // 0..15: o-quad
    const int j_c = tid & 15;    // 0..15: col-triple
    const int zcol = tid % 48;
    const int zcg  = tid / 48;   // 0..4 active (tid<240)
    const int zt24 = (zcol / 24) * 24;
    const int zv   = zcol % 24;

    float acc[4][3];
    #pragma unroll
    for (int r = 0; r < 4; ++r){ acc[r][0]=0.f; acc[r][1]=0.f; acc[r][2]=0.f; }

    for (int s = 0; s < 3; ++s){
        __syncthreads();   // prev y-phase done before restaging wdT / rewriting zbuf
        // coalesced, conflict-free staging of pre-swizzled wd
        for (int i = tid; i < 1024; i += 256){
            int c = i >> 4, m = i & 15;
            float4 w4 = *reinterpret_cast<const float4*>(&wdTg[(size_t)s*4096 + c*64 + m*4]);
            *reinterpret_cast<float4*>(&wdT[c][m*4]) = w4;
        }
        for (int i = tid; i < 21*VP; i += 256){
            int u = i / VP, vp = i % VP;
            adjs[u][vp] = (vp < 21) ? adj[(size_t)n*SVV + s*441 + u*21 + vp] : 0.f;
        }
        __syncthreads();
        // z-phase: column-parallel, adj column hoisted to registers
        if (tid < 240){
            float areg[21];
            #pragma unroll
            for (int u = 0; u < 21; ++u) areg[u] = adjs[u][zv];
            for (int c = zcg; c < 64; c += 5){
                float zacc = 0.f;
                #pragma unroll
                for (int u = 0; u < 21; ++u) zacc += xbuf[c][zt24 + u] * areg[u];
                zbuf[c][zcol] = zacc;
            }
        }
        __syncthreads();
        // y-phase: acc[o][col] += wd[o][c] * z[c][col]
        for (int c = 0; c < 64; ++c){
            const float4 w4 = *reinterpret_cast<const float4*>(&wdT[c][4*(i_o ^ (c & 15))]);
            float z0 = zbuf[c][3*j_c + 0];
            float z1 = zbuf[c][3*j_c + 1];
            float z2 = zbuf[c][3*j_c + 2];
            acc[0][0] += w4.x*z0; acc[0][1] += w4.x*z1; acc[0][2] += w4.x*z2;
            acc[1][0] += w4.y*z0; acc[1][1] += w4.y*z1; acc[1][2] += w4.y*z2;
            acc[2][0] += w4.z*z0; acc[2][1] += w4.z*z1; acc[2][2] += w4.z*z2;
            acc[3][0] += w4.w*z0; acc[3][1] += w4.w*z1; acc[3][2] += w4.w*z2;
        }
    }

    // epilogue: +bd.sum, BN2, +residual(xbuf), relu, store
    #pragma unroll
    for (int r = 0; r < 4; ++r){
        const int o = 4*i_o + r;
        const float bsum = bd[o] + bd[64+o] + bd[128+o];
        const float sc = g2[o]*rsqrtf(var2[o]+EPSf);
        const float mu = mu2[o], be = b2[o];
        #pragma unroll
        for (int cc = 0; cc < 3; ++cc){
            const int col = 3*j_c + cc;
            const int tt = col / 24, v = col % 24;
            if (v < 21){
                float val = acc[r][cc] + bsum;
                val = (val - mu)*sc + be;
                val += xbuf[o][col];
                y0[((size_t)(n*64+o)*512 + (t0+tt))*21 + v] = fmaxf(val, 0.f);
            }
        }
    }
}

// ---------------- M1[n,c,v] = sum_t y0 ----------------
__global__ __launch_bounds__(256) void k_M1(const float* __restrict__ y0, float* __restrict__ M1)
{
    const int c = blockIdx.x, n = blockIdx.y, tid = threadIdx.x;
    float a[21];
    #pragma unroll
    for (int v = 0; v < 21; ++v) a[v] = 0.f;
    for (int t = tid; t < Tt; t += 256){
        const float* p = &y0[ ((size_t)(n*Cc+c)*Tt + t)*Vv ];
        #pragma unroll
        for (int v = 0; v < 21; ++v) a[v] += p[v];
    }
    __shared__ float red[256][21];
    #pragma unroll
    for (int v = 0; v < 21; ++v) red[tid][v] = a[v];
    __syncthreads();
    for (int off = 128; off > 0; off >>= 1){
        if (tid < off){
            #pragma unroll
            for (int v = 0; v < 21; ++v) red[tid][v] += red[tid+off][v];
        }
        __syncthreads();
    }
    if (tid < 21) M1[(size_t)(n*Cc+c)*Vv + tid] = red[0][tid];
}

// ---------------- s1[n,v] = 1 + sigmoid(conv21(M1/T)) ----------------
__global__ void k_s1(const float* __restrict__ M1, const float* __restrict__ w_sa,
                     const float* __restrict__ b_sa, float* __restrict__ s1)
{
    int i = blockIdx.x*256 + threadIdx.x;
    if (i >= Nn*Vv) return;
    int n = i / Vv, v = i % Vv;
    float sum = b_sa[0];
    for (int c = 0; c < Cc; ++c){
        const float* row = &M1[(size_t)(n*Cc+c)*Vv];
        #pragma unroll
        for (int k = 0; k < 21; ++k){
            int src = v + k - 10;
            if (src >= 0 && src < Vv)
                sum += row[src] * (1.f/512.f) * w_sa[c*21 + k];
        }
    }
    s1[i] = 1.f + sigm(sum);
}

// ---------------- M2[n,c,t] = sum_v y0*s1 ----------------
__global__ __launch_bounds__(256) void k_M2(const float* __restrict__ y0, const float* __restrict__ s1,
                      float* __restrict__ M2)
{
    int t = blockIdx.x*256 + threadIdx.x;
    int nc = blockIdx.y;
    int n = nc >> 6;
    __shared__ float s1s[21];
    if (threadIdx.x < 21) s1s[threadIdx.x] = s1[n*Vv + threadIdx.x];
    __syncthreads();
    const float* p = &y0[ ((size_t)nc*Tt + t)*Vv ];
    float sum = 0.f;
    #pragma unroll
    for (int v = 0; v < 21; ++v) sum += p[v]*s1s[v];
    M2[(size_t)nc*Tt + t] = sum;
}

// ---------------- s2[n,t] = 1 + sigmoid(conv9(M2/V)) ----------------
__global__ __launch_bounds__(512) void k_s2(const float* __restrict__ M2, const float* __restrict__ w_ta,
                      const float* __restrict__ b_ta, float* __restrict__ s2)
{
    int n = blockIdx.x, t = threadIdx.x;
    float sum = b_ta[0];
    for (int c = 0; c < Cc; ++c){
        const float* row = &M2[(size_t)(n*Cc+c)*Tt];
        #pragma unroll
        for (int k = 0; k < 9; ++k){
            int src = t + k - 4;
            if (src >= 0 && src < Tt)
                sum += row[src] * (1.f/21.f) * w_ta[c*9 + k];
        }
    }
    s2[n*Tt + t] = 1.f + sigm(sum);
}

// ---------------- s3[n,c]: channel SE from M2 and s2 ----------------
__global__ __launch_bounds__(64) void k_s3(const float* __restrict__ M2, const float* __restrict__ s2,
                     const float* __restrict__ w1, const float* __restrict__ bf1,
                     const float* __restrict__ w2, const float* __restrict__ bf2,
                     float* __restrict__ s3)
{
    int n = blockIdx.x, c = threadIdx.x;
    __shared__ float sec[64];
    __shared__ float hh[32];
    const float* row = &M2[(size_t)(n*Cc+c)*Tt];
    const float* s2r = &s2[n*Tt];
    float dot = 0.f;
    for (int t = 0; t < Tt; ++t) dot += row[t]*s2r[t];
    sec[c] = dot * (1.f/(512.f*21.f));
    __syncthreads();
    if (c < 32){
        float h = bf1[c];
        for (int k = 0; k < 64; ++k) h += w1[c*64+k]*sec[k];
        hh[c] = fmaxf(h, 0.f);
    }
    __syncthreads();
    float o = bf2[c];
    for (int k = 0; k < 32; ++k) o += w2[c*32+k]*hh[k];
    s3[n*Cc + c] = 1.f + sigm(o);
}

// ---------------- final in-place: relu(y0*s1*s2*s3) ----------------
__global__ __launch_bounds__(256) void k_final(float* __restrict__ y,
    const float* __restrict__ s1, const float* __restrict__ s2, const float* __restrict__ s3)
{
    const size_t total = (size_t)Nn*Cc*Tt*Vv;
    for (size_t i = (size_t)blockIdx.x*256 + threadIdx.x; i < total; i += (size_t)gridDim.x*256){
        int v = (int)(i % Vv);
        size_t r = i / Vv;
        int t = (int)(r % Tt); r /= Tt;
        int c = (int)(r % Cc);
        int n = (int)(r / Cc);
        float val = y[i] * s1[n*Vv+v] * s2[n*Tt+t] * s3[n*Cc+c];
        y[i] = fmaxf(val, 0.f);
    }
}

extern "C" void kernel_launch(void* const* d_in, const int* in_sizes, int n_in,
                              void* d_out, int out_size, void* d_ws, size_t ws_size,
                              hipStream_t stream)
{
    const float* x    = (const float*)d_in[0];
    const float* g1   = (const float*)d_in[2];
    const float* b1   = (const float*)d_in[3];
    const float* mu1  = (const float*)d_in[4];
    const float* var1 = (const float*)d_in[5];
    const float* PA   = (const float*)d_in[6];
    const float* alpha= (const float*)d_in[7];
    const float* wa   = (const float*)d_in[8];
    const float* ba   = (const float*)d_in[9];
    const float* wb   = (const float*)d_in[10];
    const float* bb   = (const float*)d_in[11];
    const float* wd   = (const float*)d_in[12];
    const float* bd   = (const float*)d_in[13];
    const float* g2   = (const float*)d_in[14];
    const float* b2   = (const float*)d_in[15];
    const float* mu2  = (const float*)d_in[16];
    const float* var2 = (const float*)d_in[17];
    const float* w_sa = (const float*)d_in[18];
    const float* b_sa = (const float*)d_in[19];
    const float* w_ta = (const float*)d_in[20];
    const float* b_ta = (const float*)d_in[21];
    const float* w_fc1= (const float*)d_in[22];
    const float* b_fc1= (const float*)d_in[23];
    const float* w_fc2= (const float*)d_in[24];
    const float* b_fc2= (const float*)d_in[25];

    // ws layout: xbP bf16 [32][64][512][24] = 25,165,824 elems = 50.33 MB, then f32 scratch
    __hip_bfloat16* xbP = (__hip_bfloat16*)d_ws;
    float* fws  = (float*)d_ws + 12582912;   // 50.33MB / 4
    float* part = fws;                 // 677376
    float* adjw = part + 677376;       // 42336
    float* M1   = adjw + 42336;        // 43008
    float* s1   = M1   + 43008;        // 672
    float* M2   = s1   + 672;          // 1048576
    float* s2   = M2   + 1048576;      // 16384
    float* s3   = s2   + 16384;        // 2048
    float* wdTg = s3   + 2048;         // 12288
    float* y0   = (float*)d_out;

    k_xb  <<<dim3(64, Nn), 256, 0, stream>>>(x, g1,b1,mu1,var1, xbP);
    k_wdT <<<48, 256, 0, stream>>>(wd, wdTg);
    k_attn<<<dim3(NCHUNK, Nn), 256, 0, stream>>>(xbP, wa,ba,wb,bb, part);
    k_adj <<<(Nn*SVV + 255)/256, 256, 0, stream>>>(part, PA, alpha, adjw);
    k_y0  <<<dim3(Tt/2, Nn), 256, 0, stream>>>(xbP, adjw, wdTg,bd, g2,b2,mu2,var2, y0);
    k_M1  <<<dim3(Cc, Nn), 256, 0, stream>>>(y0, M1);
    k_s1  <<<(Nn*Vv + 255)/256, 256, 0, stream>>>(M1, w_sa, b_sa, s1);
    k_M2  <<<dim3(Tt/256, Nn*Cc), 256, 0, stream>>>(y0, s1, M2);
    k_s2  <<<Nn, 512, 0, stream>>>(M2, w_ta, b_ta, s2);
    k_s3  <<<Nn, 64, 0, stream>>>(M2, s2, w_fc1, b_fc1, w_fc2, b_fc2, s3);
    k_final<<<2048, 256, 0, stream>>>(y0, s1, s2, s3);
}

// Round 5
// 520.027 us; speedup vs baseline: 1.9732x; 1.5333x over previous
//
#include <hip/hip_runtime.h>
#include <hip/hip_bf16.h>
#include <math.h>

// AAGCN block, N=32 C=64 T=512 V=21 E=16 S=3.
// Round 5: MFMA k_y0. z = xb@adj and y = wd@z both on 16x16x32 bf16 matrix
// cores; adj/wd pre-packed into fragment layout in global; LDS strides chosen
// conflict-minimal (xbuf 272B rows, zbuf 144B cols). k_final de-div'd.

#define Nn 32
#define Cc 64
#define Tt 512
#define Vv 21
#define VP 24
#define Ss 3
#define EPSf 1e-5f
#define NCHUNK 16
#define SVV (Ss*Vv*Vv)   // 1323

typedef __attribute__((ext_vector_type(8))) short short8;
typedef __attribute__((ext_vector_type(4))) float f32x4;

__device__ __forceinline__ float sigm(float x){ return 1.f/(1.f+expf(-x)); }
__device__ __forceinline__ float bf2f(unsigned short u){ return __uint_as_float((unsigned)u << 16); }
__device__ __forceinline__ unsigned short f2bf(float f){
    __hip_bfloat16 h = __float2bfloat16(f);
    return *reinterpret_cast<unsigned short*>(&h);
}

// ---------------- materialize xb (BN1 + raw-reshape shuffle), bf16, V->24 pad ----------------
// xbP[n][a][b][vp] = BN1(x[n][b&63][a*8+(b>>6)][v]), param j = v*64+a; vp>=21 -> 0
__global__ __launch_bounds__(256) void k_xb(
    const float* __restrict__ x,
    const float* __restrict__ g1, const float* __restrict__ b1,
    const float* __restrict__ mu1, const float* __restrict__ var1,
    unsigned short* __restrict__ xbP)
{
    const int a = blockIdx.x;
    const int n = blockIdx.y;
    const int tid = threadIdx.x;
    __shared__ float brick[64][172];
    __shared__ float psc[21], pmu[21], pbe[21];
    if (tid < 21){
        int j = tid*64 + a;
        psc[tid] = g1[j]*rsqrtf(var1[j]+EPSf);
        pmu[tid] = mu1[j];
        pbe[tid] = b1[j];
    }
    const float* xs = x + (size_t)(n*64)*10752 + a*168;
    for (int i = tid; i < 64*168; i += 256){
        int c = i / 168, r = i % 168;
        brick[c][r] = xs[(size_t)c*10752 + r];
    }
    __syncthreads();
    unsigned short* op = xbP + (size_t)(n*64 + a)*512*VP;
    for (int i = tid; i < 512*VP; i += 256){
        int b = i / VP, vp = i % VP;
        float val = 0.f;
        if (vp < 21){
            float xv = brick[b & 63][(b >> 6)*21 + vp];
            val = (xv - pmu[vp]) * psc[vp] + pbe[vp];
        }
        op[i] = f2bf(val);
    }
}

// ---------------- pack wd into MFMA A-fragment layout + BN2 params ----------------
// wdF[(((s*4+w)*2+ks)*64 + l)*8 + j] = bf16(wd[s][o][c]), o=16w+(l&15), c=32ks+8*(l>>4)+j
__global__ __launch_bounds__(256) void k_wdT(
    const float* __restrict__ wd, const float* __restrict__ bd,
    const float* __restrict__ g2, const float* __restrict__ b2,
    const float* __restrict__ mu2, const float* __restrict__ var2,
    unsigned short* __restrict__ wdF, float4* __restrict__ bn2p)
{
    int i = blockIdx.x*256 + threadIdx.x;
    if (i < 1536){
        int s  = i / 512;
        int w  = (i >> 7) & 3;
        int ks = (i >> 6) & 1;
        int l  = i & 63;
        int o  = 16*w + (l & 15);
        #pragma unroll
        for (int j = 0; j < 8; ++j){
            int c = 32*ks + 8*(l >> 4) + j;
            wdF[(size_t)i*8 + j] = f2bf(wd[(s*64 + o)*64 + c]);
        }
    }
    if (i < 64){
        float bsum = bd[i] + bd[64+i] + bd[128+i];
        float sc = g2[i]*rsqrtf(var2[i]+EPSf);
        bn2p[i] = make_float4(bsum, sc, mu2[i], b2[i]);
    }
}

// ---------------- attention pre-activation partials ----------------
__global__ __launch_bounds__(256) void k_attn(
    const unsigned short* __restrict__ xbP,
    const float* __restrict__ wa, const float* __restrict__ ba,
    const float* __restrict__ wb, const float* __restrict__ bb,
    float* __restrict__ part)
{
    const int chunk = blockIdx.x;
    const int n = blockIdx.y;
    const int tid = threadIdx.x;

    __shared__ float was[48][65];
    __shared__ float wbs[48][65];
    __shared__ float xbt[2][64][22];
    __shared__ float m1s[2][48][23];
    __shared__ float m2s[2][48][23];

    for (int i = tid; i < 48*64; i += 256){
        was[i>>6][i&63] = wa[i];
        wbs[i>>6][i&63] = wb[i];
    }

    const int mv  = tid % 21;
    const int ms0 = tid / 21;
    float bas[4] = {0,0,0,0}, bbs2[4] = {0,0,0,0};
    if (tid < 252){
        #pragma unroll
        for (int j = 0; j < 4; ++j){ bas[j] = ba[ms0 + 12*j]; bbs2[j] = bb[ms0 + 12*j]; }
    }

    float acc[6] = {0.f,0.f,0.f,0.f,0.f,0.f};

    for (int t2 = 0; t2 < 16; ++t2){
        const int tb = chunk*32 + t2*2;
        __syncthreads();
        for (int i = tid; i < 2*64*21; i += 256){
            int tt = i / 1344; int r = i % 1344;
            int a = r / 21, v = r % 21;
            xbt[tt][a][v] = bf2f(xbP[((size_t)((n*64+a)*512) + tb+tt)*VP + v]);
        }
        __syncthreads();
        if (tid < 252){
            float m1a[4], m1b[4], m2a[4], m2b[4];
            #pragma unroll
            for (int j = 0; j < 4; ++j){
                m1a[j]=bas[j]; m1b[j]=bas[j]; m2a[j]=bbs2[j]; m2b[j]=bbs2[j];
            }
            for (int c = 0; c < 64; ++c){
                float x0 = xbt[0][c][mv];
                float x1 = xbt[1][c][mv];
                #pragma unroll
                for (int j = 0; j < 4; ++j){
                    float wav = was[ms0+12*j][c];
                    float wbv = wbs[ms0+12*j][c];
                    m1a[j] += x0*wav;  m1b[j] += x1*wav;
                    m2a[j] += x0*wbv;  m2b[j] += x1*wbv;
                }
            }
            #pragma unroll
            for (int j = 0; j < 4; ++j){
                m1s[0][ms0+12*j][mv] = m1a[j];
                m1s[1][ms0+12*j][mv] = m1b[j];
                m2s[0][ms0+12*j][mv] = m2a[j];
                m2s[1][ms0+12*j][mv] = m2b[j];
            }
        }
        __syncthreads();
        #pragma unroll
        for (int k = 0; k < 6; ++k){
            int idx = tid + k*256;
            if (idx < SVV){
                int s = idx / 441; int r = idx % 441;
                int u = r / 21, vv = r % 21;
                float t0 = 0.f;
                #pragma unroll
                for (int e = 0; e < 16; ++e){
                    t0 += m1s[0][s*16+e][u]*m2s[0][s*16+e][vv];
                    t0 += m1s[1][s*16+e][u]*m2s[1][s*16+e][vv];
                }
                acc[k] += t0;
            }
        }
    }
    #pragma unroll
    for (int k = 0; k < 6; ++k){
        int idx = tid + k*256;
        if (idx < SVV) part[ (size_t)(n*NCHUNK + chunk)*SVV + idx ] = acc[k];
    }
}

// ---------------- adj = PA + tanh(pre/8192)*alpha ----------------
__global__ void k_adj(const float* __restrict__ part, const float* __restrict__ PA,
                      const float* __restrict__ alpha, float* __restrict__ adj)
{
    int i = blockIdx.x*256 + threadIdx.x;
    if (i >= Nn*SVV) return;
    int n = i / SVV;
    int idx = i % SVV;
    float pre = 0.f;
    for (int ch = 0; ch < NCHUNK; ++ch)
        pre += part[(size_t)(n*NCHUNK+ch)*SVV + idx];
    adj[i] = PA[idx] + tanhf(pre * (1.f/8192.f)) * alpha[0];
}

// ---------------- pack adj into MFMA B-fragment layout (bf16) ----------------
// adjF[(((n*3+s)*2+h)*64 + l)*8 + j] = bf16(adj[n][s][u][v']), u=8*(l>>4)+j, v'=16h+(l&15)
__global__ __launch_bounds__(256) void k_adjF(const float* __restrict__ adj,
                                              unsigned short* __restrict__ adjF)
{
    int i = blockIdx.x*256 + threadIdx.x;
    if (i >= Nn*Ss*2*64) return;
    int n = i / 384;
    int r = i % 384;
    int s = r / 128;
    int r2 = r % 128;
    int h = r2 >> 6;
    int l = r2 & 63;
    int v = 16*h + (l & 15);
    #pragma unroll
    for (int j = 0; j < 8; ++j){
        int u = 8*(l >> 4) + j;
        float val = (u < 21 && v < 21) ? adj[(size_t)n*SVV + s*441 + u*21 + v] : 0.f;
        adjF[(size_t)i*8 + j] = f2bf(val);
    }
}

// ---------------- graph conv + wd + BN2 + residual + relu (MFMA) ----------------
// block = (n, 4 t's). 4 waves; wave w = M-tile (c-tile for z, o-tile for y).
// cols: 128 = 4t x 32v' (v' 21..31 zero). 288 MFMA/block.
__global__ __launch_bounds__(256) void k_y0(
    const unsigned short* __restrict__ xbP,
    const unsigned short* __restrict__ adjF,
    const unsigned short* __restrict__ wdF,
    const float4* __restrict__ bn2p,
    float* __restrict__ y0)
{
    const int n  = blockIdx.y;
    const int t0 = blockIdx.x * 4;
    const int tid = threadIdx.x;
    const int w  = tid >> 6;
    const int l  = tid & 63;
    const int g  = l >> 4;
    const int ln = l & 15;

    __shared__ unsigned short xbuf[64*136];   // [c][4t x 32u], row stride 272B
    __shared__ unsigned short zbuf[128*72];   // [col][64c], col stride 144B

    // stage xbuf: thread -> (c = tid>>2, t = tid&3); 24 bf16 + 8 zeros
    {
        const int c = tid >> 2, t = tid & 3;
        const uint4* s4 = reinterpret_cast<const uint4*>(
            xbP + ((size_t)(n*64 + c)*512 + t0 + t)*VP);
        uint4* d4 = reinterpret_cast<uint4*>(&xbuf[c*136 + t*32]);
        d4[0] = s4[0]; d4[1] = s4[1]; d4[2] = s4[2];
        d4[3] = make_uint4(0u,0u,0u,0u);
    }
    __syncthreads();

    // A_x fragments: lane: c = 16w+ln, k = u = 8g + j   (4 t's)
    short8 ax[4];
    #pragma unroll
    for (int t = 0; t < 4; ++t)
        ax[t] = *reinterpret_cast<const short8*>(&xbuf[(16*w + ln)*136 + t*32 + 8*g]);

    // B_adj fragments (global, per n): lane: v' = 16h+ln, u = 8g + j
    short8 badj[3][2];
    {
        const unsigned short* ap = adjF + (size_t)n*Ss*2*64*8;
        #pragma unroll
        for (int s = 0; s < 3; ++s)
            #pragma unroll
            for (int h = 0; h < 2; ++h)
                badj[s][h] = *reinterpret_cast<const short8*>(ap + ((s*2 + h)*64 + l)*8);
    }

    f32x4 acc[8];
    #pragma unroll
    for (int ct = 0; ct < 8; ++ct) acc[ct] = (f32x4){0.f,0.f,0.f,0.f};

    for (int s = 0; s < 3; ++s){
        if (s) __syncthreads();
        // z-MFMA: D_z[ct] rows c=16w+4g+r, cols v'=16h+ln (ct = t*2+h)
        f32x4 dz[8];
        #pragma unroll
        for (int ct = 0; ct < 8; ++ct)
            dz[ct] = __builtin_amdgcn_mfma_f32_16x16x32_bf16(
                         ax[ct>>1], badj[s][ct&1], (f32x4){0.f,0.f,0.f,0.f}, 0, 0, 0);
        // pack 4 f32 -> 4 bf16, write b64 to zbuf[col][c]
        #pragma unroll
        for (int ct = 0; ct < 8; ++ct){
            unsigned u0 = (unsigned)f2bf(dz[ct][0]) | ((unsigned)f2bf(dz[ct][1]) << 16);
            unsigned u1 = (unsigned)f2bf(dz[ct][2]) | ((unsigned)f2bf(dz[ct][3]) << 16);
            int col = (ct >> 1)*32 + (ct & 1)*16 + ln;
            *reinterpret_cast<uint2*>(&zbuf[col*72 + 16*w + 4*g]) = make_uint2(u0, u1);
        }
        __syncthreads();
        // y-MFMA: A_w (global frags), B_z from zbuf
        short8 aw0 = *reinterpret_cast<const short8*>(wdF + (size_t)(((s*4 + w)*2 + 0)*64 + l)*8);
        short8 aw1 = *reinterpret_cast<const short8*>(wdF + (size_t)(((s*4 + w)*2 + 1)*64 + l)*8);
        #pragma unroll
        for (int ct = 0; ct < 8; ++ct){
            int col = (ct >> 1)*32 + (ct & 1)*16 + ln;
            short8 b0 = *reinterpret_cast<const short8*>(&zbuf[col*72 + 0  + 8*g]);
            short8 b1 = *reinterpret_cast<const short8*>(&zbuf[col*72 + 32 + 8*g]);
            acc[ct] = __builtin_amdgcn_mfma_f32_16x16x32_bf16(aw0, b0, acc[ct], 0, 0, 0);
            acc[ct] = __builtin_amdgcn_mfma_f32_16x16x32_bf16(aw1, b1, acc[ct], 0, 0, 0);
        }
    }

    // epilogue: BN2 + residual + relu + store. o = 16w+4g+r, col=(t, v'=16h+ln)
    float4 bp[4];
    #pragma unroll
    for (int r = 0; r < 4; ++r) bp[r] = bn2p[16*w + 4*g + r];
    #pragma unroll
    for (int ct = 0; ct < 8; ++ct){
        const int t  = ct >> 1;
        const int vp = (ct & 1)*16 + ln;
        if (vp < 21){
            #pragma unroll
            for (int r = 0; r < 4; ++r){
                const int o = 16*w + 4*g + r;
                float val = acc[ct][r] + bp[r].x;
                val = (val - bp[r].z)*bp[r].y + bp[r].w;
                val += bf2f(xbuf[o*136 + t*32 + vp]);
                y0[((size_t)(n*64 + o)*512 + t0 + t)*21 + vp] = fmaxf(val, 0.f);
            }
        }
    }
}

// ---------------- M1[n,c,v] = sum_t y0 ----------------
__global__ __launch_bounds__(256) void k_M1(const float* __restrict__ y0, float* __restrict__ M1)
{
    const int c = blockIdx.x, n = blockIdx.y, tid = threadIdx.x;
    float a[21];
    #pragma unroll
    for (int v = 0; v < 21; ++v) a[v] = 0.f;
    for (int t = tid; t < Tt; t += 256){
        const float* p = &y0[ ((size_t)(n*Cc+c)*Tt + t)*Vv ];
        #pragma unroll
        for (int v = 0; v < 21; ++v) a[v] += p[v];
    }
    __shared__ float red[256][21];
    #pragma unroll
    for (int v = 0; v < 21; ++v) red[tid][v] = a[v];
    __syncthreads();
    for (int off = 128; off > 0; off >>= 1){
        if (tid < off){
            #pragma unroll
            for (int v = 0; v < 21; ++v) red[tid][v] += red[tid+off][v];
        }
        __syncthreads();
    }
    if (tid < 21) M1[(size_t)(n*Cc+c)*Vv + tid] = red[0][tid];
}

// ---------------- s1[n,v] = 1 + sigmoid(conv21(M1/T)) ----------------
__global__ void k_s1(const float* __restrict__ M1, const float* __restrict__ w_sa,
                     const float* __restrict__ b_sa, float* __restrict__ s1)
{
    int i = blockIdx.x*256 + threadIdx.x;
    if (i >= Nn*Vv) return;
    int n = i / Vv, v = i % Vv;
    float sum = b_sa[0];
    for (int c = 0; c < Cc; ++c){
        const float* row = &M1[(size_t)(n*Cc+c)*Vv];
        #pragma unroll
        for (int k = 0; k < 21; ++k){
            int src = v + k - 10;
            if (src >= 0 && src < Vv)
                sum += row[src] * (1.f/512.f) * w_sa[c*21 + k];
        }
    }
    s1[i] = 1.f + sigm(sum);
}

// ---------------- M2[n,c,t] = sum_v y0*s1 ----------------
__global__ __launch_bounds__(256) void k_M2(const float* __restrict__ y0, const float* __restrict__ s1,
                      float* __restrict__ M2)
{
    int t = blockIdx.x*256 + threadIdx.x;
    int nc = blockIdx.y;
    int n = nc >> 6;
    __shared__ float s1s[21];
    if (threadIdx.x < 21) s1s[threadIdx.x] = s1[n*Vv + threadIdx.x];
    __syncthreads();
    const float* p = &y0[ ((size_t)nc*Tt + t)*Vv ];
    float sum = 0.f;
    #pragma unroll
    for (int v = 0; v < 21; ++v) sum += p[v]*s1s[v];
    M2[(size_t)nc*Tt + t] = sum;
}

// ---------------- s2[n,t] = 1 + sigmoid(conv9(M2/V)) ----------------
__global__ __launch_bounds__(512) void k_s2(const float* __restrict__ M2, const float* __restrict__ w_ta,
                      const float* __restrict__ b_ta, float* __restrict__ s2)
{
    int n = blockIdx.x, t = threadIdx.x;
    float sum = b_ta[0];
    for (int c = 0; c < Cc; ++c){
        const float* row = &M2[(size_t)(n*Cc+c)*Tt];
        #pragma unroll
        for (int k = 0; k < 9; ++k){
            int src = t + k - 4;
            if (src >= 0 && src < Tt)
                sum += row[src] * (1.f/21.f) * w_ta[c*9 + k];
        }
    }
    s2[n*Tt + t] = 1.f + sigm(sum);
}

// ---------------- s3[n,c]: channel SE from M2 and s2 ----------------
__global__ __launch_bounds__(64) void k_s3(const float* __restrict__ M2, const float* __restrict__ s2,
                     const float* __restrict__ w1, const float* __restrict__ bf1,
                     const float* __restrict__ w2, const float* __restrict__ bf2,
                     float* __restrict__ s3)
{
    int n = blockIdx.x, c = threadIdx.x;
    __shared__ float sec[64];
    __shared__ float hh[32];
    const float* row = &M2[(size_t)(n*Cc+c)*Tt];
    const float* s2r = &s2[n*Tt];
    float dot = 0.f;
    for (int t = 0; t < Tt; ++t) dot += row[t]*s2r[t];
    sec[c] = dot * (1.f/(512.f*21.f));
    __syncthreads();
    if (c < 32){
        float h = bf1[c];
        for (int k = 0; k < 64; ++k) h += w1[c*64+k]*sec[k];
        hh[c] = fmaxf(h, 0.f);
    }
    __syncthreads();
    float o = bf2[c];
    for (int k = 0; k < 32; ++k) o += w2[c*32+k]*hh[k];
    s3[n*Cc + c] = 1.f + sigm(o);
}

// ---------------- final in-place: relu(y0*s1*s2*s3), per (n,c) row ----------------
__global__ __launch_bounds__(256) void k_final(float* __restrict__ y,
    const float* __restrict__ s1, const float* __restrict__ s2, const float* __restrict__ s3)
{
    const int c = blockIdx.x, n = blockIdx.y, tid = threadIdx.x;
    __shared__ float s1s[21];
    if (tid < 21) s1s[tid] = s1[n*Vv + tid];
    __syncthreads();
    const float sc3 = s3[n*Cc + c];
    float* base = y + (size_t)(n*Cc + c)*Tt*Vv;
    const float* s2r = s2 + n*Tt;
    for (int t = tid; t < Tt; t += 256){
        const float f = s2r[t] * sc3;
        float* p = base + (size_t)t*Vv;
        #pragma unroll
        for (int v = 0; v < 21; ++v)
            p[v] = fmaxf(p[v] * s1s[v] * f, 0.f);
    }
}

extern "C" void kernel_launch(void* const* d_in, const int* in_sizes, int n_in,
                              void* d_out, int out_size, void* d_ws, size_t ws_size,
                              hipStream_t stream)
{
    const float* x    = (const float*)d_in[0];
    const float* g1   = (const float*)d_in[2];
    const float* b1   = (const float*)d_in[3];
    const float* mu1  = (const float*)d_in[4];
    const float* var1 = (const float*)d_in[5];
    const float* PA   = (const float*)d_in[6];
    const float* alpha= (const float*)d_in[7];
    const float* wa   = (const float*)d_in[8];
    const float* ba   = (const float*)d_in[9];
    const float* wb   = (const float*)d_in[10];
    const float* bb   = (const float*)d_in[11];
    const float* wd   = (const float*)d_in[12];
    const float* bd   = (const float*)d_in[13];
    const float* g2   = (const float*)d_in[14];
    const float* b2   = (const float*)d_in[15];
    const float* mu2  = (const float*)d_in[16];
    const float* var2 = (const float*)d_in[17];
    const float* w_sa = (const float*)d_in[18];
    const float* b_sa = (const float*)d_in[19];
    const float* w_ta = (const float*)d_in[20];
    const float* b_ta = (const float*)d_in[21];
    const float* w_fc1= (const float*)d_in[22];
    const float* b_fc1= (const float*)d_in[23];
    const float* w_fc2= (const float*)d_in[24];
    const float* b_fc2= (const float*)d_in[25];

    // ws: xbP bf16 [32][64][512][24] = 25,165,824 elems (50.33MB), then f32/bf16 scratch
    unsigned short* xbP = (unsigned short*)d_ws;
    float* fws  = (float*)d_ws + 12582912;
    float* part = fws;                   // 677376
    float* adjw = part + 677376;         // 42336
    float* M1   = adjw + 42336;          // 43008
    float* s1   = M1   + 43008;          // 672
    float* M2   = s1   + 672;            // 1048576
    float* s2   = M2   + 1048576;        // 16384
    float* s3   = s2   + 16384;          // 2048
    float4* bn2p = (float4*)(s3 + 2048); // 256 f32
    unsigned short* wdF  = (unsigned short*)((float*)bn2p + 256);  // 12288 u16 (6144 f32)
    unsigned short* adjF = (unsigned short*)((float*)bn2p + 256 + 6144); // 98304 u16
    float* y0   = (float*)d_out;

    k_xb  <<<dim3(64, Nn), 256, 0, stream>>>(x, g1,b1,mu1,var1, xbP);
    k_wdT <<<6, 256, 0, stream>>>(wd, bd, g2, b2, mu2, var2, wdF, bn2p);
    k_attn<<<dim3(NCHUNK, Nn), 256, 0, stream>>>(xbP, wa,ba,wb,bb, part);
    k_adj <<<(Nn*SVV + 255)/256, 256, 0, stream>>>(part, PA, alpha, adjw);
    k_adjF<<<48, 256, 0, stream>>>(adjw, adjF);
    k_y0  <<<dim3(Tt/4, Nn), 256, 0, stream>>>(xbP, adjF, wdF, bn2p, y0);
    k_M1  <<<dim3(Cc, Nn), 256, 0, stream>>>(y0, M1);
    k_s1  <<<(Nn*Vv + 255)/256, 256, 0, stream>>>(M1, w_sa, b_sa, s1);
    k_M2  <<<dim3(Tt/256, Nn*Cc), 256, 0, stream>>>(y0, s1, M2);
    k_s2  <<<Nn, 512, 0, stream>>>(M2, w_ta, b_ta, s2);
    k_s3  <<<Nn, 64, 0, stream>>>(M2, s2, w_fc1, b_fc1, w_fc2, b_fc2, s3);
    k_final<<<dim3(Cc, Nn), 256, 0, stream>>>(y0, s1, s2, s3);
}

// Round 6
// 415.175 us; speedup vs baseline: 2.4715x; 1.2525x over previous
//
#include <hip/hip_runtime.h>
#include <hip/hip_bf16.h>
#include <math.h>

// AAGCN block, N=32 C=64 T=512 V=21 E=16 S=3.
// Round 6: MFMA k_attn. xb stored as xbT[n][t][v][c] (c-contiguous);
// phase A (embeddings) = [wa;wb](96x64) @ xb(64x192cols) per 8-t step,
// B-frags read straight from global, C scattered k-major into LDS;
// phase B (Gram) = m1^T @ m2 over K=128/step, accumulated 4 steps.
// k_y0 stages its xbuf from xbT via lane=c transpose writes.

#define Nn 32
#define Cc 64
#define Tt 512
#define Vv 21
#define VP 24
#define Ss 3
#define EPSf 1e-5f
#define NCHUNK 16
#define SVV (Ss*Vv*Vv)   // 1323
#define KSTR 136         // m-buf k-stride (16B-aligned rows, conflict-spread)

typedef __attribute__((ext_vector_type(8))) short short8;
typedef __attribute__((ext_vector_type(4))) float f32x4;

__device__ __forceinline__ float sigm(float x){ return 1.f/(1.f+expf(-x)); }
__device__ __forceinline__ float bf2f(unsigned short u){ return __uint_as_float((unsigned)u << 16); }
__device__ __forceinline__ unsigned short f2bf(float f){
    __hip_bfloat16 h = __float2bfloat16(f);
    return *reinterpret_cast<unsigned short*>(&h);
}

// ---------------- materialize xbT (BN1 + raw-reshape shuffle), bf16 ----------------
// xbT[n][b][vp][a] = BN1(x[n][b&63][a*8+(b>>6)][v]), param j = v*64+a; vp>=21 -> 0
// block = (c0 = b&63, n): owns all of x[n][c0], writes b = c0+64m, m=0..7, all a.
__global__ __launch_bounds__(256) void k_xb(
    const float* __restrict__ x,
    const float* __restrict__ g1, const float* __restrict__ b1,
    const float* __restrict__ mu1, const float* __restrict__ var1,
    unsigned short* __restrict__ xbT)
{
    const int c0 = blockIdx.x;
    const int n  = blockIdx.y;
    const int tid = threadIdx.x;
    __shared__ float brick[10752];                 // x[n][c0][t][v] flat t*21+v
    __shared__ float psc[1344], pmu[1344], pbe[1344];
    const float* xs = x + (size_t)(n*64 + c0)*10752;
    for (int i = tid; i < 2688; i += 256)
        *reinterpret_cast<float4*>(&brick[i*4]) = *reinterpret_cast<const float4*>(&xs[i*4]);
    for (int i = tid; i < 1344; i += 256){
        psc[i] = g1[i]*rsqrtf(var1[i]+EPSf);
        pmu[i] = mu1[i];
        pbe[i] = b1[i];
    }
    __syncthreads();
    for (int i = tid; i < 1536; i += 256){
        int vp = i % 24;
        int m  = (i / 24) % 8;
        int ag = i / 192;              // a-oct
        unsigned short pk[8];
        #pragma unroll
        for (int da = 0; da < 8; ++da){
            int a = ag*8 + da;
            float val = 0.f;
            if (vp < 21){
                float xv = brick[(a*8 + m)*21 + vp];
                int j = vp*64 + a;
                val = (xv - pmu[j])*psc[j] + pbe[j];
            }
            pk[da] = f2bf(val);
        }
        *reinterpret_cast<uint4*>(xbT + ((size_t)((n*512 + c0 + 64*m)*24 + vp))*64 + ag*8) =
            *reinterpret_cast<const uint4*>(pk);
    }
}

// ---------------- pack wd into MFMA A-fragment layout + BN2 params ----------------
__global__ __launch_bounds__(256) void k_wdT(
    const float* __restrict__ wd, const float* __restrict__ bd,
    const float* __restrict__ g2, const float* __restrict__ b2,
    const float* __restrict__ mu2, const float* __restrict__ var2,
    unsigned short* __restrict__ wdF, float4* __restrict__ bn2p)
{
    int i = blockIdx.x*256 + threadIdx.x;
    if (i < 1536){
        int s  = i / 512;
        int w  = (i >> 7) & 3;
        int ks = (i >> 6) & 1;
        int l  = i & 63;
        int o  = 16*w + (l & 15);
        #pragma unroll
        for (int j = 0; j < 8; ++j){
            int c = 32*ks + 8*(l >> 4) + j;
            wdF[(size_t)i*8 + j] = f2bf(wd[(s*64 + o)*64 + c]);
        }
    }
    if (i < 64){
        float bsum = bd[i] + bd[64+i] + bd[128+i];
        float sc = g2[i]*rsqrtf(var2[i]+EPSf);
        bn2p[i] = make_float4(bsum, sc, mu2[i], b2[i]);
    }
}

// ---------------- pack [wa;wb] into MFMA A-fragment layout (96 x 64) ----------------
// wawbF[((mt*2+ks)*64 + l)*8 + j] = src[s=mt%3][e=l&15][c=ks*32+8*(l>>4)+j]
__global__ __launch_bounds__(256) void k_wab(
    const float* __restrict__ wa, const float* __restrict__ wb,
    unsigned short* __restrict__ wawbF)
{
    int i = blockIdx.x*256 + threadIdx.x;
    if (i >= 768) return;
    int mt = i / 128;
    int ks = (i / 64) & 1;
    int l  = i & 63;
    int e  = l & 15;
    int g  = l >> 4;
    const float* src = (mt < 3) ? wa : wb;
    int s = (mt < 3) ? mt : mt - 3;
    #pragma unroll
    for (int j = 0; j < 8; ++j){
        int c = ks*32 + 8*g + j;
        wawbF[(size_t)i*8 + j] = f2bf(src[(s*16 + e)*64 + c]);
    }
}

// ---------------- attention pre-activation partials (MFMA) ----------------
// block (chunk, n); 4 waves. Per 8-t step:
// phase A: m1m2[96][192] = [wa;wb]@xb + bias -> scatter k-major to m-bufs
// phase B: pre[s][u][v] += m1^T @ m2 (K=128), acc over 4 steps.
__global__ __launch_bounds__(256) void k_attn(
    const unsigned short* __restrict__ xbT,
    const unsigned short* __restrict__ wawbF,
    const float* __restrict__ ba, const float* __restrict__ bb,
    float* __restrict__ part)
{
    const int chunk = blockIdx.x;
    const int n = blockIdx.y;
    const int tid = threadIdx.x;
    const int w  = tid >> 6;
    const int l  = tid & 63;
    const int g  = l >> 4;
    const int ln = l & 15;

    __shared__ unsigned short m1buf[3*32*KSTR];
    __shared__ unsigned short m2buf[3*32*KSTR];

    // zero the u-pad rows (u 24..31) once
    for (int i = tid; i < 3*8*KSTR; i += 256){
        int s = i / (8*KSTR), r = i % (8*KSTR);
        int off = (s*32 + 24)*KSTR + r;
        m1buf[off] = 0; m2buf[off] = 0;
    }

    // persistent A-frags + bias
    short8 aF[6][2];
    float4 bias4[6];
    #pragma unroll
    for (int mt = 0; mt < 6; ++mt){
        #pragma unroll
        for (int ks = 0; ks < 2; ++ks)
            aF[mt][ks] = *reinterpret_cast<const short8*>(wawbF + (size_t)((mt*2+ks)*64 + l)*8);
        const float* bsrc = (mt < 3) ? (ba + mt*16) : (bb + (mt-3)*16);
        bias4[mt] = *reinterpret_cast<const float4*>(bsrc + 4*g);
    }

    f32x4 accB[3];
    #pragma unroll
    for (int q = 0; q < 3; ++q) accB[q] = (f32x4){0.f,0.f,0.f,0.f};

    // per-lane col decode for this wave's 3 N-tiles
    int colv[3], colt[3];
    #pragma unroll
    for (int q = 0; q < 3; ++q){
        int col = (3*w + q)*16 + ln;
        colt[q] = col / 24;
        colv[q] = col % 24;
    }

    for (int st = 0; st < 4; ++st){
        const int tb = chunk*32 + st*8;
        // ---- phase A ----
        #pragma unroll
        for (int q = 0; q < 3; ++q){
            const unsigned short* bp = xbT + ((size_t)(n*512 + tb + colt[q])*24 + colv[q])*64;
            short8 b0 = *reinterpret_cast<const short8*>(bp + 8*g);
            short8 b1 = *reinterpret_cast<const short8*>(bp + 32 + 8*g);
            #pragma unroll
            for (int mt = 0; mt < 6; ++mt){
                f32x4 c;
                c[0] = bias4[mt].x; c[1] = bias4[mt].y;
                c[2] = bias4[mt].z; c[3] = bias4[mt].w;
                c = __builtin_amdgcn_mfma_f32_16x16x32_bf16(aF[mt][0], b0, c, 0, 0, 0);
                c = __builtin_amdgcn_mfma_f32_16x16x32_bf16(aF[mt][1], b1, c, 0, 0, 0);
                // scatter: value (row = mt*16+4g+r, col) -> buf[s][v][kidx=t*16+4g+r]
                unsigned short* dst = (mt < 3) ? m1buf : m2buf;
                int s = (mt < 3) ? mt : mt - 3;
                unsigned u0 = (unsigned)f2bf(c[0]) | ((unsigned)f2bf(c[1]) << 16);
                unsigned u1 = (unsigned)f2bf(c[2]) | ((unsigned)f2bf(c[3]) << 16);
                int off = (s*32 + colv[q])*KSTR + colt[q]*16 + 4*g;
                *reinterpret_cast<uint2*>(dst + off) = make_uint2(u0, u1);
            }
        }
        __syncthreads();
        // ---- phase B ----
        #pragma unroll
        for (int q = 0; q < 3; ++q){
            int ct = 3*w + q;
            int s = ct >> 2, mtile = (ct >> 1) & 1, ntile = ct & 1;
            #pragma unroll
            for (int kk = 0; kk < 4; ++kk){
                short8 a = *reinterpret_cast<const short8*>(&m1buf[(s*32 + mtile*16 + ln)*KSTR + kk*32 + 8*g]);
                short8 b = *reinterpret_cast<const short8*>(&m2buf[(s*32 + ntile*16 + ln)*KSTR + kk*32 + 8*g]);
                accB[q] = __builtin_amdgcn_mfma_f32_16x16x32_bf16(a, b, accB[q], 0, 0, 0);
            }
        }
        __syncthreads();
    }

    float* pout = part + (size_t)(n*NCHUNK + chunk)*SVV;
    #pragma unroll
    for (int q = 0; q < 3; ++q){
        int ct = 3*w + q;
        int s = ct >> 2, mtile = (ct >> 1) & 1, ntile = ct & 1;
        int v = ntile*16 + ln;
        #pragma unroll
        for (int r = 0; r < 4; ++r){
            int u = mtile*16 + 4*g + r;
            if (u < 21 && v < 21)
                pout[s*441 + u*21 + v] = accB[q][r];
        }
    }
}

// ---------------- adj = PA + tanh(pre/8192)*alpha ----------------
__global__ void k_adj(const float* __restrict__ part, const float* __restrict__ PA,
                      const float* __restrict__ alpha, float* __restrict__ adj)
{
    int i = blockIdx.x*256 + threadIdx.x;
    if (i >= Nn*SVV) return;
    int n = i / SVV;
    int idx = i % SVV;
    float pre = 0.f;
    for (int ch = 0; ch < NCHUNK; ++ch)
        pre += part[(size_t)(n*NCHUNK+ch)*SVV + idx];
    adj[i] = PA[idx] + tanhf(pre * (1.f/8192.f)) * alpha[0];
}

// ---------------- pack adj into MFMA B-fragment layout (bf16) ----------------
__global__ __launch_bounds__(256) void k_adjF(const float* __restrict__ adj,
                                              unsigned short* __restrict__ adjF)
{
    int i = blockIdx.x*256 + threadIdx.x;
    if (i >= Nn*Ss*2*64) return;
    int n = i / 384;
    int r = i % 384;
    int s = r / 128;
    int r2 = r % 128;
    int h = r2 >> 6;
    int l = r2 & 63;
    int v = 16*h + (l & 15);
    #pragma unroll
    for (int j = 0; j < 8; ++j){
        int u = 8*(l >> 4) + j;
        float val = (u < 21 && v < 21) ? adj[(size_t)n*SVV + s*441 + u*21 + v] : 0.f;
        adjF[(size_t)i*8 + j] = f2bf(val);
    }
}

// ---------------- graph conv + wd + BN2 + residual + relu (MFMA) ----------------
__global__ __launch_bounds__(256) void k_y0(
    const unsigned short* __restrict__ xbT,
    const unsigned short* __restrict__ adjF,
    const unsigned short* __restrict__ wdF,
    const float4* __restrict__ bn2p,
    float* __restrict__ y0)
{
    const int n  = blockIdx.y;
    const int t0 = blockIdx.x * 4;
    const int tid = threadIdx.x;
    const int w  = tid >> 6;
    const int l  = tid & 63;
    const int g  = l >> 4;
    const int ln = l & 15;

    __shared__ unsigned short xbuf[64*136];   // [c][4t x 32u], row stride 272B
    __shared__ unsigned short zbuf[128*72];   // [col][64c], col stride 144B

    // zero-pad u=24..31 of each (c,t)
    {
        int c = tid >> 2, t = tid & 3;
        *reinterpret_cast<uint4*>(&xbuf[c*136 + t*32 + 24]) = make_uint4(0u,0u,0u,0u);
    }
    // stage xbuf from xbT via lane=c transpose (conflict-free writes)
    for (int k = 0; k < 3; ++k){
        int i = tid + k*256;                  // 768 = 8cg x 4t x 24u
        int u = i % 24, t = (i/24) & 3, cg = i / 96;
        uint4 d = *reinterpret_cast<const uint4*>(
            xbT + ((size_t)(n*512 + t0 + t)*24 + u)*64 + cg*8);
        const unsigned short* p = reinterpret_cast<const unsigned short*>(&d);
        #pragma unroll
        for (int dc = 0; dc < 8; ++dc)
            xbuf[(cg*8 + dc)*136 + t*32 + u] = p[dc];
    }
    __syncthreads();

    // A_x fragments: lane: c = 16w+ln, k = u = 8g + j   (4 t's)
    short8 ax[4];
    #pragma unroll
    for (int t = 0; t < 4; ++t)
        ax[t] = *reinterpret_cast<const short8*>(&xbuf[(16*w + ln)*136 + t*32 + 8*g]);

    // B_adj fragments (global, per n)
    short8 badj[3][2];
    {
        const unsigned short* ap = adjF + (size_t)n*Ss*2*64*8;
        #pragma unroll
        for (int s = 0; s < 3; ++s)
            #pragma unroll
            for (int h = 0; h < 2; ++h)
                badj[s][h] = *reinterpret_cast<const short8*>(ap + ((s*2 + h)*64 + l)*8);
    }

    f32x4 acc[8];
    #pragma unroll
    for (int ct = 0; ct < 8; ++ct) acc[ct] = (f32x4){0.f,0.f,0.f,0.f};

    for (int s = 0; s < 3; ++s){
        if (s) __syncthreads();
        f32x4 dz[8];
        #pragma unroll
        for (int ct = 0; ct < 8; ++ct)
            dz[ct] = __builtin_amdgcn_mfma_f32_16x16x32_bf16(
                         ax[ct>>1], badj[s][ct&1], (f32x4){0.f,0.f,0.f,0.f}, 0, 0, 0);
        #pragma unroll
        for (int ct = 0; ct < 8; ++ct){
            unsigned u0 = (unsigned)f2bf(dz[ct][0]) | ((unsigned)f2bf(dz[ct][1]) << 16);
            unsigned u1 = (unsigned)f2bf(dz[ct][2]) | ((unsigned)f2bf(dz[ct][3]) << 16);
            int col = (ct >> 1)*32 + (ct & 1)*16 + ln;
            *reinterpret_cast<uint2*>(&zbuf[col*72 + 16*w + 4*g]) = make_uint2(u0, u1);
        }
        __syncthreads();
        short8 aw0 = *reinterpret_cast<const short8*>(wdF + (size_t)(((s*4 + w)*2 + 0)*64 + l)*8);
        short8 aw1 = *reinterpret_cast<const short8*>(wdF + (size_t)(((s*4 + w)*2 + 1)*64 + l)*8);
        #pragma unroll
        for (int ct = 0; ct < 8; ++ct){
            int col = (ct >> 1)*32 + (ct & 1)*16 + ln;
            short8 b0 = *reinterpret_cast<const short8*>(&zbuf[col*72 + 0  + 8*g]);
            short8 b1 = *reinterpret_cast<const short8*>(&zbuf[col*72 + 32 + 8*g]);
            acc[ct] = __builtin_amdgcn_mfma_f32_16x16x32_bf16(aw0, b0, acc[ct], 0, 0, 0);
            acc[ct] = __builtin_amdgcn_mfma_f32_16x16x32_bf16(aw1, b1, acc[ct], 0, 0, 0);
        }
    }

    float4 bp[4];
    #pragma unroll
    for (int r = 0; r < 4; ++r) bp[r] = bn2p[16*w + 4*g + r];
    #pragma unroll
    for (int ct = 0; ct < 8; ++ct){
        const int t  = ct >> 1;
        const int vp = (ct & 1)*16 + ln;
        if (vp < 21){
            #pragma unroll
            for (int r = 0; r < 4; ++r){
                const int o = 16*w + 4*g + r;
                float val = acc[ct][r] + bp[r].x;
                val = (val - bp[r].z)*bp[r].y + bp[r].w;
                val += bf2f(xbuf[o*136 + t*32 + vp]);
                y0[((size_t)(n*64 + o)*512 + t0 + t)*21 + vp] = fmaxf(val, 0.f);
            }
        }
    }
}

// ---------------- M1[n,c,v] = sum_t y0 ----------------
__global__ __launch_bounds__(256) void k_M1(const float* __restrict__ y0, float* __restrict__ M1)
{
    const int c = blockIdx.x, n = blockIdx.y, tid = threadIdx.x;
    float a[21];
    #pragma unroll
    for (int v = 0; v < 21; ++v) a[v] = 0.f;
    for (int t = tid; t < Tt; t += 256){
        const float* p = &y0[ ((size_t)(n*Cc+c)*Tt + t)*Vv ];
        #pragma unroll
        for (int v = 0; v < 21; ++v) a[v] += p[v];
    }
    __shared__ float red[256][21];
    #pragma unroll
    for (int v = 0; v < 21; ++v) red[tid][v] = a[v];
    __syncthreads();
    for (int off = 128; off > 0; off >>= 1){
        if (tid < off){
            #pragma unroll
            for (int v = 0; v < 21; ++v) red[tid][v] += red[tid+off][v];
        }
        __syncthreads();
    }
    if (tid < 21) M1[(size_t)(n*Cc+c)*Vv + tid] = red[0][tid];
}

// ---------------- s1[n,v] = 1 + sigmoid(conv21(M1/T)) ----------------
__global__ void k_s1(const float* __restrict__ M1, const float* __restrict__ w_sa,
                     const float* __restrict__ b_sa, float* __restrict__ s1)
{
    int i = blockIdx.x*256 + threadIdx.x;
    if (i >= Nn*Vv) return;
    int n = i / Vv, v = i % Vv;
    float sum = b_sa[0];
    for (int c = 0; c < Cc; ++c){
        const float* row = &M1[(size_t)(n*Cc+c)*Vv];
        #pragma unroll
        for (int k = 0; k < 21; ++k){
            int src = v + k - 10;
            if (src >= 0 && src < Vv)
                sum += row[src] * (1.f/512.f) * w_sa[c*21 + k];
        }
    }
    s1[i] = 1.f + sigm(sum);
}

// ---------------- M2[n,c,t] = sum_v y0*s1 ----------------
__global__ __launch_bounds__(256) void k_M2(const float* __restrict__ y0, const float* __restrict__ s1,
                      float* __restrict__ M2)
{
    int t = blockIdx.x*256 + threadIdx.x;
    int nc = blockIdx.y;
    int n = nc >> 6;
    __shared__ float s1s[21];
    if (threadIdx.x < 21) s1s[threadIdx.x] = s1[n*Vv + threadIdx.x];
    __syncthreads();
    const float* p = &y0[ ((size_t)nc*Tt + t)*Vv ];
    float sum = 0.f;
    #pragma unroll
    for (int v = 0; v < 21; ++v) sum += p[v]*s1s[v];
    M2[(size_t)nc*Tt + t] = sum;
}

// ---------------- s2[n,t] = 1 + sigmoid(conv9(M2/V)) ----------------
__global__ __launch_bounds__(512) void k_s2(const float* __restrict__ M2, const float* __restrict__ w_ta,
                      const float* __restrict__ b_ta, float* __restrict__ s2)
{
    int n = blockIdx.x, t = threadIdx.x;
    float sum = b_ta[0];
    for (int c = 0; c < Cc; ++c){
        const float* row = &M2[(size_t)(n*Cc+c)*Tt];
        #pragma unroll
        for (int k = 0; k < 9; ++k){
            int src = t + k - 4;
            if (src >= 0 && src < Tt)
                sum += row[src] * (1.f/21.f) * w_ta[c*9 + k];
        }
    }
    s2[n*Tt + t] = 1.f + sigm(sum);
}

// ---------------- s3[n,c]: channel SE from M2 and s2 ----------------
__global__ __launch_bounds__(64) void k_s3(const float* __restrict__ M2, const float* __restrict__ s2,
                     const float* __restrict__ w1, const float* __restrict__ bf1,
                     const float* __restrict__ w2, const float* __restrict__ bf2,
                     float* __restrict__ s3)
{
    int n = blockIdx.x, c = threadIdx.x;
    __shared__ float sec[64];
    __shared__ float hh[32];
    const float* row = &M2[(size_t)(n*Cc+c)*Tt];
    const float* s2r = &s2[n*Tt];
    float dot = 0.f;
    for (int t = 0; t < Tt; ++t) dot += row[t]*s2r[t];
    sec[c] = dot * (1.f/(512.f*21.f));
    __syncthreads();
    if (c < 32){
        float h = bf1[c];
        for (int k = 0; k < 64; ++k) h += w1[c*64+k]*sec[k];
        hh[c] = fmaxf(h, 0.f);
    }
    __syncthreads();
    float o = bf2[c];
    for (int k = 0; k < 32; ++k) o += w2[c*32+k]*hh[k];
    s3[n*Cc + c] = 1.f + sigm(o);
}

// ---------------- final in-place: relu(y0*s1*s2*s3), per (n,c) row ----------------
__global__ __launch_bounds__(256) void k_final(float* __restrict__ y,
    const float* __restrict__ s1, const float* __restrict__ s2, const float* __restrict__ s3)
{
    const int c = blockIdx.x, n = blockIdx.y, tid = threadIdx.x;
    __shared__ float s1s[21];
    if (tid < 21) s1s[tid] = s1[n*Vv + tid];
    __syncthreads();
    const float sc3 = s3[n*Cc + c];
    float* base = y + (size_t)(n*Cc + c)*Tt*Vv;
    const float* s2r = s2 + n*Tt;
    for (int t = tid; t < Tt; t += 256){
        const float f = s2r[t] * sc3;
        float* p = base + (size_t)t*Vv;
        #pragma unroll
        for (int v = 0; v < 21; ++v)
            p[v] = fmaxf(p[v] * s1s[v] * f, 0.f);
    }
}

extern "C" void kernel_launch(void* const* d_in, const int* in_sizes, int n_in,
                              void* d_out, int out_size, void* d_ws, size_t ws_size,
                              hipStream_t stream)
{
    const float* x    = (const float*)d_in[0];
    const float* g1   = (const float*)d_in[2];
    const float* b1   = (const float*)d_in[3];
    const float* mu1  = (const float*)d_in[4];
    const float* var1 = (const float*)d_in[5];
    const float* PA   = (const float*)d_in[6];
    const float* alpha= (const float*)d_in[7];
    const float* wa   = (const float*)d_in[8];
    const float* ba   = (const float*)d_in[9];
    const float* wb   = (const float*)d_in[10];
    const float* bb   = (const float*)d_in[11];
    const float* wd   = (const float*)d_in[12];
    const float* bd   = (const float*)d_in[13];
    const float* g2   = (const float*)d_in[14];
    const float* b2   = (const float*)d_in[15];
    const float* mu2  = (const float*)d_in[16];
    const float* var2 = (const float*)d_in[17];
    const float* w_sa = (const float*)d_in[18];
    const float* b_sa = (const float*)d_in[19];
    const float* w_ta = (const float*)d_in[20];
    const float* b_ta = (const float*)d_in[21];
    const float* w_fc1= (const float*)d_in[22];
    const float* b_fc1= (const float*)d_in[23];
    const float* w_fc2= (const float*)d_in[24];
    const float* b_fc2= (const float*)d_in[25];

    // ws: xbT bf16 [32][512][24][64] = 25,165,824 elems (50.33 MB), then scratch
    unsigned short* xbT = (unsigned short*)d_ws;
    float* fws  = (float*)d_ws + 12582912;
    float* part = fws;                   // 677376
    float* adjw = part + 677376;         // 42336
    float* M1   = adjw + 42336;          // 43008
    float* s1   = M1   + 43008;          // 672
    float* M2   = s1   + 672;            // 1048576
    float* s2   = M2   + 1048576;        // 16384
    float* s3   = s2   + 16384;          // 2048
    float4* bn2p = (float4*)(s3 + 2048); // 256 f32
    unsigned short* wdF   = (unsigned short*)((float*)bn2p + 256);   // 12288 u16
    unsigned short* adjF  = wdF + 12288;                             // 98304 u16
    unsigned short* wawbF = adjF + 98304;                            // 6144 u16
    float* y0   = (float*)d_out;

    k_xb  <<<dim3(64, Nn), 256, 0, stream>>>(x, g1,b1,mu1,var1, xbT);
    k_wdT <<<6, 256, 0, stream>>>(wd, bd, g2, b2, mu2, var2, wdF, bn2p);
    k_wab <<<3, 256, 0, stream>>>(wa, wb, wawbF);
    k_attn<<<dim3(NCHUNK, Nn), 256, 0, stream>>>(xbT, wawbF, ba, bb, part);
    k_adj <<<(Nn*SVV + 255)/256, 256, 0, stream>>>(part, PA, alpha, adjw);
    k_adjF<<<48, 256, 0, stream>>>(adjw, adjF);
    k_y0  <<<dim3(Tt/4, Nn), 256, 0, stream>>>(xbT, adjF, wdF, bn2p, y0);
    k_M1  <<<dim3(Cc, Nn), 256, 0, stream>>>(y0, M1);
    k_s1  <<<(Nn*Vv + 255)/256, 256, 0, stream>>>(M1, w_sa, b_sa, s1);
    k_M2  <<<dim3(Tt/256, Nn*Cc), 256, 0, stream>>>(y0, s1, M2);
    k_s2  <<<Nn, 512, 0, stream>>>(M2, w_ta, b_ta, s2);
    k_s3  <<<Nn, 64, 0, stream>>>(M2, s2, w_fc1, b_fc1, w_fc2, b_fc2, s3);
    k_final<<<dim3(Cc, Nn), 256, 0, stream>>>(y0, s1, s2, s3);
}

// Round 7
// 359.611 us; speedup vs baseline: 2.8534x; 1.1545x over previous
//
#include <hip/hip_runtime.h>
#include <hip/hip_bf16.h>
#include <math.h>

// AAGCN block, N=32 C=64 T=512 V=21 E=16 S=3.
// Round 7: k_xb conflict-free LDS layouts (params transposed [a][25],
// brick [512][24] so reads are lane-consecutive). No structural changes.

#define Nn 32
#define Cc 64
#define Tt 512
#define Vv 21
#define VP 24
#define Ss 3
#define EPSf 1e-5f
#define NCHUNK 16
#define SVV (Ss*Vv*Vv)   // 1323
#define KSTR 136         // m-buf k-stride (16B-aligned rows, conflict-spread)

typedef __attribute__((ext_vector_type(8))) short short8;
typedef __attribute__((ext_vector_type(4))) float f32x4;

__device__ __forceinline__ float sigm(float x){ return 1.f/(1.f+expf(-x)); }
__device__ __forceinline__ float bf2f(unsigned short u){ return __uint_as_float((unsigned)u << 16); }
__device__ __forceinline__ unsigned short f2bf(float f){
    __hip_bfloat16 h = __float2bfloat16(f);
    return *reinterpret_cast<unsigned short*>(&h);
}

// ---------------- materialize xbT (BN1 + raw-reshape shuffle), bf16 ----------------
// xbT[n][b][vp][a] = BN1(x[n][b&63][a*8+(b>>6)][v]), param j = v*64+a; vp>=21 -> 0
// block = (c0 = b&63, n). Conflict-free LDS: brick[t][24], params [a][25].
__global__ __launch_bounds__(256) void k_xb(
    const float* __restrict__ x,
    const float* __restrict__ g1, const float* __restrict__ b1,
    const float* __restrict__ mu1, const float* __restrict__ var1,
    unsigned short* __restrict__ xbT)
{
    const int c0 = blockIdx.x;
    const int n  = blockIdx.y;
    const int tid = threadIdx.x;
    __shared__ float brick[512*24];                 // [t][24]
    __shared__ float pscT[64*25], pmuT[64*25], pbeT[64*25];  // [a][25]
    const float* xs = x + (size_t)(n*64 + c0)*10752;
    for (int i = tid; i < 10752; i += 256)
        brick[(i/21)*24 + (i%21)] = xs[i];
    for (int i = tid; i < 1344; i += 256){
        int a = i & 63, v = i >> 6;
        pscT[a*25+v] = g1[i]*rsqrtf(var1[i]+EPSf);
        pmuT[a*25+v] = mu1[i];
        pbeT[a*25+v] = b1[i];
    }
    __syncthreads();
    #pragma unroll
    for (int ii = 0; ii < 6; ++ii){
        int i = tid + ii*256;
        int vp = i % 24;
        int m  = (i / 24) % 8;
        int ag = i / 192;              // a-oct (wave-uniform)
        unsigned short pk[8];
        #pragma unroll
        for (int da = 0; da < 8; ++da){
            int a = ag*8 + da;
            float val = 0.f;
            if (vp < 21){
                float xv = brick[(a*8 + m)*24 + vp];
                val = (xv - pmuT[a*25+vp])*pscT[a*25+vp] + pbeT[a*25+vp];
            }
            pk[da] = f2bf(val);
        }
        *reinterpret_cast<uint4*>(xbT + ((size_t)((n*512 + c0 + 64*m)*24 + vp))*64 + ag*8) =
            *reinterpret_cast<const uint4*>(pk);
    }
}

// ---------------- pack wd into MFMA A-fragment layout + BN2 params ----------------
__global__ __launch_bounds__(256) void k_wdT(
    const float* __restrict__ wd, const float* __restrict__ bd,
    const float* __restrict__ g2, const float* __restrict__ b2,
    const float* __restrict__ mu2, const float* __restrict__ var2,
    unsigned short* __restrict__ wdF, float4* __restrict__ bn2p)
{
    int i = blockIdx.x*256 + threadIdx.x;
    if (i < 1536){
        int s  = i / 512;
        int w  = (i >> 7) & 3;
        int ks = (i >> 6) & 1;
        int l  = i & 63;
        int o  = 16*w + (l & 15);
        #pragma unroll
        for (int j = 0; j < 8; ++j){
            int c = 32*ks + 8*(l >> 4) + j;
            wdF[(size_t)i*8 + j] = f2bf(wd[(s*64 + o)*64 + c]);
        }
    }
    if (i < 64){
        float bsum = bd[i] + bd[64+i] + bd[128+i];
        float sc = g2[i]*rsqrtf(var2[i]+EPSf);
        bn2p[i] = make_float4(bsum, sc, mu2[i], b2[i]);
    }
}

// ---------------- pack [wa;wb] into MFMA A-fragment layout (96 x 64) ----------------
__global__ __launch_bounds__(256) void k_wab(
    const float* __restrict__ wa, const float* __restrict__ wb,
    unsigned short* __restrict__ wawbF)
{
    int i = blockIdx.x*256 + threadIdx.x;
    if (i >= 768) return;
    int mt = i / 128;
    int ks = (i / 64) & 1;
    int l  = i & 63;
    int e  = l & 15;
    int g  = l >> 4;
    const float* src = (mt < 3) ? wa : wb;
    int s = (mt < 3) ? mt : mt - 3;
    #pragma unroll
    for (int j = 0; j < 8; ++j){
        int c = ks*32 + 8*g + j;
        wawbF[(size_t)i*8 + j] = f2bf(src[(s*16 + e)*64 + c]);
    }
}

// ---------------- attention pre-activation partials (MFMA) ----------------
__global__ __launch_bounds__(256) void k_attn(
    const unsigned short* __restrict__ xbT,
    const unsigned short* __restrict__ wawbF,
    const float* __restrict__ ba, const float* __restrict__ bb,
    float* __restrict__ part)
{
    const int chunk = blockIdx.x;
    const int n = blockIdx.y;
    const int tid = threadIdx.x;
    const int w  = tid >> 6;
    const int l  = tid & 63;
    const int g  = l >> 4;
    const int ln = l & 15;

    __shared__ unsigned short m1buf[3*32*KSTR];
    __shared__ unsigned short m2buf[3*32*KSTR];

    for (int i = tid; i < 3*8*KSTR; i += 256){
        int s = i / (8*KSTR), r = i % (8*KSTR);
        int off = (s*32 + 24)*KSTR + r;
        m1buf[off] = 0; m2buf[off] = 0;
    }

    short8 aF[6][2];
    float4 bias4[6];
    #pragma unroll
    for (int mt = 0; mt < 6; ++mt){
        #pragma unroll
        for (int ks = 0; ks < 2; ++ks)
            aF[mt][ks] = *reinterpret_cast<const short8*>(wawbF + (size_t)((mt*2+ks)*64 + l)*8);
        const float* bsrc = (mt < 3) ? (ba + mt*16) : (bb + (mt-3)*16);
        bias4[mt] = *reinterpret_cast<const float4*>(bsrc + 4*g);
    }

    f32x4 accB[3];
    #pragma unroll
    for (int q = 0; q < 3; ++q) accB[q] = (f32x4){0.f,0.f,0.f,0.f};

    int colv[3], colt[3];
    #pragma unroll
    for (int q = 0; q < 3; ++q){
        int col = (3*w + q)*16 + ln;
        colt[q] = col / 24;
        colv[q] = col % 24;
    }

    for (int st = 0; st < 4; ++st){
        const int tb = chunk*32 + st*8;
        #pragma unroll
        for (int q = 0; q < 3; ++q){
            const unsigned short* bp = xbT + ((size_t)(n*512 + tb + colt[q])*24 + colv[q])*64;
            short8 b0 = *reinterpret_cast<const short8*>(bp + 8*g);
            short8 b1 = *reinterpret_cast<const short8*>(bp + 32 + 8*g);
            #pragma unroll
            for (int mt = 0; mt < 6; ++mt){
                f32x4 c;
                c[0] = bias4[mt].x; c[1] = bias4[mt].y;
                c[2] = bias4[mt].z; c[3] = bias4[mt].w;
                c = __builtin_amdgcn_mfma_f32_16x16x32_bf16(aF[mt][0], b0, c, 0, 0, 0);
                c = __builtin_amdgcn_mfma_f32_16x16x32_bf16(aF[mt][1], b1, c, 0, 0, 0);
                unsigned short* dst = (mt < 3) ? m1buf : m2buf;
                int s = (mt < 3) ? mt : mt - 3;
                unsigned u0 = (unsigned)f2bf(c[0]) | ((unsigned)f2bf(c[1]) << 16);
                unsigned u1 = (unsigned)f2bf(c[2]) | ((unsigned)f2bf(c[3]) << 16);
                int off = (s*32 + colv[q])*KSTR + colt[q]*16 + 4*g;
                *reinterpret_cast<uint2*>(dst + off) = make_uint2(u0, u1);
            }
        }
        __syncthreads();
        #pragma unroll
        for (int q = 0; q < 3; ++q){
            int ct = 3*w + q;
            int s = ct >> 2, mtile = (ct >> 1) & 1, ntile = ct & 1;
            #pragma unroll
            for (int kk = 0; kk < 4; ++kk){
                short8 a = *reinterpret_cast<const short8*>(&m1buf[(s*32 + mtile*16 + ln)*KSTR + kk*32 + 8*g]);
                short8 b = *reinterpret_cast<const short8*>(&m2buf[(s*32 + ntile*16 + ln)*KSTR + kk*32 + 8*g]);
                accB[q] = __builtin_amdgcn_mfma_f32_16x16x32_bf16(a, b, accB[q], 0, 0, 0);
            }
        }
        __syncthreads();
    }

    float* pout = part + (size_t)(n*NCHUNK + chunk)*SVV;
    #pragma unroll
    for (int q = 0; q < 3; ++q){
        int ct = 3*w + q;
        int s = ct >> 2, mtile = (ct >> 1) & 1, ntile = ct & 1;
        int v = ntile*16 + ln;
        #pragma unroll
        for (int r = 0; r < 4; ++r){
            int u = mtile*16 + 4*g + r;
            if (u < 21 && v < 21)
                pout[s*441 + u*21 + v] = accB[q][r];
        }
    }
}

// ---------------- adj = PA + tanh(pre/8192)*alpha ----------------
__global__ void k_adj(const float* __restrict__ part, const float* __restrict__ PA,
                      const float* __restrict__ alpha, float* __restrict__ adj)
{
    int i = blockIdx.x*256 + threadIdx.x;
    if (i >= Nn*SVV) return;
    int n = i / SVV;
    int idx = i % SVV;
    float pre = 0.f;
    for (int ch = 0; ch < NCHUNK; ++ch)
        pre += part[(size_t)(n*NCHUNK+ch)*SVV + idx];
    adj[i] = PA[idx] + tanhf(pre * (1.f/8192.f)) * alpha[0];
}

// ---------------- pack adj into MFMA B-fragment layout (bf16) ----------------
__global__ __launch_bounds__(256) void k_adjF(const float* __restrict__ adj,
                                              unsigned short* __restrict__ adjF)
{
    int i = blockIdx.x*256 + threadIdx.x;
    if (i >= Nn*Ss*2*64) return;
    int n = i / 384;
    int r = i % 384;
    int s = r / 128;
    int r2 = r % 128;
    int h = r2 >> 6;
    int l = r2 & 63;
    int v = 16*h + (l & 15);
    #pragma unroll
    for (int j = 0; j < 8; ++j){
        int u = 8*(l >> 4) + j;
        float val = (u < 21 && v < 21) ? adj[(size_t)n*SVV + s*441 + u*21 + v] : 0.f;
        adjF[(size_t)i*8 + j] = f2bf(val);
    }
}

// ---------------- graph conv + wd + BN2 + residual + relu (MFMA) ----------------
__global__ __launch_bounds__(256) void k_y0(
    const unsigned short* __restrict__ xbT,
    const unsigned short* __restrict__ adjF,
    const unsigned short* __restrict__ wdF,
    const float4* __restrict__ bn2p,
    float* __restrict__ y0)
{
    const int n  = blockIdx.y;
    const int t0 = blockIdx.x * 4;
    const int tid = threadIdx.x;
    const int w  = tid >> 6;
    const int l  = tid & 63;
    const int g  = l >> 4;
    const int ln = l & 15;

    __shared__ unsigned short xbuf[64*136];   // [c][4t x 32u], row stride 272B
    __shared__ unsigned short zbuf[128*72];   // [col][64c], col stride 144B

    {
        int c = tid >> 2, t = tid & 3;
        *reinterpret_cast<uint4*>(&xbuf[c*136 + t*32 + 24]) = make_uint4(0u,0u,0u,0u);
    }
    for (int k = 0; k < 3; ++k){
        int i = tid + k*256;                  // 768 = 8cg x 4t x 24u
        int u = i % 24, t = (i/24) & 3, cg = i / 96;
        uint4 d = *reinterpret_cast<const uint4*>(
            xbT + ((size_t)(n*512 + t0 + t)*24 + u)*64 + cg*8);
        const unsigned short* p = reinterpret_cast<const unsigned short*>(&d);
        #pragma unroll
        for (int dc = 0; dc < 8; ++dc)
            xbuf[(cg*8 + dc)*136 + t*32 + u] = p[dc];
    }
    __syncthreads();

    short8 ax[4];
    #pragma unroll
    for (int t = 0; t < 4; ++t)
        ax[t] = *reinterpret_cast<const short8*>(&xbuf[(16*w + ln)*136 + t*32 + 8*g]);

    short8 badj[3][2];
    {
        const unsigned short* ap = adjF + (size_t)n*Ss*2*64*8;
        #pragma unroll
        for (int s = 0; s < 3; ++s)
            #pragma unroll
            for (int h = 0; h < 2; ++h)
                badj[s][h] = *reinterpret_cast<const short8*>(ap + ((s*2 + h)*64 + l)*8);
    }

    f32x4 acc[8];
    #pragma unroll
    for (int ct = 0; ct < 8; ++ct) acc[ct] = (f32x4){0.f,0.f,0.f,0.f};

    for (int s = 0; s < 3; ++s){
        if (s) __syncthreads();
        f32x4 dz[8];
        #pragma unroll
        for (int ct = 0; ct < 8; ++ct)
            dz[ct] = __builtin_amdgcn_mfma_f32_16x16x32_bf16(
                         ax[ct>>1], badj[s][ct&1], (f32x4){0.f,0.f,0.f,0.f}, 0, 0, 0);
        #pragma unroll
        for (int ct = 0; ct < 8; ++ct){
            unsigned u0 = (unsigned)f2bf(dz[ct][0]) | ((unsigned)f2bf(dz[ct][1]) << 16);
            unsigned u1 = (unsigned)f2bf(dz[ct][2]) | ((unsigned)f2bf(dz[ct][3]) << 16);
            int col = (ct >> 1)*32 + (ct & 1)*16 + ln;
            *reinterpret_cast<uint2*>(&zbuf[col*72 + 16*w + 4*g]) = make_uint2(u0, u1);
        }
        __syncthreads();
        short8 aw0 = *reinterpret_cast<const short8*>(wdF + (size_t)(((s*4 + w)*2 + 0)*64 + l)*8);
        short8 aw1 = *reinterpret_cast<const short8*>(wdF + (size_t)(((s*4 + w)*2 + 1)*64 + l)*8);
        #pragma unroll
        for (int ct = 0; ct < 8; ++ct){
            int col = (ct >> 1)*32 + (ct & 1)*16 + ln;
            short8 b0 = *reinterpret_cast<const short8*>(&zbuf[col*72 + 0  + 8*g]);
            short8 b1 = *reinterpret_cast<const short8*>(&zbuf[col*72 + 32 + 8*g]);
            acc[ct] = __builtin_amdgcn_mfma_f32_16x16x32_bf16(aw0, b0, acc[ct], 0, 0, 0);
            acc[ct] = __builtin_amdgcn_mfma_f32_16x16x32_bf16(aw1, b1, acc[ct], 0, 0, 0);
        }
    }

    float4 bp[4];
    #pragma unroll
    for (int r = 0; r < 4; ++r) bp[r] = bn2p[16*w + 4*g + r];
    #pragma unroll
    for (int ct = 0; ct < 8; ++ct){
        const int t  = ct >> 1;
        const int vp = (ct & 1)*16 + ln;
        if (vp < 21){
            #pragma unroll
            for (int r = 0; r < 4; ++r){
                const int o = 16*w + 4*g + r;
                float val = acc[ct][r] + bp[r].x;
                val = (val - bp[r].z)*bp[r].y + bp[r].w;
                val += bf2f(xbuf[o*136 + t*32 + vp]);
                y0[((size_t)(n*64 + o)*512 + t0 + t)*21 + vp] = fmaxf(val, 0.f);
            }
        }
    }
}

// ---------------- M1[n,c,v] = sum_t y0 ----------------
__global__ __launch_bounds__(256) void k_M1(const float* __restrict__ y0, float* __restrict__ M1)
{
    const int c = blockIdx.x, n = blockIdx.y, tid = threadIdx.x;
    float a[21];
    #pragma unroll
    for (int v = 0; v < 21; ++v) a[v] = 0.f;
    for (int t = tid; t < Tt; t += 256){
        const float* p = &y0[ ((size_t)(n*Cc+c)*Tt + t)*Vv ];
        #pragma unroll
        for (int v = 0; v < 21; ++v) a[v] += p[v];
    }
    __shared__ float red[256][21];
    #pragma unroll
    for (int v = 0; v < 21; ++v) red[tid][v] = a[v];
    __syncthreads();
    for (int off = 128; off > 0; off >>= 1){
        if (tid < off){
            #pragma unroll
            for (int v = 0; v < 21; ++v) red[tid][v] += red[tid+off][v];
        }
        __syncthreads();
    }
    if (tid < 21) M1[(size_t)(n*Cc+c)*Vv + tid] = red[0][tid];
}

// ---------------- s1[n,v] = 1 + sigmoid(conv21(M1/T)) ----------------
__global__ void k_s1(const float* __restrict__ M1, const float* __restrict__ w_sa,
                     const float* __restrict__ b_sa, float* __restrict__ s1)
{
    int i = blockIdx.x*256 + threadIdx.x;
    if (i >= Nn*Vv) return;
    int n = i / Vv, v = i % Vv;
    float sum = b_sa[0];
    for (int c = 0; c < Cc; ++c){
        const float* row = &M1[(size_t)(n*Cc+c)*Vv];
        #pragma unroll
        for (int k = 0; k < 21; ++k){
            int src = v + k - 10;
            if (src >= 0 && src < Vv)
                sum += row[src] * (1.f/512.f) * w_sa[c*21 + k];
        }
    }
    s1[i] = 1.f + sigm(sum);
}

// ---------------- M2[n,c,t] = sum_v y0*s1 ----------------
__global__ __launch_bounds__(256) void k_M2(const float* __restrict__ y0, const float* __restrict__ s1,
                      float* __restrict__ M2)
{
    int t = blockIdx.x*256 + threadIdx.x;
    int nc = blockIdx.y;
    int n = nc >> 6;
    __shared__ float s1s[21];
    if (threadIdx.x < 21) s1s[threadIdx.x] = s1[n*Vv + threadIdx.x];
    __syncthreads();
    const float* p = &y0[ ((size_t)nc*Tt + t)*Vv ];
    float sum = 0.f;
    #pragma unroll
    for (int v = 0; v < 21; ++v) sum += p[v]*s1s[v];
    M2[(size_t)nc*Tt + t] = sum;
}

// ---------------- s2[n,t] = 1 + sigmoid(conv9(M2/V)) ----------------
__global__ __launch_bounds__(512) void k_s2(const float* __restrict__ M2, const float* __restrict__ w_ta,
                      const float* __restrict__ b_ta, float* __restrict__ s2)
{
    int n = blockIdx.x, t = threadIdx.x;
    float sum = b_ta[0];
    for (int c = 0; c < Cc; ++c){
        const float* row = &M2[(size_t)(n*Cc+c)*Tt];
        #pragma unroll
        for (int k = 0; k < 9; ++k){
            int src = t + k - 4;
            if (src >= 0 && src < Tt)
                sum += row[src] * (1.f/21.f) * w_ta[c*9 + k];
        }
    }
    s2[n*Tt + t] = 1.f + sigm(sum);
}

// ---------------- s3[n,c]: channel SE from M2 and s2 ----------------
__global__ __launch_bounds__(64) void k_s3(const float* __restrict__ M2, const float* __restrict__ s2,
                     const float* __restrict__ w1, const float* __restrict__ bf1,
                     const float* __restrict__ w2, const float* __restrict__ bf2,
                     float* __restrict__ s3)
{
    int n = blockIdx.x, c = threadIdx.x;
    __shared__ float sec[64];
    __shared__ float hh[32];
    const float* row = &M2[(size_t)(n*Cc+c)*Tt];
    const float* s2r = &s2[n*Tt];
    float dot = 0.f;
    for (int t = 0; t < Tt; ++t) dot += row[t]*s2r[t];
    sec[c] = dot * (1.f/(512.f*21.f));
    __syncthreads();
    if (c < 32){
        float h = bf1[c];
        for (int k = 0; k < 64; ++k) h += w1[c*64+k]*sec[k];
        hh[c] = fmaxf(h, 0.f);
    }
    __syncthreads();
    float o = bf2[c];
    for (int k = 0; k < 32; ++k) o += w2[c*32+k]*hh[k];
    s3[n*Cc + c] = 1.f + sigm(o);
}

// ---------------- final in-place: relu(y0*s1*s2*s3), per (n,c) row ----------------
__global__ __launch_bounds__(256) void k_final(float* __restrict__ y,
    const float* __restrict__ s1, const float* __restrict__ s2, const float* __restrict__ s3)
{
    const int c = blockIdx.x, n = blockIdx.y, tid = threadIdx.x;
    __shared__ float s1s[21];
    if (tid < 21) s1s[tid] = s1[n*Vv + tid];
    __syncthreads();
    const float sc3 = s3[n*Cc + c];
    float* base = y + (size_t)(n*Cc + c)*Tt*Vv;
    const float* s2r = s2 + n*Tt;
    for (int t = tid; t < Tt; t += 256){
        const float f = s2r[t] * sc3;
        float* p = base + (size_t)t*Vv;
        #pragma unroll
        for (int v = 0; v < 21; ++v)
            p[v] = fmaxf(p[v] * s1s[v] * f, 0.f);
    }
}

extern "C" void kernel_launch(void* const* d_in, const int* in_sizes, int n_in,
                              void* d_out, int out_size, void* d_ws, size_t ws_size,
                              hipStream_t stream)
{
    const float* x    = (const float*)d_in[0];
    const float* g1   = (const float*)d_in[2];
    const float* b1   = (const float*)d_in[3];
    const float* mu1  = (const float*)d_in[4];
    const float* var1 = (const float*)d_in[5];
    const float* PA   = (const float*)d_in[6];
    const float* alpha= (const float*)d_in[7];
    const float* wa   = (const float*)d_in[8];
    const float* ba   = (const float*)d_in[9];
    const float* wb   = (const float*)d_in[10];
    const float* bb   = (const float*)d_in[11];
    const float* wd   = (const float*)d_in[12];
    const float* bd   = (const float*)d_in[13];
    const float* g2   = (const float*)d_in[14];
    const float* b2   = (const float*)d_in[15];
    const float* mu2  = (const float*)d_in[16];
    const float* var2 = (const float*)d_in[17];
    const float* w_sa = (const float*)d_in[18];
    const float* b_sa = (const float*)d_in[19];
    const float* w_ta = (const float*)d_in[20];
    const float* b_ta = (const float*)d_in[21];
    const float* w_fc1= (const float*)d_in[22];
    const float* b_fc1= (const float*)d_in[23];
    const float* w_fc2= (const float*)d_in[24];
    const float* b_fc2= (const float*)d_in[25];

    // ws: xbT bf16 [32][512][24][64] = 25,165,824 elems (50.33 MB), then scratch
    unsigned short* xbT = (unsigned short*)d_ws;
    float* fws  = (float*)d_ws + 12582912;
    float* part = fws;                   // 677376
    float* adjw = part + 677376;         // 42336
    float* M1   = adjw + 42336;          // 43008
    float* s1   = M1   + 43008;          // 672
    float* M2   = s1   + 672;            // 1048576
    float* s2   = M2   + 1048576;        // 16384
    float* s3   = s2   + 16384;          // 2048
    float4* bn2p = (float4*)(s3 + 2048); // 256 f32
    unsigned short* wdF   = (unsigned short*)((float*)bn2p + 256);   // 12288 u16
    unsigned short* adjF  = wdF + 12288;                             // 98304 u16
    unsigned short* wawbF = adjF + 98304;                            // 6144 u16
    float* y0   = (float*)d_out;

    k_xb  <<<dim3(64, Nn), 256, 0, stream>>>(x, g1,b1,mu1,var1, xbT);
    k_wdT <<<6, 256, 0, stream>>>(wd, bd, g2, b2, mu2, var2, wdF, bn2p);
    k_wab <<<3, 256, 0, stream>>>(wa, wb, wawbF);
    k_attn<<<dim3(NCHUNK, Nn), 256, 0, stream>>>(xbT, wawbF, ba, bb, part);
    k_adj <<<(Nn*SVV + 255)/256, 256, 0, stream>>>(part, PA, alpha, adjw);
    k_adjF<<<48, 256, 0, stream>>>(adjw, adjF);
    k_y0  <<<dim3(Tt/4, Nn), 256, 0, stream>>>(xbT, adjF, wdF, bn2p, y0);
    k_M1  <<<dim3(Cc, Nn), 256, 0, stream>>>(y0, M1);
    k_s1  <<<(Nn*Vv + 255)/256, 256, 0, stream>>>(M1, w_sa, b_sa, s1);
    k_M2  <<<dim3(Tt/256, Nn*Cc), 256, 0, stream>>>(y0, s1, M2);
    k_s2  <<<Nn, 512, 0, stream>>>(M2, w_ta, b_ta, s2);
    k_s3  <<<Nn, 64, 0, stream>>>(M2, s2, w_fc1, b_fc1, w_fc2, b_fc2, s3);
    k_final<<<dim3(Cc, Nn), 256, 0, stream>>>(y0, s1, s2, s3);
}

// Round 8
// 205.836 us; speedup vs baseline: 4.9851x; 1.7471x over previous
//
#include <hip/hip_runtime.h>
#include <hip/hip_bf16.h>
#include <math.h>

// AAGCN block, N=32 C=64 T=512 V=21 E=16 S=3.
// Round 8: de-serialize the SE kernels. k_s1/k_s2 restructured as LDS-staged
// parallel-reduce (old versions were 8-VGPR latency chains, k_s1 = 113us!).
// k_s3 split into k_sec (coalesced strided dot, 2048 blocks) + k_s3fc (tiny FC).

#define Nn 32
#define Cc 64
#define Tt 512
#define Vv 21
#define VP 24
#define Ss 3
#define EPSf 1e-5f
#define NCHUNK 16
#define SVV (Ss*Vv*Vv)   // 1323
#define KSTR 136         // m-buf k-stride (16B-aligned rows, conflict-spread)

typedef __attribute__((ext_vector_type(8))) short short8;
typedef __attribute__((ext_vector_type(4))) float f32x4;

__device__ __forceinline__ float sigm(float x){ return 1.f/(1.f+expf(-x)); }
__device__ __forceinline__ float bf2f(unsigned short u){ return __uint_as_float((unsigned)u << 16); }
__device__ __forceinline__ unsigned short f2bf(float f){
    __hip_bfloat16 h = __float2bfloat16(f);
    return *reinterpret_cast<unsigned short*>(&h);
}

// ---------------- materialize xbT (BN1 + raw-reshape shuffle), bf16 ----------------
__global__ __launch_bounds__(256) void k_xb(
    const float* __restrict__ x,
    const float* __restrict__ g1, const float* __restrict__ b1,
    const float* __restrict__ mu1, const float* __restrict__ var1,
    unsigned short* __restrict__ xbT)
{
    const int c0 = blockIdx.x;
    const int n  = blockIdx.y;
    const int tid = threadIdx.x;
    __shared__ float brick[512*24];                 // [t][24]
    __shared__ float pscT[64*25], pmuT[64*25], pbeT[64*25];  // [a][25]
    const float* xs = x + (size_t)(n*64 + c0)*10752;
    for (int i = tid; i < 10752; i += 256)
        brick[(i/21)*24 + (i%21)] = xs[i];
    for (int i = tid; i < 1344; i += 256){
        int a = i & 63, v = i >> 6;
        pscT[a*25+v] = g1[i]*rsqrtf(var1[i]+EPSf);
        pmuT[a*25+v] = mu1[i];
        pbeT[a*25+v] = b1[i];
    }
    __syncthreads();
    #pragma unroll
    for (int ii = 0; ii < 6; ++ii){
        int i = tid + ii*256;
        int vp = i % 24;
        int m  = (i / 24) % 8;
        int ag = i / 192;              // a-oct (wave-uniform)
        unsigned short pk[8];
        #pragma unroll
        for (int da = 0; da < 8; ++da){
            int a = ag*8 + da;
            float val = 0.f;
            if (vp < 21){
                float xv = brick[(a*8 + m)*24 + vp];
                val = (xv - pmuT[a*25+vp])*pscT[a*25+vp] + pbeT[a*25+vp];
            }
            pk[da] = f2bf(val);
        }
        *reinterpret_cast<uint4*>(xbT + ((size_t)((n*512 + c0 + 64*m)*24 + vp))*64 + ag*8) =
            *reinterpret_cast<const uint4*>(pk);
    }
}

// ---------------- pack wd into MFMA A-fragment layout + BN2 params ----------------
__global__ __launch_bounds__(256) void k_wdT(
    const float* __restrict__ wd, const float* __restrict__ bd,
    const float* __restrict__ g2, const float* __restrict__ b2,
    const float* __restrict__ mu2, const float* __restrict__ var2,
    unsigned short* __restrict__ wdF, float4* __restrict__ bn2p)
{
    int i = blockIdx.x*256 + threadIdx.x;
    if (i < 1536){
        int s  = i / 512;
        int w  = (i >> 7) & 3;
        int ks = (i >> 6) & 1;
        int l  = i & 63;
        int o  = 16*w + (l & 15);
        #pragma unroll
        for (int j = 0; j < 8; ++j){
            int c = 32*ks + 8*(l >> 4) + j;
            wdF[(size_t)i*8 + j] = f2bf(wd[(s*64 + o)*64 + c]);
        }
    }
    if (i < 64){
        float bsum = bd[i] + bd[64+i] + bd[128+i];
        float sc = g2[i]*rsqrtf(var2[i]+EPSf);
        bn2p[i] = make_float4(bsum, sc, mu2[i], b2[i]);
    }
}

// ---------------- pack [wa;wb] into MFMA A-fragment layout (96 x 64) ----------------
__global__ __launch_bounds__(256) void k_wab(
    const float* __restrict__ wa, const float* __restrict__ wb,
    unsigned short* __restrict__ wawbF)
{
    int i = blockIdx.x*256 + threadIdx.x;
    if (i >= 768) return;
    int mt = i / 128;
    int ks = (i / 64) & 1;
    int l  = i & 63;
    int e  = l & 15;
    int g  = l >> 4;
    const float* src = (mt < 3) ? wa : wb;
    int s = (mt < 3) ? mt : mt - 3;
    #pragma unroll
    for (int j = 0; j < 8; ++j){
        int c = ks*32 + 8*g + j;
        wawbF[(size_t)i*8 + j] = f2bf(src[(s*16 + e)*64 + c]);
    }
}

// ---------------- attention pre-activation partials (MFMA) ----------------
__global__ __launch_bounds__(256) void k_attn(
    const unsigned short* __restrict__ xbT,
    const unsigned short* __restrict__ wawbF,
    const float* __restrict__ ba, const float* __restrict__ bb,
    float* __restrict__ part)
{
    const int chunk = blockIdx.x;
    const int n = blockIdx.y;
    const int tid = threadIdx.x;
    const int w  = tid >> 6;
    const int l  = tid & 63;
    const int g  = l >> 4;
    const int ln = l & 15;

    __shared__ unsigned short m1buf[3*32*KSTR];
    __shared__ unsigned short m2buf[3*32*KSTR];

    for (int i = tid; i < 3*8*KSTR; i += 256){
        int s = i / (8*KSTR), r = i % (8*KSTR);
        int off = (s*32 + 24)*KSTR + r;
        m1buf[off] = 0; m2buf[off] = 0;
    }

    short8 aF[6][2];
    float4 bias4[6];
    #pragma unroll
    for (int mt = 0; mt < 6; ++mt){
        #pragma unroll
        for (int ks = 0; ks < 2; ++ks)
            aF[mt][ks] = *reinterpret_cast<const short8*>(wawbF + (size_t)((mt*2+ks)*64 + l)*8);
        const float* bsrc = (mt < 3) ? (ba + mt*16) : (bb + (mt-3)*16);
        bias4[mt] = *reinterpret_cast<const float4*>(bsrc + 4*g);
    }

    f32x4 accB[3];
    #pragma unroll
    for (int q = 0; q < 3; ++q) accB[q] = (f32x4){0.f,0.f,0.f,0.f};

    int colv[3], colt[3];
    #pragma unroll
    for (int q = 0; q < 3; ++q){
        int col = (3*w + q)*16 + ln;
        colt[q] = col / 24;
        colv[q] = col % 24;
    }

    for (int st = 0; st < 4; ++st){
        const int tb = chunk*32 + st*8;
        #pragma unroll
        for (int q = 0; q < 3; ++q){
            const unsigned short* bp = xbT + ((size_t)(n*512 + tb + colt[q])*24 + colv[q])*64;
            short8 b0 = *reinterpret_cast<const short8*>(bp + 8*g);
            short8 b1 = *reinterpret_cast<const short8*>(bp + 32 + 8*g);
            #pragma unroll
            for (int mt = 0; mt < 6; ++mt){
                f32x4 c;
                c[0] = bias4[mt].x; c[1] = bias4[mt].y;
                c[2] = bias4[mt].z; c[3] = bias4[mt].w;
                c = __builtin_amdgcn_mfma_f32_16x16x32_bf16(aF[mt][0], b0, c, 0, 0, 0);
                c = __builtin_amdgcn_mfma_f32_16x16x32_bf16(aF[mt][1], b1, c, 0, 0, 0);
                unsigned short* dst = (mt < 3) ? m1buf : m2buf;
                int s = (mt < 3) ? mt : mt - 3;
                unsigned u0 = (unsigned)f2bf(c[0]) | ((unsigned)f2bf(c[1]) << 16);
                unsigned u1 = (unsigned)f2bf(c[2]) | ((unsigned)f2bf(c[3]) << 16);
                int off = (s*32 + colv[q])*KSTR + colt[q]*16 + 4*g;
                *reinterpret_cast<uint2*>(dst + off) = make_uint2(u0, u1);
            }
        }
        __syncthreads();
        #pragma unroll
        for (int q = 0; q < 3; ++q){
            int ct = 3*w + q;
            int s = ct >> 2, mtile = (ct >> 1) & 1, ntile = ct & 1;
            #pragma unroll
            for (int kk = 0; kk < 4; ++kk){
                short8 a = *reinterpret_cast<const short8*>(&m1buf[(s*32 + mtile*16 + ln)*KSTR + kk*32 + 8*g]);
                short8 b = *reinterpret_cast<const short8*>(&m2buf[(s*32 + ntile*16 + ln)*KSTR + kk*32 + 8*g]);
                accB[q] = __builtin_amdgcn_mfma_f32_16x16x32_bf16(a, b, accB[q], 0, 0, 0);
            }
        }
        __syncthreads();
    }

    float* pout = part + (size_t)(n*NCHUNK + chunk)*SVV;
    #pragma unroll
    for (int q = 0; q < 3; ++q){
        int ct = 3*w + q;
        int s = ct >> 2, mtile = (ct >> 1) & 1, ntile = ct & 1;
        int v = ntile*16 + ln;
        #pragma unroll
        for (int r = 0; r < 4; ++r){
            int u = mtile*16 + 4*g + r;
            if (u < 21 && v < 21)
                pout[s*441 + u*21 + v] = accB[q][r];
        }
    }
}

// ---------------- adj = PA + tanh(pre/8192)*alpha ----------------
__global__ void k_adj(const float* __restrict__ part, const float* __restrict__ PA,
                      const float* __restrict__ alpha, float* __restrict__ adj)
{
    int i = blockIdx.x*256 + threadIdx.x;
    if (i >= Nn*SVV) return;
    int n = i / SVV;
    int idx = i % SVV;
    float pre = 0.f;
    for (int ch = 0; ch < NCHUNK; ++ch)
        pre += part[(size_t)(n*NCHUNK+ch)*SVV + idx];
    adj[i] = PA[idx] + tanhf(pre * (1.f/8192.f)) * alpha[0];
}

// ---------------- pack adj into MFMA B-fragment layout (bf16) ----------------
__global__ __launch_bounds__(256) void k_adjF(const float* __restrict__ adj,
                                              unsigned short* __restrict__ adjF)
{
    int i = blockIdx.x*256 + threadIdx.x;
    if (i >= Nn*Ss*2*64) return;
    int n = i / 384;
    int r = i % 384;
    int s = r / 128;
    int r2 = r % 128;
    int h = r2 >> 6;
    int l = r2 & 63;
    int v = 16*h + (l & 15);
    #pragma unroll
    for (int j = 0; j < 8; ++j){
        int u = 8*(l >> 4) + j;
        float val = (u < 21 && v < 21) ? adj[(size_t)n*SVV + s*441 + u*21 + v] : 0.f;
        adjF[(size_t)i*8 + j] = f2bf(val);
    }
}

// ---------------- graph conv + wd + BN2 + residual + relu (MFMA) ----------------
__global__ __launch_bounds__(256) void k_y0(
    const unsigned short* __restrict__ xbT,
    const unsigned short* __restrict__ adjF,
    const unsigned short* __restrict__ wdF,
    const float4* __restrict__ bn2p,
    float* __restrict__ y0)
{
    const int n  = blockIdx.y;
    const int t0 = blockIdx.x * 4;
    const int tid = threadIdx.x;
    const int w  = tid >> 6;
    const int l  = tid & 63;
    const int g  = l >> 4;
    const int ln = l & 15;

    __shared__ unsigned short xbuf[64*136];   // [c][4t x 32u], row stride 272B
    __shared__ unsigned short zbuf[128*72];   // [col][64c], col stride 144B

    {
        int c = tid >> 2, t = tid & 3;
        *reinterpret_cast<uint4*>(&xbuf[c*136 + t*32 + 24]) = make_uint4(0u,0u,0u,0u);
    }
    for (int k = 0; k < 3; ++k){
        int i = tid + k*256;                  // 768 = 8cg x 4t x 24u
        int u = i % 24, t = (i/24) & 3, cg = i / 96;
        uint4 d = *reinterpret_cast<const uint4*>(
            xbT + ((size_t)(n*512 + t0 + t)*24 + u)*64 + cg*8);
        const unsigned short* p = reinterpret_cast<const unsigned short*>(&d);
        #pragma unroll
        for (int dc = 0; dc < 8; ++dc)
            xbuf[(cg*8 + dc)*136 + t*32 + u] = p[dc];
    }
    __syncthreads();

    short8 ax[4];
    #pragma unroll
    for (int t = 0; t < 4; ++t)
        ax[t] = *reinterpret_cast<const short8*>(&xbuf[(16*w + ln)*136 + t*32 + 8*g]);

    short8 badj[3][2];
    {
        const unsigned short* ap = adjF + (size_t)n*Ss*2*64*8;
        #pragma unroll
        for (int s = 0; s < 3; ++s)
            #pragma unroll
            for (int h = 0; h < 2; ++h)
                badj[s][h] = *reinterpret_cast<const short8*>(ap + ((s*2 + h)*64 + l)*8);
    }

    f32x4 acc[8];
    #pragma unroll
    for (int ct = 0; ct < 8; ++ct) acc[ct] = (f32x4){0.f,0.f,0.f,0.f};

    for (int s = 0; s < 3; ++s){
        if (s) __syncthreads();
        f32x4 dz[8];
        #pragma unroll
        for (int ct = 0; ct < 8; ++ct)
            dz[ct] = __builtin_amdgcn_mfma_f32_16x16x32_bf16(
                         ax[ct>>1], badj[s][ct&1], (f32x4){0.f,0.f,0.f,0.f}, 0, 0, 0);
        #pragma unroll
        for (int ct = 0; ct < 8; ++ct){
            unsigned u0 = (unsigned)f2bf(dz[ct][0]) | ((unsigned)f2bf(dz[ct][1]) << 16);
            unsigned u1 = (unsigned)f2bf(dz[ct][2]) | ((unsigned)f2bf(dz[ct][3]) << 16);
            int col = (ct >> 1)*32 + (ct & 1)*16 + ln;
            *reinterpret_cast<uint2*>(&zbuf[col*72 + 16*w + 4*g]) = make_uint2(u0, u1);
        }
        __syncthreads();
        short8 aw0 = *reinterpret_cast<const short8*>(wdF + (size_t)(((s*4 + w)*2 + 0)*64 + l)*8);
        short8 aw1 = *reinterpret_cast<const short8*>(wdF + (size_t)(((s*4 + w)*2 + 1)*64 + l)*8);
        #pragma unroll
        for (int ct = 0; ct < 8; ++ct){
            int col = (ct >> 1)*32 + (ct & 1)*16 + ln;
            short8 b0 = *reinterpret_cast<const short8*>(&zbuf[col*72 + 0  + 8*g]);
            short8 b1 = *reinterpret_cast<const short8*>(&zbuf[col*72 + 32 + 8*g]);
            acc[ct] = __builtin_amdgcn_mfma_f32_16x16x32_bf16(aw0, b0, acc[ct], 0, 0, 0);
            acc[ct] = __builtin_amdgcn_mfma_f32_16x16x32_bf16(aw1, b1, acc[ct], 0, 0, 0);
        }
    }

    float4 bp[4];
    #pragma unroll
    for (int r = 0; r < 4; ++r) bp[r] = bn2p[16*w + 4*g + r];
    #pragma unroll
    for (int ct = 0; ct < 8; ++ct){
        const int t  = ct >> 1;
        const int vp = (ct & 1)*16 + ln;
        if (vp < 21){
            #pragma unroll
            for (int r = 0; r < 4; ++r){
                const int o = 16*w + 4*g + r;
                float val = acc[ct][r] + bp[r].x;
                val = (val - bp[r].z)*bp[r].y + bp[r].w;
                val += bf2f(xbuf[o*136 + t*32 + vp]);
                y0[((size_t)(n*64 + o)*512 + t0 + t)*21 + vp] = fmaxf(val, 0.f);
            }
        }
    }
}

// ---------------- M1[n,c,v] = sum_t y0 ----------------
__global__ __launch_bounds__(256) void k_M1(const float* __restrict__ y0, float* __restrict__ M1)
{
    const int c = blockIdx.x, n = blockIdx.y, tid = threadIdx.x;
    float a[21];
    #pragma unroll
    for (int v = 0; v < 21; ++v) a[v] = 0.f;
    for (int t = tid; t < Tt; t += 256){
        const float* p = &y0[ ((size_t)(n*Cc+c)*Tt + t)*Vv ];
        #pragma unroll
        for (int v = 0; v < 21; ++v) a[v] += p[v];
    }
    __shared__ float red[256][21];
    #pragma unroll
    for (int v = 0; v < 21; ++v) red[tid][v] = a[v];
    __syncthreads();
    for (int off = 128; off > 0; off >>= 1){
        if (tid < off){
            #pragma unroll
            for (int v = 0; v < 21; ++v) red[tid][v] += red[tid+off][v];
        }
        __syncthreads();
    }
    if (tid < 21) M1[(size_t)(n*Cc+c)*Vv + tid] = red[0][tid];
}

// ---------------- s1[n,v] = 1 + sigmoid(conv21(M1/T)) — LDS-parallel ----------------
// block per n, 256 threads: (v = tid%21, cg = tid/21 of 12); reduce over cg.
__global__ __launch_bounds__(256) void k_s1(const float* __restrict__ M1, const float* __restrict__ w_sa,
                     const float* __restrict__ b_sa, float* __restrict__ s1)
{
    const int n = blockIdx.x, tid = threadIdx.x;
    __shared__ float m1s[64][22];
    __shared__ float ws[64][22];
    __shared__ float red[12][21];
    for (int i = tid; i < 1344; i += 256){
        int c = i / 21, v = i % 21;
        m1s[c][v] = M1[(size_t)(n*64+c)*21 + v];
        ws[c][v]  = w_sa[i];
    }
    __syncthreads();
    const int v = tid % 21;
    const int cg = tid / 21;       // 0..11 valid
    float sum = 0.f;
    if (tid < 252){
        for (int c = cg; c < 64; c += 12){
            #pragma unroll
            for (int k = 0; k < 21; ++k){
                int src = v + k - 10;
                if (src >= 0 && src < 21)
                    sum += m1s[c][src] * ws[c][k];
            }
        }
        red[cg][v] = sum;
    }
    __syncthreads();
    if (tid < 21){
        float tot = b_sa[0];
        #pragma unroll
        for (int g = 0; g < 12; ++g) tot += red[g][tid] * (1.f/512.f);
        s1[n*Vv + tid] = 1.f + sigm(tot);
    }
}

// ---------------- M2[n,c,t] = sum_v y0*s1 ----------------
__global__ __launch_bounds__(256) void k_M2(const float* __restrict__ y0, const float* __restrict__ s1,
                      float* __restrict__ M2)
{
    int t = blockIdx.x*256 + threadIdx.x;
    int nc = blockIdx.y;
    int n = nc >> 6;
    __shared__ float s1s[21];
    if (threadIdx.x < 21) s1s[threadIdx.x] = s1[n*Vv + threadIdx.x];
    __syncthreads();
    const float* p = &y0[ ((size_t)nc*Tt + t)*Vv ];
    float sum = 0.f;
    #pragma unroll
    for (int v = 0; v < 21; ++v) sum += p[v]*s1s[v];
    M2[(size_t)nc*Tt + t] = sum;
}

// ---------------- s2[n,t] = 1 + sigmoid(conv9(M2/V)) — LDS-staged tiles ----------------
// grid (8, n): block handles 64 t's; stage M2[n][64c][t0-4..t0+67] + w_ta in LDS.
__global__ __launch_bounds__(256) void k_s2(const float* __restrict__ M2, const float* __restrict__ w_ta,
                      const float* __restrict__ b_ta, float* __restrict__ s2)
{
    const int n = blockIdx.y;
    const int t0 = blockIdx.x * 64;
    const int tid = threadIdx.x;
    __shared__ float m2s[64][72];
    __shared__ float wts[576];
    __shared__ float red[4][64];
    for (int i = tid; i < 64*72; i += 256){
        int c = i / 72, tt = i % 72;
        int src = t0 + tt - 4;
        m2s[c][tt] = (src >= 0 && src < 512) ? M2[(size_t)(n*64+c)*512 + src] : 0.f;
    }
    for (int i = tid; i < 576; i += 256) wts[i] = w_ta[i];
    __syncthreads();
    const int tl = tid & 63;
    const int cg = tid >> 6;
    float sum = 0.f;
    for (int c = cg*16; c < cg*16+16; ++c){
        #pragma unroll
        for (int k = 0; k < 9; ++k)
            sum += m2s[c][tl + k] * wts[c*9 + k];
    }
    red[cg][tl] = sum;
    __syncthreads();
    if (cg == 0){
        float tot = b_ta[0] + (red[0][tl]+red[1][tl]+red[2][tl]+red[3][tl]) * (1.f/21.f);
        s2[n*512 + t0 + tl] = 1.f + sigm(tot);
    }
}

// ---------------- sec[n,c] = (sum_t M2*s2)/(T*V) — coalesced + reduce ----------------
__global__ __launch_bounds__(256) void k_sec(const float* __restrict__ M2, const float* __restrict__ s2,
                      float* __restrict__ sec)
{
    const int c = blockIdx.x, n = blockIdx.y, tid = threadIdx.x;
    const float* row = &M2[(size_t)(n*Cc+c)*Tt];
    const float* s2r = &s2[n*Tt];
    float acc = row[tid]*s2r[tid] + row[tid+256]*s2r[tid+256];
    #pragma unroll
    for (int off = 32; off > 0; off >>= 1)
        acc += __shfl_down(acc, off, 64);
    __shared__ float red[4];
    if ((tid & 63) == 0) red[tid >> 6] = acc;
    __syncthreads();
    if (tid == 0)
        sec[n*Cc + c] = (red[0]+red[1]+red[2]+red[3]) * (1.f/(512.f*21.f));
}

// ---------------- s3[n,c]: tiny FC from sec ----------------
__global__ __launch_bounds__(64) void k_s3fc(const float* __restrict__ sec,
                     const float* __restrict__ w1, const float* __restrict__ bf1,
                     const float* __restrict__ w2, const float* __restrict__ bf2,
                     float* __restrict__ s3)
{
    int n = blockIdx.x, c = threadIdx.x;
    __shared__ float secs[64];
    __shared__ float hh[32];
    secs[c] = sec[n*Cc + c];
    __syncthreads();
    if (c < 32){
        float h = bf1[c];
        #pragma unroll 8
        for (int k = 0; k < 64; ++k) h += w1[c*64+k]*secs[k];
        hh[c] = fmaxf(h, 0.f);
    }
    __syncthreads();
    float o = bf2[c];
    #pragma unroll 8
    for (int k = 0; k < 32; ++k) o += w2[c*32+k]*hh[k];
    s3[n*Cc + c] = 1.f + sigm(o);
}

// ---------------- final in-place: relu(y0*s1*s2*s3), per (n,c) row ----------------
__global__ __launch_bounds__(256) void k_final(float* __restrict__ y,
    const float* __restrict__ s1, const float* __restrict__ s2, const float* __restrict__ s3)
{
    const int c = blockIdx.x, n = blockIdx.y, tid = threadIdx.x;
    __shared__ float s1s[21];
    if (tid < 21) s1s[tid] = s1[n*Vv + tid];
    __syncthreads();
    const float sc3 = s3[n*Cc + c];
    float* base = y + (size_t)(n*Cc + c)*Tt*Vv;
    const float* s2r = s2 + n*Tt;
    for (int t = tid; t < Tt; t += 256){
        const float f = s2r[t] * sc3;
        float* p = base + (size_t)t*Vv;
        #pragma unroll
        for (int v = 0; v < 21; ++v)
            p[v] = fmaxf(p[v] * s1s[v] * f, 0.f);
    }
}

extern "C" void kernel_launch(void* const* d_in, const int* in_sizes, int n_in,
                              void* d_out, int out_size, void* d_ws, size_t ws_size,
                              hipStream_t stream)
{
    const float* x    = (const float*)d_in[0];
    const float* g1   = (const float*)d_in[2];
    const float* b1   = (const float*)d_in[3];
    const float* mu1  = (const float*)d_in[4];
    const float* var1 = (const float*)d_in[5];
    const float* PA   = (const float*)d_in[6];
    const float* alpha= (const float*)d_in[7];
    const float* wa   = (const float*)d_in[8];
    const float* ba   = (const float*)d_in[9];
    const float* wb   = (const float*)d_in[10];
    const float* bb   = (const float*)d_in[11];
    const float* wd   = (const float*)d_in[12];
    const float* bd   = (const float*)d_in[13];
    const float* g2   = (const float*)d_in[14];
    const float* b2   = (const float*)d_in[15];
    const float* mu2  = (const float*)d_in[16];
    const float* var2 = (const float*)d_in[17];
    const float* w_sa = (const float*)d_in[18];
    const float* b_sa = (const float*)d_in[19];
    const float* w_ta = (const float*)d_in[20];
    const float* b_ta = (const float*)d_in[21];
    const float* w_fc1= (const float*)d_in[22];
    const float* b_fc1= (const float*)d_in[23];
    const float* w_fc2= (const float*)d_in[24];
    const float* b_fc2= (const float*)d_in[25];

    // ws: xbT bf16 [32][512][24][64] = 25,165,824 elems (50.33 MB), then scratch
    unsigned short* xbT = (unsigned short*)d_ws;
    float* fws  = (float*)d_ws + 12582912;
    float* part = fws;                   // 677376
    float* adjw = part + 677376;         // 42336
    float* M1   = adjw + 42336;          // 43008
    float* s1   = M1   + 43008;          // 672
    float* M2   = s1   + 672;            // 1048576
    float* s2   = M2   + 1048576;        // 16384
    float* s3   = s2   + 16384;          // 2048
    float4* bn2p = (float4*)(s3 + 2048); // 256 f32
    unsigned short* wdF   = (unsigned short*)((float*)bn2p + 256);   // 12288 u16
    unsigned short* adjF  = wdF + 12288;                             // 98304 u16
    unsigned short* wawbF = adjF + 98304;                            // 6144 u16
    float* sec  = (float*)(wawbF + 6144);                            // 2048 f32
    float* y0   = (float*)d_out;

    k_xb  <<<dim3(64, Nn), 256, 0, stream>>>(x, g1,b1,mu1,var1, xbT);
    k_wdT <<<6, 256, 0, stream>>>(wd, bd, g2, b2, mu2, var2, wdF, bn2p);
    k_wab <<<3, 256, 0, stream>>>(wa, wb, wawbF);
    k_attn<<<dim3(NCHUNK, Nn), 256, 0, stream>>>(xbT, wawbF, ba, bb, part);
    k_adj <<<(Nn*SVV + 255)/256, 256, 0, stream>>>(part, PA, alpha, adjw);
    k_adjF<<<48, 256, 0, stream>>>(adjw, adjF);
    k_y0  <<<dim3(Tt/4, Nn), 256, 0, stream>>>(xbT, adjF, wdF, bn2p, y0);
    k_M1  <<<dim3(Cc, Nn), 256, 0, stream>>>(y0, M1);
    k_s1  <<<Nn, 256, 0, stream>>>(M1, w_sa, b_sa, s1);
    k_M2  <<<dim3(Tt/256, Nn*Cc), 256, 0, stream>>>(y0, s1, M2);
    k_s2  <<<dim3(8, Nn), 256, 0, stream>>>(M2, w_ta, b_ta, s2);
    k_sec <<<dim3(Cc, Nn), 256, 0, stream>>>(M2, s2, sec);
    k_s3fc<<<Nn, 64, 0, stream>>>(sec, w_fc1, b_fc1, w_fc2, b_fc2, s3);
    k_final<<<dim3(Cc, Nn), 256, 0, stream>>>(y0, s1, s2, s3);
}

// Round 9
// 199.172 us; speedup vs baseline: 5.1518x; 1.0335x over previous
//
#include <hip/hip_runtime.h>
#include <hip/hip_bf16.h>
#include <math.h>

// AAGCN block, N=32 C=64 T=512 V=21 E=16 S=3.
// Round 9: k_xb occupancy+vectorization rewrite (split a-halves: 31KB LDS ->
// 5 blocks/CU, float4 global loads, folded BN params); k_final float4 I/O.

#define Nn 32
#define Cc 64
#define Tt 512
#define Vv 21
#define VP 24
#define Ss 3
#define EPSf 1e-5f
#define NCHUNK 16
#define SVV (Ss*Vv*Vv)   // 1323
#define KSTR 136         // m-buf k-stride (16B-aligned rows, conflict-spread)

typedef __attribute__((ext_vector_type(8))) short short8;
typedef __attribute__((ext_vector_type(4))) float f32x4;

__device__ __forceinline__ float sigm(float x){ return 1.f/(1.f+expf(-x)); }
__device__ __forceinline__ float bf2f(unsigned short u){ return __uint_as_float((unsigned)u << 16); }
__device__ __forceinline__ unsigned short f2bf(float f){
    __hip_bfloat16 h = __float2bfloat16(f);
    return *reinterpret_cast<unsigned short*>(&h);
}

// ---------------- materialize xbT (BN1 + raw-reshape shuffle), bf16 ----------------
// xbT[n][b][vp][a] = BN1(x[n][b&63][a*8+(b>>6)][v]); block = (c0, a-half, n).
__global__ __launch_bounds__(256) void k_xb(
    const float* __restrict__ x,
    const float* __restrict__ g1, const float* __restrict__ b1,
    const float* __restrict__ mu1, const float* __restrict__ var1,
    unsigned short* __restrict__ xbT)
{
    const int c0 = blockIdx.x & 63;
    const int ah = blockIdx.x >> 6;      // a-half: a in [ah*32, ah*32+32)
    const int n  = blockIdx.y;
    const int tid = threadIdx.x;
    __shared__ float brick[256*24];      // [t_local][24]
    __shared__ float2 pps[32*26];        // [a_local][26] = (sc, beta - mu*sc)

    // load x[n][c0][ah*256 .. +256)[*] = 5376 contiguous floats, float4
    const float* xs = x + (size_t)(n*64 + c0)*10752 + ah*5376;
    for (int i = tid; i < 1344; i += 256){
        float4 d = *reinterpret_cast<const float4*>(xs + i*4);
        int f = i*4;
        #pragma unroll
        for (int e = 0; e < 4; ++e){
            int fe = f + e;
            int t = fe / 21;
            int v = fe - t*21;
            brick[t*24 + v] = ((const float*)&d)[e];
        }
    }
    for (int i = tid; i < 768; i += 256){
        int al = i / 24, vp = i % 24;
        float2 p = make_float2(0.f, 0.f);
        if (vp < 21){
            int j = vp*64 + ah*32 + al;
            float sc = g1[j]*rsqrtf(var1[j]+EPSf);
            p.x = sc; p.y = b1[j] - mu1[j]*sc;
        }
        pps[al*26 + vp] = p;
    }
    __syncthreads();

    // compute + store: 6144 u16 out; i -> (vp = i%24, m = (i/24)%8, agl = i/192)
    #pragma unroll
    for (int ii = 0; ii < 3; ++ii){
        int i = tid + ii*256;
        int vp  = i % 24;
        int m   = (i / 24) % 8;
        int agl = i / 192;               // 0..3 (wave-uniform)
        unsigned short pk[8];
        #pragma unroll
        for (int da = 0; da < 8; ++da){
            int al = agl*8 + da;
            float val = 0.f;
            if (vp < 21){
                float xv = brick[(al*8 + m)*24 + vp];
                float2 p = pps[al*26 + vp];
                val = xv*p.x + p.y;
            }
            pk[da] = f2bf(val);
        }
        *reinterpret_cast<uint4*>(
            xbT + ((size_t)((n*512 + c0 + 64*m)*24 + vp))*64 + ah*32 + agl*8) =
            *reinterpret_cast<const uint4*>(pk);
    }
}

// ---------------- pack wd into MFMA A-fragment layout + BN2 params ----------------
__global__ __launch_bounds__(256) void k_wdT(
    const float* __restrict__ wd, const float* __restrict__ bd,
    const float* __restrict__ g2, const float* __restrict__ b2,
    const float* __restrict__ mu2, const float* __restrict__ var2,
    unsigned short* __restrict__ wdF, float4* __restrict__ bn2p)
{
    int i = blockIdx.x*256 + threadIdx.x;
    if (i < 1536){
        int s  = i / 512;
        int w  = (i >> 7) & 3;
        int ks = (i >> 6) & 1;
        int l  = i & 63;
        int o  = 16*w + (l & 15);
        #pragma unroll
        for (int j = 0; j < 8; ++j){
            int c = 32*ks + 8*(l >> 4) + j;
            wdF[(size_t)i*8 + j] = f2bf(wd[(s*64 + o)*64 + c]);
        }
    }
    if (i < 64){
        float bsum = bd[i] + bd[64+i] + bd[128+i];
        float sc = g2[i]*rsqrtf(var2[i]+EPSf);
        bn2p[i] = make_float4(bsum, sc, mu2[i], b2[i]);
    }
}

// ---------------- pack [wa;wb] into MFMA A-fragment layout (96 x 64) ----------------
__global__ __launch_bounds__(256) void k_wab(
    const float* __restrict__ wa, const float* __restrict__ wb,
    unsigned short* __restrict__ wawbF)
{
    int i = blockIdx.x*256 + threadIdx.x;
    if (i >= 768) return;
    int mt = i / 128;
    int ks = (i / 64) & 1;
    int l  = i & 63;
    int e  = l & 15;
    int g  = l >> 4;
    const float* src = (mt < 3) ? wa : wb;
    int s = (mt < 3) ? mt : mt - 3;
    #pragma unroll
    for (int j = 0; j < 8; ++j){
        int c = ks*32 + 8*g + j;
        wawbF[(size_t)i*8 + j] = f2bf(src[(s*16 + e)*64 + c]);
    }
}

// ---------------- attention pre-activation partials (MFMA) ----------------
__global__ __launch_bounds__(256) void k_attn(
    const unsigned short* __restrict__ xbT,
    const unsigned short* __restrict__ wawbF,
    const float* __restrict__ ba, const float* __restrict__ bb,
    float* __restrict__ part)
{
    const int chunk = blockIdx.x;
    const int n = blockIdx.y;
    const int tid = threadIdx.x;
    const int w  = tid >> 6;
    const int l  = tid & 63;
    const int g  = l >> 4;
    const int ln = l & 15;

    __shared__ unsigned short m1buf[3*32*KSTR];
    __shared__ unsigned short m2buf[3*32*KSTR];

    for (int i = tid; i < 3*8*KSTR; i += 256){
        int s = i / (8*KSTR), r = i % (8*KSTR);
        int off = (s*32 + 24)*KSTR + r;
        m1buf[off] = 0; m2buf[off] = 0;
    }

    short8 aF[6][2];
    float4 bias4[6];
    #pragma unroll
    for (int mt = 0; mt < 6; ++mt){
        #pragma unroll
        for (int ks = 0; ks < 2; ++ks)
            aF[mt][ks] = *reinterpret_cast<const short8*>(wawbF + (size_t)((mt*2+ks)*64 + l)*8);
        const float* bsrc = (mt < 3) ? (ba + mt*16) : (bb + (mt-3)*16);
        bias4[mt] = *reinterpret_cast<const float4*>(bsrc + 4*g);
    }

    f32x4 accB[3];
    #pragma unroll
    for (int q = 0; q < 3; ++q) accB[q] = (f32x4){0.f,0.f,0.f,0.f};

    int colv[3], colt[3];
    #pragma unroll
    for (int q = 0; q < 3; ++q){
        int col = (3*w + q)*16 + ln;
        colt[q] = col / 24;
        colv[q] = col % 24;
    }

    for (int st = 0; st < 4; ++st){
        const int tb = chunk*32 + st*8;
        #pragma unroll
        for (int q = 0; q < 3; ++q){
            const unsigned short* bp = xbT + ((size_t)(n*512 + tb + colt[q])*24 + colv[q])*64;
            short8 b0 = *reinterpret_cast<const short8*>(bp + 8*g);
            short8 b1 = *reinterpret_cast<const short8*>(bp + 32 + 8*g);
            #pragma unroll
            for (int mt = 0; mt < 6; ++mt){
                f32x4 c;
                c[0] = bias4[mt].x; c[1] = bias4[mt].y;
                c[2] = bias4[mt].z; c[3] = bias4[mt].w;
                c = __builtin_amdgcn_mfma_f32_16x16x32_bf16(aF[mt][0], b0, c, 0, 0, 0);
                c = __builtin_amdgcn_mfma_f32_16x16x32_bf16(aF[mt][1], b1, c, 0, 0, 0);
                unsigned short* dst = (mt < 3) ? m1buf : m2buf;
                int s = (mt < 3) ? mt : mt - 3;
                unsigned u0 = (unsigned)f2bf(c[0]) | ((unsigned)f2bf(c[1]) << 16);
                unsigned u1 = (unsigned)f2bf(c[2]) | ((unsigned)f2bf(c[3]) << 16);
                int off = (s*32 + colv[q])*KSTR + colt[q]*16 + 4*g;
                *reinterpret_cast<uint2*>(dst + off) = make_uint2(u0, u1);
            }
        }
        __syncthreads();
        #pragma unroll
        for (int q = 0; q < 3; ++q){
            int ct = 3*w + q;
            int s = ct >> 2, mtile = (ct >> 1) & 1, ntile = ct & 1;
            #pragma unroll
            for (int kk = 0; kk < 4; ++kk){
                short8 a = *reinterpret_cast<const short8*>(&m1buf[(s*32 + mtile*16 + ln)*KSTR + kk*32 + 8*g]);
                short8 b = *reinterpret_cast<const short8*>(&m2buf[(s*32 + ntile*16 + ln)*KSTR + kk*32 + 8*g]);
                accB[q] = __builtin_amdgcn_mfma_f32_16x16x32_bf16(a, b, accB[q], 0, 0, 0);
            }
        }
        __syncthreads();
    }

    float* pout = part + (size_t)(n*NCHUNK + chunk)*SVV;
    #pragma unroll
    for (int q = 0; q < 3; ++q){
        int ct = 3*w + q;
        int s = ct >> 2, mtile = (ct >> 1) & 1, ntile = ct & 1;
        int v = ntile*16 + ln;
        #pragma unroll
        for (int r = 0; r < 4; ++r){
            int u = mtile*16 + 4*g + r;
            if (u < 21 && v < 21)
                pout[s*441 + u*21 + v] = accB[q][r];
        }
    }
}

// ---------------- adj = PA + tanh(pre/8192)*alpha ----------------
__global__ void k_adj(const float* __restrict__ part, const float* __restrict__ PA,
                      const float* __restrict__ alpha, float* __restrict__ adj)
{
    int i = blockIdx.x*256 + threadIdx.x;
    if (i >= Nn*SVV) return;
    int n = i / SVV;
    int idx = i % SVV;
    float pre = 0.f;
    for (int ch = 0; ch < NCHUNK; ++ch)
        pre += part[(size_t)(n*NCHUNK+ch)*SVV + idx];
    adj[i] = PA[idx] + tanhf(pre * (1.f/8192.f)) * alpha[0];
}

// ---------------- pack adj into MFMA B-fragment layout (bf16) ----------------
__global__ __launch_bounds__(256) void k_adjF(const float* __restrict__ adj,
                                              unsigned short* __restrict__ adjF)
{
    int i = blockIdx.x*256 + threadIdx.x;
    if (i >= Nn*Ss*2*64) return;
    int n = i / 384;
    int r = i % 384;
    int s = r / 128;
    int r2 = r % 128;
    int h = r2 >> 6;
    int l = r2 & 63;
    int v = 16*h + (l & 15);
    #pragma unroll
    for (int j = 0; j < 8; ++j){
        int u = 8*(l >> 4) + j;
        float val = (u < 21 && v < 21) ? adj[(size_t)n*SVV + s*441 + u*21 + v] : 0.f;
        adjF[(size_t)i*8 + j] = f2bf(val);
    }
}

// ---------------- graph conv + wd + BN2 + residual + relu (MFMA) ----------------
__global__ __launch_bounds__(256) void k_y0(
    const unsigned short* __restrict__ xbT,
    const unsigned short* __restrict__ adjF,
    const unsigned short* __restrict__ wdF,
    const float4* __restrict__ bn2p,
    float* __restrict__ y0)
{
    const int n  = blockIdx.y;
    const int t0 = blockIdx.x * 4;
    const int tid = threadIdx.x;
    const int w  = tid >> 6;
    const int l  = tid & 63;
    const int g  = l >> 4;
    const int ln = l & 15;

    __shared__ unsigned short xbuf[64*136];   // [c][4t x 32u], row stride 272B
    __shared__ unsigned short zbuf[128*72];   // [col][64c], col stride 144B

    {
        int c = tid >> 2, t = tid & 3;
        *reinterpret_cast<uint4*>(&xbuf[c*136 + t*32 + 24]) = make_uint4(0u,0u,0u,0u);
    }
    for (int k = 0; k < 3; ++k){
        int i = tid + k*256;                  // 768 = 8cg x 4t x 24u
        int u = i % 24, t = (i/24) & 3, cg = i / 96;
        uint4 d = *reinterpret_cast<const uint4*>(
            xbT + ((size_t)(n*512 + t0 + t)*24 + u)*64 + cg*8);
        const unsigned short* p = reinterpret_cast<const unsigned short*>(&d);
        #pragma unroll
        for (int dc = 0; dc < 8; ++dc)
            xbuf[(cg*8 + dc)*136 + t*32 + u] = p[dc];
    }
    __syncthreads();

    short8 ax[4];
    #pragma unroll
    for (int t = 0; t < 4; ++t)
        ax[t] = *reinterpret_cast<const short8*>(&xbuf[(16*w + ln)*136 + t*32 + 8*g]);

    short8 badj[3][2];
    {
        const unsigned short* ap = adjF + (size_t)n*Ss*2*64*8;
        #pragma unroll
        for (int s = 0; s < 3; ++s)
            #pragma unroll
            for (int h = 0; h < 2; ++h)
                badj[s][h] = *reinterpret_cast<const short8*>(ap + ((s*2 + h)*64 + l)*8);
    }

    f32x4 acc[8];
    #pragma unroll
    for (int ct = 0; ct < 8; ++ct) acc[ct] = (f32x4){0.f,0.f,0.f,0.f};

    for (int s = 0; s < 3; ++s){
        if (s) __syncthreads();
        f32x4 dz[8];
        #pragma unroll
        for (int ct = 0; ct < 8; ++ct)
            dz[ct] = __builtin_amdgcn_mfma_f32_16x16x32_bf16(
                         ax[ct>>1], badj[s][ct&1], (f32x4){0.f,0.f,0.f,0.f}, 0, 0, 0);
        #pragma unroll
        for (int ct = 0; ct < 8; ++ct){
            unsigned u0 = (unsigned)f2bf(dz[ct][0]) | ((unsigned)f2bf(dz[ct][1]) << 16);
            unsigned u1 = (unsigned)f2bf(dz[ct][2]) | ((unsigned)f2bf(dz[ct][3]) << 16);
            int col = (ct >> 1)*32 + (ct & 1)*16 + ln;
            *reinterpret_cast<uint2*>(&zbuf[col*72 + 16*w + 4*g]) = make_uint2(u0, u1);
        }
        __syncthreads();
        short8 aw0 = *reinterpret_cast<const short8*>(wdF + (size_t)(((s*4 + w)*2 + 0)*64 + l)*8);
        short8 aw1 = *reinterpret_cast<const short8*>(wdF + (size_t)(((s*4 + w)*2 + 1)*64 + l)*8);
        #pragma unroll
        for (int ct = 0; ct < 8; ++ct){
            int col = (ct >> 1)*32 + (ct & 1)*16 + ln;
            short8 b0 = *reinterpret_cast<const short8*>(&zbuf[col*72 + 0  + 8*g]);
            short8 b1 = *reinterpret_cast<const short8*>(&zbuf[col*72 + 32 + 8*g]);
            acc[ct] = __builtin_amdgcn_mfma_f32_16x16x32_bf16(aw0, b0, acc[ct], 0, 0, 0);
            acc[ct] = __builtin_amdgcn_mfma_f32_16x16x32_bf16(aw1, b1, acc[ct], 0, 0, 0);
        }
    }

    float4 bp[4];
    #pragma unroll
    for (int r = 0; r < 4; ++r) bp[r] = bn2p[16*w + 4*g + r];
    #pragma unroll
    for (int ct = 0; ct < 8; ++ct){
        const int t  = ct >> 1;
        const int vp = (ct & 1)*16 + ln;
        if (vp < 21){
            #pragma unroll
            for (int r = 0; r < 4; ++r){
                const int o = 16*w + 4*g + r;
                float val = acc[ct][r] + bp[r].x;
                val = (val - bp[r].z)*bp[r].y + bp[r].w;
                val += bf2f(xbuf[o*136 + t*32 + vp]);
                y0[((size_t)(n*64 + o)*512 + t0 + t)*21 + vp] = fmaxf(val, 0.f);
            }
        }
    }
}

// ---------------- M1[n,c,v] = sum_t y0 ----------------
__global__ __launch_bounds__(256) void k_M1(const float* __restrict__ y0, float* __restrict__ M1)
{
    const int c = blockIdx.x, n = blockIdx.y, tid = threadIdx.x;
    float a[21];
    #pragma unroll
    for (int v = 0; v < 21; ++v) a[v] = 0.f;
    for (int t = tid; t < Tt; t += 256){
        const float* p = &y0[ ((size_t)(n*Cc+c)*Tt + t)*Vv ];
        #pragma unroll
        for (int v = 0; v < 21; ++v) a[v] += p[v];
    }
    __shared__ float red[256][21];
    #pragma unroll
    for (int v = 0; v < 21; ++v) red[tid][v] = a[v];
    __syncthreads();
    for (int off = 128; off > 0; off >>= 1){
        if (tid < off){
            #pragma unroll
            for (int v = 0; v < 21; ++v) red[tid][v] += red[tid+off][v];
        }
        __syncthreads();
    }
    if (tid < 21) M1[(size_t)(n*Cc+c)*Vv + tid] = red[0][tid];
}

// ---------------- s1[n,v] = 1 + sigmoid(conv21(M1/T)) — LDS-parallel ----------------
__global__ __launch_bounds__(256) void k_s1(const float* __restrict__ M1, const float* __restrict__ w_sa,
                     const float* __restrict__ b_sa, float* __restrict__ s1)
{
    const int n = blockIdx.x, tid = threadIdx.x;
    __shared__ float m1s[64][22];
    __shared__ float ws[64][22];
    __shared__ float red[12][21];
    for (int i = tid; i < 1344; i += 256){
        int c = i / 21, v = i % 21;
        m1s[c][v] = M1[(size_t)(n*64+c)*21 + v];
        ws[c][v]  = w_sa[i];
    }
    __syncthreads();
    const int v = tid % 21;
    const int cg = tid / 21;       // 0..11 valid
    float sum = 0.f;
    if (tid < 252){
        for (int c = cg; c < 64; c += 12){
            #pragma unroll
            for (int k = 0; k < 21; ++k){
                int src = v + k - 10;
                if (src >= 0 && src < 21)
                    sum += m1s[c][src] * ws[c][k];
            }
        }
        red[cg][v] = sum;
    }
    __syncthreads();
    if (tid < 21){
        float tot = b_sa[0];
        #pragma unroll
        for (int g = 0; g < 12; ++g) tot += red[g][tid] * (1.f/512.f);
        s1[n*Vv + tid] = 1.f + sigm(tot);
    }
}

// ---------------- M2[n,c,t] = sum_v y0*s1 ----------------
__global__ __launch_bounds__(256) void k_M2(const float* __restrict__ y0, const float* __restrict__ s1,
                      float* __restrict__ M2)
{
    int t = blockIdx.x*256 + threadIdx.x;
    int nc = blockIdx.y;
    int n = nc >> 6;
    __shared__ float s1s[21];
    if (threadIdx.x < 21) s1s[threadIdx.x] = s1[n*Vv + threadIdx.x];
    __syncthreads();
    const float* p = &y0[ ((size_t)nc*Tt + t)*Vv ];
    float sum = 0.f;
    #pragma unroll
    for (int v = 0; v < 21; ++v) sum += p[v]*s1s[v];
    M2[(size_t)nc*Tt + t] = sum;
}

// ---------------- s2[n,t] = 1 + sigmoid(conv9(M2/V)) — LDS-staged tiles ----------------
__global__ __launch_bounds__(256) void k_s2(const float* __restrict__ M2, const float* __restrict__ w_ta,
                      const float* __restrict__ b_ta, float* __restrict__ s2)
{
    const int n = blockIdx.y;
    const int t0 = blockIdx.x * 64;
    const int tid = threadIdx.x;
    __shared__ float m2s[64][72];
    __shared__ float wts[576];
    __shared__ float red[4][64];
    for (int i = tid; i < 64*72; i += 256){
        int c = i / 72, tt = i % 72;
        int src = t0 + tt - 4;
        m2s[c][tt] = (src >= 0 && src < 512) ? M2[(size_t)(n*64+c)*512 + src] : 0.f;
    }
    for (int i = tid; i < 576; i += 256) wts[i] = w_ta[i];
    __syncthreads();
    const int tl = tid & 63;
    const int cg = tid >> 6;
    float sum = 0.f;
    for (int c = cg*16; c < cg*16+16; ++c){
        #pragma unroll
        for (int k = 0; k < 9; ++k)
            sum += m2s[c][tl + k] * wts[c*9 + k];
    }
    red[cg][tl] = sum;
    __syncthreads();
    if (cg == 0){
        float tot = b_ta[0] + (red[0][tl]+red[1][tl]+red[2][tl]+red[3][tl]) * (1.f/21.f);
        s2[n*512 + t0 + tl] = 1.f + sigm(tot);
    }
}

// ---------------- sec[n,c] = (sum_t M2*s2)/(T*V) — coalesced + reduce ----------------
__global__ __launch_bounds__(256) void k_sec(const float* __restrict__ M2, const float* __restrict__ s2,
                      float* __restrict__ sec)
{
    const int c = blockIdx.x, n = blockIdx.y, tid = threadIdx.x;
    const float* row = &M2[(size_t)(n*Cc+c)*Tt];
    const float* s2r = &s2[n*Tt];
    float acc = row[tid]*s2r[tid] + row[tid+256]*s2r[tid+256];
    #pragma unroll
    for (int off = 32; off > 0; off >>= 1)
        acc += __shfl_down(acc, off, 64);
    __shared__ float red[4];
    if ((tid & 63) == 0) red[tid >> 6] = acc;
    __syncthreads();
    if (tid == 0)
        sec[n*Cc + c] = (red[0]+red[1]+red[2]+red[3]) * (1.f/(512.f*21.f));
}

// ---------------- s3[n,c]: tiny FC from sec ----------------
__global__ __launch_bounds__(64) void k_s3fc(const float* __restrict__ sec,
                     const float* __restrict__ w1, const float* __restrict__ bf1,
                     const float* __restrict__ w2, const float* __restrict__ bf2,
                     float* __restrict__ s3)
{
    int n = blockIdx.x, c = threadIdx.x;
    __shared__ float secs[64];
    __shared__ float hh[32];
    secs[c] = sec[n*Cc + c];
    __syncthreads();
    if (c < 32){
        float h = bf1[c];
        #pragma unroll 8
        for (int k = 0; k < 64; ++k) h += w1[c*64+k]*secs[k];
        hh[c] = fmaxf(h, 0.f);
    }
    __syncthreads();
    float o = bf2[c];
    #pragma unroll 8
    for (int k = 0; k < 32; ++k) o += w2[c*32+k]*hh[k];
    s3[n*Cc + c] = 1.f + sigm(o);
}

// ---------------- final in-place: relu(y0*s1*s2*s3), float4 I/O ----------------
__global__ __launch_bounds__(256) void k_final(float* __restrict__ y,
    const float* __restrict__ s1, const float* __restrict__ s2, const float* __restrict__ s3)
{
    const int c = blockIdx.x, n = blockIdx.y, tid = threadIdx.x;
    __shared__ float s1s[21];
    __shared__ float s2s[512];
    if (tid < 21) s1s[tid] = s1[n*Vv + tid];
    for (int i = tid; i < 512; i += 256) s2s[i] = s2[n*512 + i];
    __syncthreads();
    const float sc3 = s3[n*Cc + c];
    float* base = y + (size_t)(n*Cc + c)*10752;
    for (int i = tid; i < 2688; i += 256){
        float4 d = *reinterpret_cast<const float4*>(base + i*4);
        float r[4];
        #pragma unroll
        for (int e = 0; e < 4; ++e){
            int f = i*4 + e;
            int t = f / 21;
            int v = f - t*21;
            r[e] = fmaxf(((const float*)&d)[e] * s1s[v] * s2s[t] * sc3, 0.f);
        }
        *reinterpret_cast<float4*>(base + i*4) = make_float4(r[0], r[1], r[2], r[3]);
    }
}

extern "C" void kernel_launch(void* const* d_in, const int* in_sizes, int n_in,
                              void* d_out, int out_size, void* d_ws, size_t ws_size,
                              hipStream_t stream)
{
    const float* x    = (const float*)d_in[0];
    const float* g1   = (const float*)d_in[2];
    const float* b1   = (const float*)d_in[3];
    const float* mu1  = (const float*)d_in[4];
    const float* var1 = (const float*)d_in[5];
    const float* PA   = (const float*)d_in[6];
    const float* alpha= (const float*)d_in[7];
    const float* wa   = (const float*)d_in[8];
    const float* ba   = (const float*)d_in[9];
    const float* wb   = (const float*)d_in[10];
    const float* bb   = (const float*)d_in[11];
    const float* wd   = (const float*)d_in[12];
    const float* bd   = (const float*)d_in[13];
    const float* g2   = (const float*)d_in[14];
    const float* b2   = (const float*)d_in[15];
    const float* mu2  = (const float*)d_in[16];
    const float* var2 = (const float*)d_in[17];
    const float* w_sa = (const float*)d_in[18];
    const float* b_sa = (const float*)d_in[19];
    const float* w_ta = (const float*)d_in[20];
    const float* b_ta = (const float*)d_in[21];
    const float* w_fc1= (const float*)d_in[22];
    const float* b_fc1= (const float*)d_in[23];
    const float* w_fc2= (const float*)d_in[24];
    const float* b_fc2= (const float*)d_in[25];

    // ws: xbT bf16 [32][512][24][64] = 25,165,824 elems (50.33 MB), then scratch
    unsigned short* xbT = (unsigned short*)d_ws;
    float* fws  = (float*)d_ws + 12582912;
    float* part = fws;                   // 677376
    float* adjw = part + 677376;         // 42336
    float* M1   = adjw + 42336;          // 43008
    float* s1   = M1   + 43008;          // 672
    float* M2   = s1   + 672;            // 1048576
    float* s2   = M2   + 1048576;        // 16384
    float* s3   = s2   + 16384;          // 2048
    float4* bn2p = (float4*)(s3 + 2048); // 256 f32
    unsigned short* wdF   = (unsigned short*)((float*)bn2p + 256);   // 12288 u16
    unsigned short* adjF  = wdF + 12288;                             // 98304 u16
    unsigned short* wawbF = adjF + 98304;                            // 6144 u16
    float* sec  = (float*)(wawbF + 6144);                            // 2048 f32
    float* y0   = (float*)d_out;

    k_xb  <<<dim3(128, Nn), 256, 0, stream>>>(x, g1,b1,mu1,var1, xbT);
    k_wdT <<<6, 256, 0, stream>>>(wd, bd, g2, b2, mu2, var2, wdF, bn2p);
    k_wab <<<3, 256, 0, stream>>>(wa, wb, wawbF);
    k_attn<<<dim3(NCHUNK, Nn), 256, 0, stream>>>(xbT, wawbF, ba, bb, part);
    k_adj <<<(Nn*SVV + 255)/256, 256, 0, stream>>>(part, PA, alpha, adjw);
    k_adjF<<<48, 256, 0, stream>>>(adjw, adjF);
    k_y0  <<<dim3(Tt/4, Nn), 256, 0, stream>>>(xbT, adjF, wdF, bn2p, y0);
    k_M1  <<<dim3(Cc, Nn), 256, 0, stream>>>(y0, M1);
    k_s1  <<<Nn, 256, 0, stream>>>(M1, w_sa, b_sa, s1);
    k_M2  <<<dim3(Tt/256, Nn*Cc), 256, 0, stream>>>(y0, s1, M2);
    k_s2  <<<dim3(8, Nn), 256, 0, stream>>>(M2, w_ta, b_ta, s2);
    k_sec <<<dim3(Cc, Nn), 256, 0, stream>>>(M2, s2, sec);
    k_s3fc<<<Nn, 64, 0, stream>>>(sec, w_fc1, b_fc1, w_fc2, b_fc2, s3);
    k_final<<<dim3(Cc, Nn), 256, 0, stream>>>(y0, s1, s2, s3);
}

// Round 11
// 179.473 us; speedup vs baseline: 5.7173x; 1.1098x over previous
//
#include <hip/hip_runtime.h>
#include <hip/hip_bf16.h>
#include <math.h>

// AAGCN block, N=32 C=64 T=512 V=21 E=16 S=3.
// Round 11: fix round-10 replay nondeterminism — k_xb pad lanes (vp>=21) read
// unwritten LDS and relied on x*0=0; NaN residue broke replays. Now predicated
// to store literal 0. Store-coalesced k_xb otherwise unchanged.

#define Nn 32
#define Cc 64
#define Tt 512
#define Vv 21
#define VP 24
#define Ss 3
#define EPSf 1e-5f
#define NCHUNK 16
#define SVV (Ss*Vv*Vv)   // 1323
#define KSTR 136         // m-buf k-stride (16B-aligned rows, conflict-spread)

typedef __attribute__((ext_vector_type(8))) short short8;
typedef __attribute__((ext_vector_type(4))) float f32x4;

__device__ __forceinline__ float sigm(float x){ return 1.f/(1.f+expf(-x)); }
__device__ __forceinline__ float bf2f(unsigned short u){ return __uint_as_float((unsigned)u << 16); }
__device__ __forceinline__ unsigned short f2bf(float f){
    __hip_bfloat16 h = __float2bfloat16(f);
    return *reinterpret_cast<unsigned short*>(&h);
}

// ---------------- materialize xbT (BN1 + raw-reshape shuffle), bf16 ----------------
// xbT[n][b][vp][a] = BN1(x[n][b&63][a*8+(b>>6)][v]); block = (c0, n).
// brick16[t][ (v + 8*(t>>6)) & 31 ] (bf16); sc/of[vp][65] f32.
__global__ __launch_bounds__(256) void k_xb(
    const float* __restrict__ x,
    const float* __restrict__ g1, const float* __restrict__ b1,
    const float* __restrict__ mu1, const float* __restrict__ var1,
    unsigned short* __restrict__ xbT)
{
    const int c0 = blockIdx.x;
    const int n  = blockIdx.y;
    const int tid = threadIdx.x;
    __shared__ unsigned short brick16[512*32];     // 32 KB
    __shared__ float scs[21*65], ofs[21*65];       // 10.7 KB

    // fold BN params: j = vp*64 + a (vp < 21 only)
    for (int j = tid; j < 1344; j += 256){
        int vp = j >> 6, a = j & 63;
        float sc = g1[j]*rsqrtf(var1[j]+EPSf);
        scs[vp*65 + a] = sc;
        ofs[vp*65 + a] = b1[j] - mu1[j]*sc;
    }
    // stage x[n][c0] (10752 f32) into swizzled bf16 brick
    const float* xs = x + (size_t)(n*64 + c0)*10752;
    for (int i = tid; i < 2688; i += 256){
        float4 d = *reinterpret_cast<const float4*>(xs + i*4);
        #pragma unroll
        for (int e = 0; e < 4; ++e){
            int f = i*4 + e;
            int t = f / 21;
            int v = f - t*21;
            brick16[t*32 + ((v + 8*(t>>6)) & 31)] = f2bf(((const float*)&d)[e]);
        }
    }
    __syncthreads();

    if (tid < 192){
        const int agl = tid & 7;       // a-group: a = agl*8 + da
        const int vp  = tid >> 3;      // 0..23
        const bool valid = (vp < 21);
        float scr[8], ofr[8];
        #pragma unroll
        for (int da = 0; da < 8; ++da){
            scr[da] = valid ? scs[vp*65 + agl*8 + da] : 0.f;
            ofr[da] = valid ? ofs[vp*65 + agl*8 + da] : 0.f;
        }
        unsigned short* ob = xbT + ((size_t)(n*512 + c0)*24 + vp)*64 + agl*8;
        #pragma unroll
        for (int m = 0; m < 8; ++m){
            unsigned short pk[8];
            #pragma unroll
            for (int da = 0; da < 8; ++da){
                int row = agl*64 + da*8 + m;     // = a*8 + m
                float xv = bf2f(brick16[row*32 + ((vp + 8*agl) & 31)]);
                float r = xv*scr[da] + ofr[da];
                pk[da] = valid ? f2bf(r) : (unsigned short)0;   // pad lanes: exact 0
            }
            *reinterpret_cast<uint4*>(ob + (size_t)m*64*24*64) =
                *reinterpret_cast<const uint4*>(pk);
        }
    }
}

// ---------------- pack wd into MFMA A-fragment layout + BN2 params ----------------
__global__ __launch_bounds__(256) void k_wdT(
    const float* __restrict__ wd, const float* __restrict__ bd,
    const float* __restrict__ g2, const float* __restrict__ b2,
    const float* __restrict__ mu2, const float* __restrict__ var2,
    unsigned short* __restrict__ wdF, float4* __restrict__ bn2p)
{
    int i = blockIdx.x*256 + threadIdx.x;
    if (i < 1536){
        int s  = i / 512;
        int w  = (i >> 7) & 3;
        int ks = (i >> 6) & 1;
        int l  = i & 63;
        int o  = 16*w + (l & 15);
        #pragma unroll
        for (int j = 0; j < 8; ++j){
            int c = 32*ks + 8*(l >> 4) + j;
            wdF[(size_t)i*8 + j] = f2bf(wd[(s*64 + o)*64 + c]);
        }
    }
    if (i < 64){
        float bsum = bd[i] + bd[64+i] + bd[128+i];
        float sc = g2[i]*rsqrtf(var2[i]+EPSf);
        bn2p[i] = make_float4(bsum, sc, mu2[i], b2[i]);
    }
}

// ---------------- pack [wa;wb] into MFMA A-fragment layout (96 x 64) ----------------
__global__ __launch_bounds__(256) void k_wab(
    const float* __restrict__ wa, const float* __restrict__ wb,
    unsigned short* __restrict__ wawbF)
{
    int i = blockIdx.x*256 + threadIdx.x;
    if (i >= 768) return;
    int mt = i / 128;
    int ks = (i / 64) & 1;
    int l  = i & 63;
    int e  = l & 15;
    int g  = l >> 4;
    const float* src = (mt < 3) ? wa : wb;
    int s = (mt < 3) ? mt : mt - 3;
    #pragma unroll
    for (int j = 0; j < 8; ++j){
        int c = ks*32 + 8*g + j;
        wawbF[(size_t)i*8 + j] = f2bf(src[(s*16 + e)*64 + c]);
    }
}

// ---------------- attention pre-activation partials (MFMA) ----------------
__global__ __launch_bounds__(256) void k_attn(
    const unsigned short* __restrict__ xbT,
    const unsigned short* __restrict__ wawbF,
    const float* __restrict__ ba, const float* __restrict__ bb,
    float* __restrict__ part)
{
    const int chunk = blockIdx.x;
    const int n = blockIdx.y;
    const int tid = threadIdx.x;
    const int w  = tid >> 6;
    const int l  = tid & 63;
    const int g  = l >> 4;
    const int ln = l & 15;

    __shared__ unsigned short m1buf[3*32*KSTR];
    __shared__ unsigned short m2buf[3*32*KSTR];

    for (int i = tid; i < 3*8*KSTR; i += 256){
        int s = i / (8*KSTR), r = i % (8*KSTR);
        int off = (s*32 + 24)*KSTR + r;
        m1buf[off] = 0; m2buf[off] = 0;
    }

    short8 aF[6][2];
    float4 bias4[6];
    #pragma unroll
    for (int mt = 0; mt < 6; ++mt){
        #pragma unroll
        for (int ks = 0; ks < 2; ++ks)
            aF[mt][ks] = *reinterpret_cast<const short8*>(wawbF + (size_t)((mt*2+ks)*64 + l)*8);
        const float* bsrc = (mt < 3) ? (ba + mt*16) : (bb + (mt-3)*16);
        bias4[mt] = *reinterpret_cast<const float4*>(bsrc + 4*g);
    }

    f32x4 accB[3];
    #pragma unroll
    for (int q = 0; q < 3; ++q) accB[q] = (f32x4){0.f,0.f,0.f,0.f};

    int colv[3], colt[3];
    #pragma unroll
    for (int q = 0; q < 3; ++q){
        int col = (3*w + q)*16 + ln;
        colt[q] = col / 24;
        colv[q] = col % 24;
    }

    for (int st = 0; st < 4; ++st){
        const int tb = chunk*32 + st*8;
        #pragma unroll
        for (int q = 0; q < 3; ++q){
            const unsigned short* bp = xbT + ((size_t)(n*512 + tb + colt[q])*24 + colv[q])*64;
            short8 b0 = *reinterpret_cast<const short8*>(bp + 8*g);
            short8 b1 = *reinterpret_cast<const short8*>(bp + 32 + 8*g);
            #pragma unroll
            for (int mt = 0; mt < 6; ++mt){
                f32x4 c;
                c[0] = bias4[mt].x; c[1] = bias4[mt].y;
                c[2] = bias4[mt].z; c[3] = bias4[mt].w;
                c = __builtin_amdgcn_mfma_f32_16x16x32_bf16(aF[mt][0], b0, c, 0, 0, 0);
                c = __builtin_amdgcn_mfma_f32_16x16x32_bf16(aF[mt][1], b1, c, 0, 0, 0);
                unsigned short* dst = (mt < 3) ? m1buf : m2buf;
                int s = (mt < 3) ? mt : mt - 3;
                unsigned u0 = (unsigned)f2bf(c[0]) | ((unsigned)f2bf(c[1]) << 16);
                unsigned u1 = (unsigned)f2bf(c[2]) | ((unsigned)f2bf(c[3]) << 16);
                int off = (s*32 + colv[q])*KSTR + colt[q]*16 + 4*g;
                *reinterpret_cast<uint2*>(dst + off) = make_uint2(u0, u1);
            }
        }
        __syncthreads();
        #pragma unroll
        for (int q = 0; q < 3; ++q){
            int ct = 3*w + q;
            int s = ct >> 2, mtile = (ct >> 1) & 1, ntile = ct & 1;
            #pragma unroll
            for (int kk = 0; kk < 4; ++kk){
                short8 a = *reinterpret_cast<const short8*>(&m1buf[(s*32 + mtile*16 + ln)*KSTR + kk*32 + 8*g]);
                short8 b = *reinterpret_cast<const short8*>(&m2buf[(s*32 + ntile*16 + ln)*KSTR + kk*32 + 8*g]);
                accB[q] = __builtin_amdgcn_mfma_f32_16x16x32_bf16(a, b, accB[q], 0, 0, 0);
            }
        }
        __syncthreads();
    }

    float* pout = part + (size_t)(n*NCHUNK + chunk)*SVV;
    #pragma unroll
    for (int q = 0; q < 3; ++q){
        int ct = 3*w + q;
        int s = ct >> 2, mtile = (ct >> 1) & 1, ntile = ct & 1;
        int v = ntile*16 + ln;
        #pragma unroll
        for (int r = 0; r < 4; ++r){
            int u = mtile*16 + 4*g + r;
            if (u < 21 && v < 21)
                pout[s*441 + u*21 + v] = accB[q][r];
        }
    }
}

// ---------------- adj = PA + tanh(pre/8192)*alpha ----------------
__global__ void k_adj(const float* __restrict__ part, const float* __restrict__ PA,
                      const float* __restrict__ alpha, float* __restrict__ adj)
{
    int i = blockIdx.x*256 + threadIdx.x;
    if (i >= Nn*SVV) return;
    int n = i / SVV;
    int idx = i % SVV;
    float pre = 0.f;
    for (int ch = 0; ch < NCHUNK; ++ch)
        pre += part[(size_t)(n*NCHUNK+ch)*SVV + idx];
    adj[i] = PA[idx] + tanhf(pre * (1.f/8192.f)) * alpha[0];
}

// ---------------- pack adj into MFMA B-fragment layout (bf16) ----------------
__global__ __launch_bounds__(256) void k_adjF(const float* __restrict__ adj,
                                              unsigned short* __restrict__ adjF)
{
    int i = blockIdx.x*256 + threadIdx.x;
    if (i >= Nn*Ss*2*64) return;
    int n = i / 384;
    int r = i % 384;
    int s = r / 128;
    int r2 = r % 128;
    int h = r2 >> 6;
    int l = r2 & 63;
    int v = 16*h + (l & 15);
    #pragma unroll
    for (int j = 0; j < 8; ++j){
        int u = 8*(l >> 4) + j;
        float val = (u < 21 && v < 21) ? adj[(size_t)n*SVV + s*441 + u*21 + v] : 0.f;
        adjF[(size_t)i*8 + j] = f2bf(val);
    }
}

// ---------------- graph conv + wd + BN2 + residual + relu (MFMA) ----------------
__global__ __launch_bounds__(256) void k_y0(
    const unsigned short* __restrict__ xbT,
    const unsigned short* __restrict__ adjF,
    const unsigned short* __restrict__ wdF,
    const float4* __restrict__ bn2p,
    float* __restrict__ y0)
{
    const int n  = blockIdx.y;
    const int t0 = blockIdx.x * 4;
    const int tid = threadIdx.x;
    const int w  = tid >> 6;
    const int l  = tid & 63;
    const int g  = l >> 4;
    const int ln = l & 15;

    __shared__ unsigned short xbuf[64*136];   // [c][4t x 32u], row stride 272B
    __shared__ unsigned short zbuf[128*72];   // [col][64c], col stride 144B

    {
        int c = tid >> 2, t = tid & 3;
        *reinterpret_cast<uint4*>(&xbuf[c*136 + t*32 + 24]) = make_uint4(0u,0u,0u,0u);
    }
    for (int k = 0; k < 3; ++k){
        int i = tid + k*256;                  // 768 = 8cg x 4t x 24u
        int u = i % 24, t = (i/24) & 3, cg = i / 96;
        uint4 d = *reinterpret_cast<const uint4*>(
            xbT + ((size_t)(n*512 + t0 + t)*24 + u)*64 + cg*8);
        const unsigned short* p = reinterpret_cast<const unsigned short*>(&d);
        #pragma unroll
        for (int dc = 0; dc < 8; ++dc)
            xbuf[(cg*8 + dc)*136 + t*32 + u] = p[dc];
    }
    __syncthreads();

    short8 ax[4];
    #pragma unroll
    for (int t = 0; t < 4; ++t)
        ax[t] = *reinterpret_cast<const short8*>(&xbuf[(16*w + ln)*136 + t*32 + 8*g]);

    short8 badj[3][2];
    {
        const unsigned short* ap = adjF + (size_t)n*Ss*2*64*8;
        #pragma unroll
        for (int s = 0; s < 3; ++s)
            #pragma unroll
            for (int h = 0; h < 2; ++h)
                badj[s][h] = *reinterpret_cast<const short8*>(ap + ((s*2 + h)*64 + l)*8);
    }

    f32x4 acc[8];
    #pragma unroll
    for (int ct = 0; ct < 8; ++ct) acc[ct] = (f32x4){0.f,0.f,0.f,0.f};

    for (int s = 0; s < 3; ++s){
        if (s) __syncthreads();
        f32x4 dz[8];
        #pragma unroll
        for (int ct = 0; ct < 8; ++ct)
            dz[ct] = __builtin_amdgcn_mfma_f32_16x16x32_bf16(
                         ax[ct>>1], badj[s][ct&1], (f32x4){0.f,0.f,0.f,0.f}, 0, 0, 0);
        #pragma unroll
        for (int ct = 0; ct < 8; ++ct){
            unsigned u0 = (unsigned)f2bf(dz[ct][0]) | ((unsigned)f2bf(dz[ct][1]) << 16);
            unsigned u1 = (unsigned)f2bf(dz[ct][2]) | ((unsigned)f2bf(dz[ct][3]) << 16);
            int col = (ct >> 1)*32 + (ct & 1)*16 + ln;
            *reinterpret_cast<uint2*>(&zbuf[col*72 + 16*w + 4*g]) = make_uint2(u0, u1);
        }
        __syncthreads();
        short8 aw0 = *reinterpret_cast<const short8*>(wdF + (size_t)(((s*4 + w)*2 + 0)*64 + l)*8);
        short8 aw1 = *reinterpret_cast<const short8*>(wdF + (size_t)(((s*4 + w)*2 + 1)*64 + l)*8);
        #pragma unroll
        for (int ct = 0; ct < 8; ++ct){
            int col = (ct >> 1)*32 + (ct & 1)*16 + ln;
            short8 b0 = *reinterpret_cast<const short8*>(&zbuf[col*72 + 0  + 8*g]);
            short8 b1 = *reinterpret_cast<const short8*>(&zbuf[col*72 + 32 + 8*g]);
            acc[ct] = __builtin_amdgcn_mfma_f32_16x16x32_bf16(aw0, b0, acc[ct], 0, 0, 0);
            acc[ct] = __builtin_amdgcn_mfma_f32_16x16x32_bf16(aw1, b1, acc[ct], 0, 0, 0);
        }
    }

    float4 bp[4];
    #pragma unroll
    for (int r = 0; r < 4; ++r) bp[r] = bn2p[16*w + 4*g + r];
    #pragma unroll
    for (int ct = 0; ct < 8; ++ct){
        const int t  = ct >> 1;
        const int vp = (ct & 1)*16 + ln;
        if (vp < 21){
            #pragma unroll
            for (int r = 0; r < 4; ++r){
                const int o = 16*w + 4*g + r;
                float val = acc[ct][r] + bp[r].x;
                val = (val - bp[r].z)*bp[r].y + bp[r].w;
                val += bf2f(xbuf[o*136 + t*32 + vp]);
                y0[((size_t)(n*64 + o)*512 + t0 + t)*21 + vp] = fmaxf(val, 0.f);
            }
        }
    }
}

// ---------------- M1[n,c,v] = sum_t y0 ----------------
__global__ __launch_bounds__(256) void k_M1(const float* __restrict__ y0, float* __restrict__ M1)
{
    const int c = blockIdx.x, n = blockIdx.y, tid = threadIdx.x;
    float a[21];
    #pragma unroll
    for (int v = 0; v < 21; ++v) a[v] = 0.f;
    for (int t = tid; t < Tt; t += 256){
        const float* p = &y0[ ((size_t)(n*Cc+c)*Tt + t)*Vv ];
        #pragma unroll
        for (int v = 0; v < 21; ++v) a[v] += p[v];
    }
    __shared__ float red[256][21];
    #pragma unroll
    for (int v = 0; v < 21; ++v) red[tid][v] = a[v];
    __syncthreads();
    for (int off = 128; off > 0; off >>= 1){
        if (tid < off){
            #pragma unroll
            for (int v = 0; v < 21; ++v) red[tid][v] += red[tid+off][v];
        }
        __syncthreads();
    }
    if (tid < 21) M1[(size_t)(n*Cc+c)*Vv + tid] = red[0][tid];
}

// ---------------- s1[n,v] = 1 + sigmoid(conv21(M1/T)) — LDS-parallel ----------------
__global__ __launch_bounds__(256) void k_s1(const float* __restrict__ M1, const float* __restrict__ w_sa,
                     const float* __restrict__ b_sa, float* __restrict__ s1)
{
    const int n = blockIdx.x, tid = threadIdx.x;
    __shared__ float m1s[64][22];
    __shared__ float ws[64][22];
    __shared__ float red[12][21];
    for (int i = tid; i < 1344; i += 256){
        int c = i / 21, v = i % 21;
        m1s[c][v] = M1[(size_t)(n*64+c)*21 + v];
        ws[c][v]  = w_sa[i];
    }
    __syncthreads();
    const int v = tid % 21;
    const int cg = tid / 21;       // 0..11 valid
    float sum = 0.f;
    if (tid < 252){
        for (int c = cg; c < 64; c += 12){
            #pragma unroll
            for (int k = 0; k < 21; ++k){
                int src = v + k - 10;
                if (src >= 0 && src < 21)
                    sum += m1s[c][src] * ws[c][k];
            }
        }
        red[cg][v] = sum;
    }
    __syncthreads();
    if (tid < 21){
        float tot = b_sa[0];
        #pragma unroll
        for (int g = 0; g < 12; ++g) tot += red[g][tid] * (1.f/512.f);
        s1[n*Vv + tid] = 1.f + sigm(tot);
    }
}

// ---------------- M2[n,c,t] = sum_v y0*s1 ----------------
__global__ __launch_bounds__(256) void k_M2(const float* __restrict__ y0, const float* __restrict__ s1,
                      float* __restrict__ M2)
{
    int t = blockIdx.x*256 + threadIdx.x;
    int nc = blockIdx.y;
    int n = nc >> 6;
    __shared__ float s1s[21];
    if (threadIdx.x < 21) s1s[threadIdx.x] = s1[n*Vv + threadIdx.x];
    __syncthreads();
    const float* p = &y0[ ((size_t)nc*Tt + t)*Vv ];
    float sum = 0.f;
    #pragma unroll
    for (int v = 0; v < 21; ++v) sum += p[v]*s1s[v];
    M2[(size_t)nc*Tt + t] = sum;
}

// ---------------- s2[n,t] = 1 + sigmoid(conv9(M2/V)) — LDS-staged tiles ----------------
__global__ __launch_bounds__(256) void k_s2(const float* __restrict__ M2, const float* __restrict__ w_ta,
                      const float* __restrict__ b_ta, float* __restrict__ s2)
{
    const int n = blockIdx.y;
    const int t0 = blockIdx.x * 64;
    const int tid = threadIdx.x;
    __shared__ float m2s[64][72];
    __shared__ float wts[576];
    __shared__ float red[4][64];
    for (int i = tid; i < 64*72; i += 256){
        int c = i / 72, tt = i % 72;
        int src = t0 + tt - 4;
        m2s[c][tt] = (src >= 0 && src < 512) ? M2[(size_t)(n*64+c)*512 + src] : 0.f;
    }
    for (int i = tid; i < 576; i += 256) wts[i] = w_ta[i];
    __syncthreads();
    const int tl = tid & 63;
    const int cg = tid >> 6;
    float sum = 0.f;
    for (int c = cg*16; c < cg*16+16; ++c){
        #pragma unroll
        for (int k = 0; k < 9; ++k)
            sum += m2s[c][tl + k] * wts[c*9 + k];
    }
    red[cg][tl] = sum;
    __syncthreads();
    if (cg == 0){
        float tot = b_ta[0] + (red[0][tl]+red[1][tl]+red[2][tl]+red[3][tl]) * (1.f/21.f);
        s2[n*512 + t0 + tl] = 1.f + sigm(tot);
    }
}

// ---------------- sec[n,c] = (sum_t M2*s2)/(T*V) — coalesced + reduce ----------------
__global__ __launch_bounds__(256) void k_sec(const float* __restrict__ M2, const float* __restrict__ s2,
                      float* __restrict__ sec)
{
    const int c = blockIdx.x, n = blockIdx.y, tid = threadIdx.x;
    const float* row = &M2[(size_t)(n*Cc+c)*Tt];
    const float* s2r = &s2[n*Tt];
    float acc = row[tid]*s2r[tid] + row[tid+256]*s2r[tid+256];
    #pragma unroll
    for (int off = 32; off > 0; off >>= 1)
        acc += __shfl_down(acc, off, 64);
    __shared__ float red[4];
    if ((tid & 63) == 0) red[tid >> 6] = acc;
    __syncthreads();
    if (tid == 0)
        sec[n*Cc + c] = (red[0]+red[1]+red[2]+red[3]) * (1.f/(512.f*21.f));
}

// ---------------- s3[n,c]: tiny FC from sec ----------------
__global__ __launch_bounds__(64) void k_s3fc(const float* __restrict__ sec,
                     const float* __restrict__ w1, const float* __restrict__ bf1,
                     const float* __restrict__ w2, const float* __restrict__ bf2,
                     float* __restrict__ s3)
{
    int n = blockIdx.x, c = threadIdx.x;
    __shared__ float secs[64];
    __shared__ float hh[32];
    secs[c] = sec[n*Cc + c];
    __syncthreads();
    if (c < 32){
        float h = bf1[c];
        #pragma unroll 8
        for (int k = 0; k < 64; ++k) h += w1[c*64+k]*secs[k];
        hh[c] = fmaxf(h, 0.f);
    }
    __syncthreads();
    float o = bf2[c];
    #pragma unroll 8
    for (int k = 0; k < 32; ++k) o += w2[c*32+k]*hh[k];
    s3[n*Cc + c] = 1.f + sigm(o);
}

// ---------------- final in-place: relu(y0*s1*s2*s3), float4 I/O ----------------
__global__ __launch_bounds__(256) void k_final(float* __restrict__ y,
    const float* __restrict__ s1, const float* __restrict__ s2, const float* __restrict__ s3)
{
    const int c = blockIdx.x, n = blockIdx.y, tid = threadIdx.x;
    __shared__ float s1s[21];
    __shared__ float s2s[512];
    if (tid < 21) s1s[tid] = s1[n*Vv + tid];
    for (int i = tid; i < 512; i += 256) s2s[i] = s2[n*512 + i];
    __syncthreads();
    const float sc3 = s3[n*Cc + c];
    float* base = y + (size_t)(n*Cc + c)*10752;
    for (int i = tid; i < 2688; i += 256){
        float4 d = *reinterpret_cast<const float4*>(base + i*4);
        float r[4];
        #pragma unroll
        for (int e = 0; e < 4; ++e){
            int f = i*4 + e;
            int t = f / 21;
            int v = f - t*21;
            r[e] = fmaxf(((const float*)&d)[e] * s1s[v] * s2s[t] * sc3, 0.f);
        }
        *reinterpret_cast<float4*>(base + i*4) = make_float4(r[0], r[1], r[2], r[3]);
    }
}

extern "C" void kernel_launch(void* const* d_in, const int* in_sizes, int n_in,
                              void* d_out, int out_size, void* d_ws, size_t ws_size,
                              hipStream_t stream)
{
    const float* x    = (const float*)d_in[0];
    const float* g1   = (const float*)d_in[2];
    const float* b1   = (const float*)d_in[3];
    const float* mu1  = (const float*)d_in[4];
    const float* var1 = (const float*)d_in[5];
    const float* PA   = (const float*)d_in[6];
    const float* alpha= (const float*)d_in[7];
    const float* wa   = (const float*)d_in[8];
    const float* ba   = (const float*)d_in[9];
    const float* wb   = (const float*)d_in[10];
    const float* bb   = (const float*)d_in[11];
    const float* wd   = (const float*)d_in[12];
    const float* bd   = (const float*)d_in[13];
    const float* g2   = (const float*)d_in[14];
    const float* b2   = (const float*)d_in[15];
    const float* mu2  = (const float*)d_in[16];
    const float* var2 = (const float*)d_in[17];
    const float* w_sa = (const float*)d_in[18];
    const float* b_sa = (const float*)d_in[19];
    const float* w_ta = (const float*)d_in[20];
    const float* b_ta = (const float*)d_in[21];
    const float* w_fc1= (const float*)d_in[22];
    const float* b_fc1= (const float*)d_in[23];
    const float* w_fc2= (const float*)d_in[24];
    const float* b_fc2= (const float*)d_in[25];

    // ws: xbT bf16 [32][512][24][64] = 25,165,824 elems (50.33 MB), then scratch
    unsigned short* xbT = (unsigned short*)d_ws;
    float* fws  = (float*)d_ws + 12582912;
    float* part = fws;                   // 677376
    float* adjw = part + 677376;         // 42336
    float* M1   = adjw + 42336;          // 43008
    float* s1   = M1   + 43008;          // 672
    float* M2   = s1   + 672;            // 1048576
    float* s2   = M2   + 1048576;        // 16384
    float* s3   = s2   + 16384;          // 2048
    float4* bn2p = (float4*)(s3 + 2048); // 256 f32
    unsigned short* wdF   = (unsigned short*)((float*)bn2p + 256);   // 12288 u16
    unsigned short* adjF  = wdF + 12288;                             // 98304 u16
    unsigned short* wawbF = adjF + 98304;                            // 6144 u16
    float* sec  = (float*)(wawbF + 6144);                            // 2048 f32
    float* y0   = (float*)d_out;

    k_xb  <<<dim3(64, Nn), 256, 0, stream>>>(x, g1,b1,mu1,var1, xbT);
    k_wdT <<<6, 256, 0, stream>>>(wd, bd, g2, b2, mu2, var2, wdF, bn2p);
    k_wab <<<3, 256, 0, stream>>>(wa, wb, wawbF);
    k_attn<<<dim3(NCHUNK, Nn), 256, 0, stream>>>(xbT, wawbF, ba, bb, part);
    k_adj <<<(Nn*SVV + 255)/256, 256, 0, stream>>>(part, PA, alpha, adjw);
    k_adjF<<<48, 256, 0, stream>>>(adjw, adjF);
    k_y0  <<<dim3(Tt/4, Nn), 256, 0, stream>>>(xbT, adjF, wdF, bn2p, y0);
    k_M1  <<<dim3(Cc, Nn), 256, 0, stream>>>(y0, M1);
    k_s1  <<<Nn, 256, 0, stream>>>(M1, w_sa, b_sa, s1);
    k_M2  <<<dim3(Tt/256, Nn*Cc), 256, 0, stream>>>(y0, s1, M2);
    k_s2  <<<dim3(8, Nn), 256, 0, stream>>>(M2, w_ta, b_ta, s2);
    k_sec <<<dim3(Cc, Nn), 256, 0, stream>>>(M2, s2, sec);
    k_s3fc<<<Nn, 64, 0, stream>>>(sec, w_fc1, b_fc1, w_fc2, b_fc2, s3);
    k_final<<<dim3(Cc, Nn), 256, 0, stream>>>(y0, s1, s2, s3);
}